// Round 2
// baseline (489.034 us; speedup 1.0000x reference)
//
#include <hip/hip_runtime.h>
#include <hip/hip_bf16.h>
#include <math.h>

#define N_NODES 10000
#define N_EDGES 100000
#define NCH 64
#define NSPEC 10

static __device__ __forceinline__ float silu_f(float x){ return x / (1.0f + __expf(-x)); }

// ---------- CSR build ----------
__global__ void k_count(const int* __restrict__ recv, int* __restrict__ cnt){
  int i = blockIdx.x*blockDim.x + threadIdx.x;
  if (i < N_EDGES) atomicAdd(&cnt[recv[i]], 1);
}

__global__ void k_scan(int* __restrict__ cnt_cursor, int* __restrict__ starts){
  __shared__ int sd[1024];
  int tid = threadIdx.x;
  int running = 0;
  for (int base = 0; base < N_NODES; base += 1024){
    int i = base + tid;
    int v = (i < N_NODES) ? cnt_cursor[i] : 0;
    sd[tid] = v;
    __syncthreads();
    for (int off = 1; off < 1024; off <<= 1){
      int t = (tid >= off) ? sd[tid - off] : 0;
      __syncthreads();
      sd[tid] += t;
      __syncthreads();
    }
    int excl = running + sd[tid] - v;
    if (i < N_NODES){ starts[i] = excl; cnt_cursor[i] = excl; }
    int tot = sd[1023];
    __syncthreads();
    running += tot;
  }
  if (tid == 0) starts[N_NODES] = running;
}

__global__ void k_fill(const int* __restrict__ recv, int* __restrict__ cursor, int* __restrict__ elist){
  int i = blockIdx.x*blockDim.x + threadIdx.x;
  if (i < N_EDGES){ int pos = atomicAdd(&cursor[recv[i]], 1); elist[pos] = i; }
}

// ---------- weight transposes: T[s][d][c] = W[s][c][d] ----------
__global__ void k_trans(const float* __restrict__ sel, const float* __restrict__ resw,
                        float* __restrict__ selT, float* __restrict__ resT){
  int i = blockIdx.x*blockDim.x + threadIdx.x;          // 10*4096
  int s = i >> 12, r = i & 4095, d = r >> 6, c = r & 63;
  int src = s*4096 + c*64 + d;
  selT[i] = sel[src];
  resT[i] = resw[src];
}

// ---------- h1 = embed[species] @ l1_lin_up ----------
__global__ void k_h1(const int* __restrict__ species, const float* __restrict__ embedW,
                     const float* __restrict__ linup, float* __restrict__ h1){
  int w = (blockIdx.x*blockDim.x + threadIdx.x) >> 6;
  int lane = threadIdx.x & 63;
  if (w >= N_NODES) return;
  int sp = __builtin_amdgcn_readfirstlane(species[w]);
  const float* x0 = embedW + sp*NCH;
  float acc = 0.f;
  #pragma unroll
  for (int d = 0; d < NCH; d++) acc += x0[d] * linup[d*NCH + lane];
  h1[w*NCH + lane] = acc;
}

// ---------- per-edge: geometry + bessel + both radial hidden layers + unit vec ----------
__global__ void k_edge(const float* __restrict__ ev,
                       const float* __restrict__ rW1a, const float* __restrict__ rW1b,
                       float* __restrict__ hid1, float* __restrict__ hid2,
                       float4* __restrict__ shu){
  int e = (blockIdx.x*blockDim.x + threadIdx.x) >> 6;
  int lane = threadIdx.x & 63;
  if (e >= N_EDGES) return;
  float ex = ev[e*3+0], ey = ev[e*3+1], ez = ev[e*3+2];
  float r = sqrtf(ex*ex + ey*ey + ez*ez + 1e-12f);
  float rinv = 1.0f / r;
  float u = r * 0.2f;                     // r / R_MAX
  float env = 0.f;
  if (u < 1.f){ float om = 1.f - u; env = om*om*(1.f + 2.f*u); }
  float pref = 0.6324555320336759f * rinv * env;   // sqrt(2/5)
  float rad[8];
  #pragma unroll
  for (int b = 0; b < 8; b++)
    rad[b] = pref * __sinf((float)(b+1) * 3.14159265358979f * u);
  float a1 = 0.f, a2 = 0.f;
  #pragma unroll
  for (int b = 0; b < 8; b++){
    a1 += rad[b] * rW1a[b*64 + lane];
    a2 += rad[b] * rW1b[b*64 + lane];
  }
  hid1[(size_t)e*64 + lane] = silu_f(a1);
  hid2[(size_t)e*64 + lane] = silu_f(a2);
  if (lane == 0) shu[e] = make_float4(ex*rinv, ey*rinv, ez*rinv, 0.f);
}

// ---------- pass-1 gather + node transforms (2 waves per node, k-split) ----------
__global__ __launch_bounds__(256, 3) void k_node1(
  const int* __restrict__ senders, const int* __restrict__ species,
  const int* __restrict__ starts, const int* __restrict__ elist,
  const float4* __restrict__ shu,
  const float* __restrict__ hid1, const float* __restrict__ h1,
  const float* __restrict__ rW2a,
  const float* __restrict__ selT,
  const float* __restrict__ pw, const float* __restrict__ uwv,
  const float* __restrict__ row,
  const float* __restrict__ linup2, const float* __restrict__ resT,
  float* __restrict__ out,
  float* __restrict__ h2o, float4* __restrict__ outvo4, float* __restrict__ reso)
{
  int lane  = threadIdx.x & 63;
  int wslot = threadIdx.x >> 6;       // 0..3
  int nl    = wslot >> 1;             // local node 0/1
  int part  = wslot & 1;              // 0: k=0 path, 1: k=1..3 path
  int n = blockIdx.x*2 + nl;

  __shared__ float s_s[2][64];
  __shared__ float s_v[2][3][64];
  __shared__ float s_o[2][64];

  // 64 weights per wave: column 4*lane (part 0) or 4*lane+1 (part 1)
  float w[64];
  #pragma unroll
  for (int h = 0; h < 64; h++) w[h] = rW2a[h*256 + 4*lane + part];

  int s0 = __builtin_amdgcn_readfirstlane(starts[n]);
  int s1 = __builtin_amdgcn_readfirstlane(starts[n+1]);
  int sp = __builtin_amdgcn_readfirstlane(species[n]);

  float acc0 = 0.f, acc1 = 0.f, acc2 = 0.f, acc3 = 0.f;
  for (int base = s0; base < s1; base += 64){
    int m = min(64, s1 - base);
    int e_l = 0, snd_l = 0;
    float svx = 0.f, svy = 0.f, svz = 0.f;
    if (lane < m){
      e_l   = elist[base + lane];
      snd_l = senders[e_l];
      float4 sv = shu[e_l];
      svx = sv.x; svy = sv.y; svz = sv.z;
    }
    for (int t = 0; t < m; t++){
      int e   = __shfl(e_l, t, 64);
      int snd = __shfl(snd_l, t, 64);
      float h1s = h1[snd*64 + lane];
      const float4* hp = reinterpret_cast<const float4*>(hid1 + (size_t)e*64);
      float rw = 0.f;
      #pragma unroll
      for (int i = 0; i < 16; i++){
        float4 hv = hp[i];
        rw += hv.x*w[4*i+0] + hv.y*w[4*i+1] + hv.z*w[4*i+2] + hv.w*w[4*i+3];
      }
      if (part == 0){
        acc0 += rw * h1s;
      } else {
        float sx = __shfl(svx, t, 64);
        float sy = __shfl(svy, t, 64);
        float sz = __shfl(svz, t, 64);
        float mm = rw * h1s;
        acc1 += mm*sx; acc2 += mm*sy; acc3 += mm*sz;
      }
    }
  }

  if (part == 0){
    s_s[nl][lane] = acc0 * 0.1f;                       // / AVG_NEIGH
  } else {
    const float c13 = 0.17320508075688773f;            // sqrt(3)/10
    s_v[nl][0][lane] = acc1 * c13;
    s_v[nl][1][lane] = acc2 * c13;
    s_v[nl][2][lane] = acc3 * c13;
  }
  __syncthreads();

  if (part == 0){
    // feats[c,k] = sum_d selW[c,d] * agg[d,k]
    const float* selp = selT + sp*4096;
    float f0 = 0.f, f1 = 0.f, f2 = 0.f, f3 = 0.f;
    #pragma unroll 8
    for (int d = 0; d < 64; d++){
      float wv = selp[d*64 + lane];
      f0 += wv * s_s[nl][d];
      f1 += wv * s_v[nl][0][d];
      f2 += wv * s_v[nl][1][d];
      f3 += wv * s_v[nl][2][d];
    }
    float s = f0;
    const float* pwp = pw  + sp*192;
    const float* uwp = uwv + sp*192;
    float pw0 = pwp[lane], pw1 = pwp[64+lane], pw2 = pwp[128+lane];
    float uw0 = uwp[lane], uw1 = uwp[64+lane], uw2 = uwp[128+lane];
    float ss = s*s;
    float o0  = pw0*s + pw1*ss + pw2*ss*s;
    float uco = uw0 + uw1*s + uw2*ss;
    outvo4[n*64 + lane] = make_float4(uco*f1, uco*f2, uco*f3, 0.f);

    float rv = o0 * row[lane];
    #pragma unroll
    for (int off = 32; off >= 1; off >>= 1) rv += __shfl_xor(rv, off, 64);
    if (lane == 0) out[n*2 + 0] = rv;

    s_o[nl][lane] = o0;
  }
  __syncthreads();

  if (part == 1){
    float hh = 0.f, rr = 0.f;
    const float* resp = resT + sp*4096;
    #pragma unroll 8
    for (int d = 0; d < 64; d++){
      float od = s_o[nl][d];
      hh += od * linup2[d*64 + lane];
      rr += od * resp[d*64 + lane];
    }
    h2o[n*64 + lane]  = hh;
    reso[n*64 + lane] = rr;
  }
}

// ---------- pass-2 gather + readout (2 waves per node, edge-split) ----------
__global__ __launch_bounds__(256, 3) void k_node2(
  const int* __restrict__ senders, const int* __restrict__ species,
  const int* __restrict__ starts, const int* __restrict__ elist,
  const float4* __restrict__ shu,
  const float* __restrict__ hid2,
  const float* __restrict__ rW2b,
  const float* __restrict__ h2o, const float4* __restrict__ outvo4,
  const float* __restrict__ reso,
  const float* __restrict__ pw2,
  const float* __restrict__ roW1, const float* __restrict__ roW2,
  float* __restrict__ out)
{
  int lane  = threadIdx.x & 63;
  int wslot = threadIdx.x >> 6;
  int nl    = wslot >> 1;
  int part  = wslot & 1;
  int n = blockIdx.x*2 + nl;

  __shared__ float s_a[2][2][64];
  __shared__ float s_out[2][64];

  float wb[64];
  #pragma unroll
  for (int h = 0; h < 64; h++) wb[h] = rW2b[h*256 + 4*lane];

  int s0 = __builtin_amdgcn_readfirstlane(starts[n]);
  int s1 = __builtin_amdgcn_readfirstlane(starts[n+1]);
  int sp = __builtin_amdgcn_readfirstlane(species[n]);

  float acc = 0.f;
  for (int base = s0; base < s1; base += 64){
    int m = min(64, s1 - base);
    int e_l = 0, snd_l = 0;
    float uvx = 0.f, uvy = 0.f, uvz = 0.f;
    if (lane < m){
      e_l   = elist[base + lane];
      snd_l = senders[e_l];
      float4 sv = shu[e_l];
      uvx = sv.x; uvy = sv.y; uvz = sv.z;
    }
    int h = (m + 1) >> 1;
    int t0 = part ? h : 0;
    int t1 = part ? m : h;
    for (int t = t0; t < t1; t++){
      int e   = __shfl(e_l, t, 64);
      int snd = __shfl(snd_l, t, 64);
      float ux = __shfl(uvx, t, 64);
      float uy = __shfl(uvy, t, 64);
      float uz = __shfl(uvz, t, 64);
      const float4* hp = reinterpret_cast<const float4*>(hid2 + (size_t)e*64);
      float rw = 0.f;
      #pragma unroll
      for (int i = 0; i < 16; i++){
        float4 hv = hp[i];
        rw += hv.x*wb[4*i+0] + hv.y*wb[4*i+1] + hv.z*wb[4*i+2] + hv.w*wb[4*i+3];
      }
      float h2s = h2o[snd*64 + lane];
      float4 ov = outvo4[snd*64 + lane];
      float edt = ov.x*ux + ov.y*uy + ov.z*uz;
      acc += rw * (h2s + edt);
    }
  }
  s_a[nl][part][lane] = acc;
  __syncthreads();

  if (part == 0){
    float s2 = (s_a[nl][0][lane] + s_a[nl][1][lane]) * 0.1f;
    const float* p2 = pw2 + sp*192;
    float q0 = p2[lane], q1 = p2[64+lane], q2 = p2[128+lane];
    float s2s = s2*s2;
    float o2 = q0*s2 + q1*s2s + q2*s2s*s2 + reso[n*64 + lane];

    s_out[nl][lane] = o2;
    asm volatile("s_waitcnt lgkmcnt(0)" ::: "memory");

    // ro2 = silu(out2 @ roW1) @ roW2 : lane -> (j = lane&15, group g = lane>>4)
    int j = lane & 15, g = lane >> 4;
    float qp = 0.f;
    #pragma unroll
    for (int t = 0; t < 16; t++){
      int c = g*16 + t;
      qp += s_out[nl][c] * roW1[c*16 + j];
    }
    qp += __shfl_xor(qp, 16, 64);
    qp += __shfl_xor(qp, 32, 64);
    float sil = qp / (1.f + __expf(-qp));
    float contrib = sil * roW2[j];
    contrib += __shfl_xor(contrib, 1, 64);
    contrib += __shfl_xor(contrib, 2, 64);
    contrib += __shfl_xor(contrib, 4, 64);
    contrib += __shfl_xor(contrib, 8, 64);
    if (lane == 0) out[n*2 + 1] = contrib;
  }
}

extern "C" void kernel_launch(void* const* d_in, const int* in_sizes, int n_in,
                              void* d_out, int out_size, void* d_ws, size_t ws_size,
                              hipStream_t stream)
{
  const float* ev     = (const float*)d_in[0];
  const int*   spec   = (const int*)  d_in[1];
  const int*   send   = (const int*)  d_in[2];
  const int*   recv   = (const int*)  d_in[3];
  const float* embedW = (const float*)d_in[4];
  const float* l1_lin = (const float*)d_in[5];
  const float* l1_rW1 = (const float*)d_in[6];
  const float* l1_rW2 = (const float*)d_in[7];
  const float* l1_sel = (const float*)d_in[8];
  const float* l1_pw  = (const float*)d_in[9];
  const float* l1_uw  = (const float*)d_in[10];
  const float* l1_row = (const float*)d_in[11];
  const float* l2_lin = (const float*)d_in[12];
  const float* l2_rW1 = (const float*)d_in[13];
  const float* l2_rW2 = (const float*)d_in[14];
  const float* l2_res = (const float*)d_in[15];
  const float* l2_pw  = (const float*)d_in[16];
  const float* l2_roW1= (const float*)d_in[17];
  const float* l2_roW2= (const float*)d_in[18];
  float* out = (float*)d_out;

  char* w = (char*)d_ws;
  float*  hid1  = (float*)w;  w += (size_t)N_EDGES*64*4;
  float*  hid2  = (float*)w;  w += (size_t)N_EDGES*64*4;
  float*  h1    = (float*)w;  w += (size_t)N_NODES*64*4;
  float*  h2o   = (float*)w;  w += (size_t)N_NODES*64*4;
  float4* outvo4= (float4*)w; w += (size_t)N_NODES*64*16;
  float*  reso  = (float*)w;  w += (size_t)N_NODES*64*4;
  float*  selT  = (float*)w;  w += (size_t)NSPEC*4096*4;
  float*  resT  = (float*)w;  w += (size_t)NSPEC*4096*4;
  float4* shu   = (float4*)w; w += (size_t)N_EDGES*16;
  int* starts = (int*)w;      w += (size_t)(N_NODES+1)*4;
  int* cursor = (int*)w;      w += (size_t)N_NODES*4;
  int* elist  = (int*)w;      w += (size_t)N_EDGES*4;

  hipMemsetAsync(cursor, 0, N_NODES*sizeof(int), stream);
  k_count<<<(N_EDGES+255)/256, 256, 0, stream>>>(recv, cursor);
  k_scan <<<1, 1024, 0, stream>>>(cursor, starts);
  k_fill <<<(N_EDGES+255)/256, 256, 0, stream>>>(recv, cursor, elist);
  k_trans<<<(NSPEC*4096)/256, 256, 0, stream>>>(l1_sel, l2_res, selT, resT);
  k_h1   <<<(N_NODES*64)/256, 256, 0, stream>>>(spec, embedW, l1_lin, h1);
  k_edge <<<(N_EDGES*64)/256, 256, 0, stream>>>(ev, l1_rW1, l2_rW1, hid1, hid2, shu);
  k_node1<<<N_NODES/2, 256, 0, stream>>>(send, spec, starts, elist, shu, hid1, h1,
        l1_rW2, selT, l1_pw, l1_uw, l1_row, l2_lin, resT, out, h2o, outvo4, reso);
  k_node2<<<N_NODES/2, 256, 0, stream>>>(send, spec, starts, elist, shu, hid2,
        l2_rW2, h2o, outvo4, reso, l2_pw, l2_roW1, l2_roW2, out);
}

// Round 3
// 445.412 us; speedup vs baseline: 1.0979x; 1.0979x over previous
//
#include <hip/hip_runtime.h>
#include <hip/hip_bf16.h>
#include <math.h>

#define N_NODES 10000
#define N_EDGES 100000
#define NCH 64
#define NSPEC 10

// ---------- CSR build ----------
__global__ void k_count(const int* __restrict__ recv, int* __restrict__ cnt){
  int i = blockIdx.x*blockDim.x + threadIdx.x;
  if (i < N_EDGES) atomicAdd(&cnt[recv[i]], 1);
}

// coarsened scan: 256 threads, 40 nodes each
__global__ void k_scan(int* __restrict__ cnt_cursor, int* __restrict__ starts){
  __shared__ int stot[256];
  int tid = threadIdx.x;
  int base = tid*40;
  int loc[40];
  int sum = 0;
  #pragma unroll
  for (int j = 0; j < 40; j++){
    int i = base + j;
    int v = (i < N_NODES) ? cnt_cursor[i] : 0;
    loc[j] = sum; sum += v;
  }
  stot[tid] = sum;
  __syncthreads();
  for (int off = 1; off < 256; off <<= 1){
    int t = (tid >= off) ? stot[tid-off] : 0;
    __syncthreads();
    stot[tid] += t;
    __syncthreads();
  }
  int excl = stot[tid] - sum;
  #pragma unroll
  for (int j = 0; j < 40; j++){
    int i = base + j;
    if (i < N_NODES){ int st = excl + loc[j]; starts[i] = st; cnt_cursor[i] = st; }
  }
  if (tid == 255) starts[N_NODES] = stot[255];
}

__global__ void k_fill(const int* __restrict__ recv, int* __restrict__ cursor, int* __restrict__ elist){
  int i = blockIdx.x*blockDim.x + threadIdx.x;
  if (i < N_EDGES){ int pos = atomicAdd(&cursor[recv[i]], 1); elist[pos] = i; }
}

// ---------- weight transposes: T[s][d][c] = W[s][c][d] ----------
__global__ void k_trans(const float* __restrict__ sel, const float* __restrict__ resw,
                        float* __restrict__ selT, float* __restrict__ resT){
  int i = blockIdx.x*blockDim.x + threadIdx.x;          // 10*4096
  int s = i >> 12, r = i & 4095, d = r >> 6, c = r & 63;
  int src = s*4096 + c*64 + d;
  selT[i] = sel[src];
  resT[i] = resw[src];
}

// ---------- h1 = embed[species] @ l1_lin_up ----------
__global__ void k_h1(const int* __restrict__ species, const float* __restrict__ embedW,
                     const float* __restrict__ linup, float* __restrict__ h1){
  int w = (blockIdx.x*blockDim.x + threadIdx.x) >> 6;
  int lane = threadIdx.x & 63;
  if (w >= N_NODES) return;
  int sp = __builtin_amdgcn_readfirstlane(species[w]);
  const float* x0 = embedW + sp*NCH;
  float acc = 0.f;
  #pragma unroll
  for (int d = 0; d < NCH; d++) acc += x0[d] * linup[d*NCH + lane];
  h1[w*NCH + lane] = acc;
}

// ---------- dense per-edge radial work: lane = edge, weights via scalar loads ----------
// PHASE 0: rw12[e][c] = (col 4c, col 4c+1) of silu(bessel@rW1)@rW2  + shu[e]
// PHASE 1: rwB[e][c]  =  col 4c
template<int PHASE>
__global__ __launch_bounds__(64) void k_rw(
    const float* __restrict__ ev,
    const float* __restrict__ rW1,
    const float* __restrict__ rW2,
    float2* __restrict__ rw12,
    float*  __restrict__ rwB,
    float4* __restrict__ shu)
{
  __shared__ float xb[64*66];
  int lane = threadIdx.x;
  int e0 = blockIdx.x * 64;
  int e = e0 + lane;
  bool act = (e < N_EDGES);

  float ex = 0.f, ey = 0.f, ez = 1.f;
  if (act){ ex = ev[e*3+0]; ey = ev[e*3+1]; ez = ev[e*3+2]; }
  float r = sqrtf(ex*ex + ey*ey + ez*ez + 1e-12f);
  float rinv = 1.0f / r;
  float u = r * 0.2f;
  float env = 0.f;
  if (u < 1.f){ float om = 1.f - u; env = om*om*(1.f + 2.f*u); }
  float pref = 0.6324555320336759f * rinv * env;   // sqrt(2/5)
  float rad[8];
  #pragma unroll
  for (int b = 0; b < 8; b++)
    rad[b] = pref * __sinf((float)(b+1) * 3.14159265358979f * u);

  if (PHASE == 0){
    if (act) shu[e] = make_float4(ex*rinv, ey*rinv, ez*rinv, 0.f);
    float2* xb2 = (float2*)xb;
    #pragma unroll
    for (int half = 0; half < 2; half++){
      int c0 = half*32;
      float a0[32], a1[32];
      #pragma unroll
      for (int i = 0; i < 32; i++){ a0[i] = 0.f; a1[i] = 0.f; }
      #pragma unroll 4
      for (int h = 0; h < 64; h++){
        float ah = 0.f;
        #pragma unroll
        for (int b = 0; b < 8; b++) ah += rad[b] * rW1[b*64 + h];   // uniform -> s_load
        float hid = ah / (1.f + __expf(-ah));
        const float* wr = rW2 + h*256 + 4*c0;                        // uniform row
        #pragma unroll
        for (int i = 0; i < 32; i++){
          a0[i] += hid * wr[4*i+0];
          a1[i] += hid * wr[4*i+1];
        }
      }
      // LDS transpose -> coalesced [e][c] writes
      #pragma unroll
      for (int i = 0; i < 32; i++) xb2[lane*33 + i] = make_float2(a0[i], a1[i]);
      asm volatile("s_waitcnt lgkmcnt(0)" ::: "memory");
      int c = lane & 31, sub = lane >> 5;
      #pragma unroll 4
      for (int k = 0; k < 32; k++){
        int row = 2*k + sub;
        float2 v = xb2[row*33 + c];
        int er = e0 + row;
        if (er < N_EDGES) rw12[(size_t)er*64 + c0 + c] = v;
      }
      asm volatile("s_waitcnt lgkmcnt(0)" ::: "memory");
    }
  } else {
    float a[64];
    #pragma unroll
    for (int i = 0; i < 64; i++) a[i] = 0.f;
    #pragma unroll 4
    for (int h = 0; h < 64; h++){
      float ah = 0.f;
      #pragma unroll
      for (int b = 0; b < 8; b++) ah += rad[b] * rW1[b*64 + h];
      float hid = ah / (1.f + __expf(-ah));
      const float* wr = rW2 + h*256;
      #pragma unroll
      for (int i = 0; i < 64; i++) a[i] += hid * wr[4*i];
    }
    #pragma unroll
    for (int i = 0; i < 64; i++) xb[lane*65 + i] = a[i];
    asm volatile("s_waitcnt lgkmcnt(0)" ::: "memory");
    #pragma unroll 4
    for (int k = 0; k < 64; k++){
      float v = xb[k*65 + lane];
      int er = e0 + k;
      if (er < N_EDGES) rwB[(size_t)er*64 + lane] = v;
    }
  }
}

// ---------- pass-1 gather + node transforms (1 wave per node, no weights) ----------
__global__ __launch_bounds__(256) void k_node1(
  const int* __restrict__ senders, const int* __restrict__ species,
  const int* __restrict__ starts, const int* __restrict__ elist,
  const float4* __restrict__ shu,
  const float2* __restrict__ rw12, const float* __restrict__ h1,
  const float* __restrict__ selT,
  const float* __restrict__ pw, const float* __restrict__ uwv,
  const float* __restrict__ row,
  const float* __restrict__ linup2, const float* __restrict__ resT,
  float* __restrict__ out,
  float4* __restrict__ outvo4, float* __restrict__ reso)
{
  int lane  = threadIdx.x & 63;
  int wslot = threadIdx.x >> 6;
  int n = blockIdx.x*4 + wslot;          // grid exact: 2500*4 = 10000
  __shared__ float4 sacc[4][64];

  int s0 = __builtin_amdgcn_readfirstlane(starts[n]);
  int s1 = __builtin_amdgcn_readfirstlane(starts[n+1]);
  int sp = __builtin_amdgcn_readfirstlane(species[n]);

  float acc0 = 0.f, acc1 = 0.f, acc2 = 0.f, acc3 = 0.f;
  for (int base = s0; base < s1; base += 64){
    int m = min(64, s1 - base);
    int e_l = 0, snd_l = 0;
    if (lane < m){
      e_l   = elist[base + lane];
      snd_l = senders[e_l];
    }
    for (int t = 0; t < m; t++){
      int e   = __builtin_amdgcn_readfirstlane(__shfl(e_l, t, 64));
      int snd = __builtin_amdgcn_readfirstlane(__shfl(snd_l, t, 64));
      float2 rv = rw12[(size_t)e*64 + lane];
      float h1s = h1[snd*64 + lane];
      float4 sv = shu[e];                      // uniform addr -> s_load
      acc0 += rv.x * h1s;
      float mm = rv.y * h1s;
      acc1 += mm*sv.x; acc2 += mm*sv.y; acc3 += mm*sv.z;
    }
  }
  const float c10 = 0.1f;                      // 1/AVG_NEIGH
  const float c13 = 0.17320508075688773f;      // sqrt(3)/10
  sacc[wslot][lane] = make_float4(acc0*c10, acc1*c13, acc2*c13, acc3*c13);
  asm volatile("s_waitcnt lgkmcnt(0)" ::: "memory");

  // feats[c,k] = sum_d selW[c,d] * agg[d,k]
  const float* selp = selT + sp*4096;
  float f0 = 0.f, f1 = 0.f, f2 = 0.f, f3 = 0.f;
  #pragma unroll 8
  for (int d = 0; d < 64; d++){
    float wv = selp[d*64 + lane];
    float4 a = sacc[wslot][d];
    f0 += wv*a.x; f1 += wv*a.y; f2 += wv*a.z; f3 += wv*a.w;
  }

  float s = f0;
  const float* pwp = pw  + sp*192;
  const float* uwp = uwv + sp*192;
  float pw0 = pwp[lane], pw1 = pwp[64+lane], pw2 = pwp[128+lane];
  float uw0 = uwp[lane], uw1 = uwp[64+lane], uw2 = uwp[128+lane];
  float ss = s*s;
  float o0  = pw0*s + pw1*ss + pw2*ss*s;
  float uco = uw0 + uw1*s + uw2*ss;

  // ro1 = sum_c o0[c]*row[c]
  float rv = o0 * row[lane];
  #pragma unroll
  for (int off = 32; off >= 1; off >>= 1) rv += __shfl_xor(rv, off, 64);
  if (lane == 0) out[n*2 + 0] = rv;

  // stage o0, compute h2 and res
  float* so = reinterpret_cast<float*>(&sacc[wslot][0]);
  asm volatile("s_waitcnt lgkmcnt(0)" ::: "memory");
  so[lane] = o0;
  asm volatile("s_waitcnt lgkmcnt(0)" ::: "memory");

  float hh = 0.f, rr = 0.f;
  const float* resp = resT + sp*4096;
  #pragma unroll 8
  for (int d = 0; d < 64; d++){
    float od = so[d];
    hh += od * linup2[d*64 + lane];
    rr += od * resp[d*64 + lane];
  }
  outvo4[n*64 + lane] = make_float4(uco*f1, uco*f2, uco*f3, hh);  // .w = h2
  reso[n*64 + lane] = rr;
}

// ---------- pass-2 gather + readout (1 wave per node) ----------
__global__ __launch_bounds__(256) void k_node2(
  const int* __restrict__ senders, const int* __restrict__ species,
  const int* __restrict__ starts, const int* __restrict__ elist,
  const float4* __restrict__ shu,
  const float* __restrict__ rwB,
  const float4* __restrict__ outvo4, const float* __restrict__ reso,
  const float* __restrict__ pw2,
  const float* __restrict__ roW1, const float* __restrict__ roW2,
  float* __restrict__ out)
{
  int lane  = threadIdx.x & 63;
  int wslot = threadIdx.x >> 6;
  int n = blockIdx.x*4 + wslot;
  __shared__ float sout[4][64];

  int s0 = __builtin_amdgcn_readfirstlane(starts[n]);
  int s1 = __builtin_amdgcn_readfirstlane(starts[n+1]);
  int sp = __builtin_amdgcn_readfirstlane(species[n]);

  float acc = 0.f;
  for (int base = s0; base < s1; base += 64){
    int m = min(64, s1 - base);
    int e_l = 0, snd_l = 0;
    if (lane < m){
      e_l   = elist[base + lane];
      snd_l = senders[e_l];
    }
    for (int t = 0; t < m; t++){
      int e   = __builtin_amdgcn_readfirstlane(__shfl(e_l, t, 64));
      int snd = __builtin_amdgcn_readfirstlane(__shfl(snd_l, t, 64));
      float rw = rwB[(size_t)e*64 + lane];
      float4 ov = outvo4[snd*64 + lane];
      float4 sv = shu[e];                      // uniform addr -> s_load
      acc += rw * (ov.w + ov.x*sv.x + ov.y*sv.y + ov.z*sv.z);
    }
  }
  float s2 = acc * 0.1f;
  const float* p2 = pw2 + sp*192;
  float q0 = p2[lane], q1 = p2[64+lane], q2 = p2[128+lane];
  float s2s = s2*s2;
  float o2 = q0*s2 + q1*s2s + q2*s2s*s2 + reso[n*64 + lane];

  sout[wslot][lane] = o2;
  asm volatile("s_waitcnt lgkmcnt(0)" ::: "memory");

  // ro2 = silu(out2 @ roW1) @ roW2
  int j = lane & 15, g = lane >> 4;
  float qp = 0.f;
  #pragma unroll
  for (int t = 0; t < 16; t++){
    int c = g*16 + t;
    qp += sout[wslot][c] * roW1[c*16 + j];
  }
  qp += __shfl_xor(qp, 16, 64);
  qp += __shfl_xor(qp, 32, 64);
  float sil = qp / (1.f + __expf(-qp));
  float contrib = sil * roW2[j];
  contrib += __shfl_xor(contrib, 1, 64);
  contrib += __shfl_xor(contrib, 2, 64);
  contrib += __shfl_xor(contrib, 4, 64);
  contrib += __shfl_xor(contrib, 8, 64);
  if (lane == 0) out[n*2 + 1] = contrib;
}

extern "C" void kernel_launch(void* const* d_in, const int* in_sizes, int n_in,
                              void* d_out, int out_size, void* d_ws, size_t ws_size,
                              hipStream_t stream)
{
  const float* ev     = (const float*)d_in[0];
  const int*   spec   = (const int*)  d_in[1];
  const int*   send   = (const int*)  d_in[2];
  const int*   recv   = (const int*)  d_in[3];
  const float* embedW = (const float*)d_in[4];
  const float* l1_lin = (const float*)d_in[5];
  const float* l1_rW1 = (const float*)d_in[6];
  const float* l1_rW2 = (const float*)d_in[7];
  const float* l1_sel = (const float*)d_in[8];
  const float* l1_pw  = (const float*)d_in[9];
  const float* l1_uw  = (const float*)d_in[10];
  const float* l1_row = (const float*)d_in[11];
  const float* l2_lin = (const float*)d_in[12];
  const float* l2_rW1 = (const float*)d_in[13];
  const float* l2_rW2 = (const float*)d_in[14];
  const float* l2_res = (const float*)d_in[15];
  const float* l2_pw  = (const float*)d_in[16];
  const float* l2_roW1= (const float*)d_in[17];
  const float* l2_roW2= (const float*)d_in[18];
  float* out = (float*)d_out;

  char* w = (char*)d_ws;
  float2* rw12  = (float2*)w; w += (size_t)N_EDGES*64*8;   // 51.2 MB; phase-C rwB aliases it
  float*  rwB   = (float*)rw12;
  float*  h1    = (float*)w;  w += (size_t)N_NODES*64*4;
  float4* outvo4= (float4*)w; w += (size_t)N_NODES*64*16;
  float*  reso  = (float*)w;  w += (size_t)N_NODES*64*4;
  float*  selT  = (float*)w;  w += (size_t)NSPEC*4096*4;
  float*  resT  = (float*)w;  w += (size_t)NSPEC*4096*4;
  float4* shu   = (float4*)w; w += (size_t)N_EDGES*16;
  int* starts = (int*)w;      w += (size_t)(N_NODES+1)*4;
  int* cursor = (int*)w;      w += (size_t)N_NODES*4;
  int* elist  = (int*)w;      w += (size_t)N_EDGES*4;

  hipMemsetAsync(cursor, 0, N_NODES*sizeof(int), stream);
  k_count<<<(N_EDGES+255)/256, 256, 0, stream>>>(recv, cursor);
  k_scan <<<1, 256, 0, stream>>>(cursor, starts);
  k_fill <<<(N_EDGES+255)/256, 256, 0, stream>>>(recv, cursor, elist);
  k_trans<<<(NSPEC*4096)/256, 256, 0, stream>>>(l1_sel, l2_res, selT, resT);
  k_h1   <<<(N_NODES*64)/256, 256, 0, stream>>>(spec, embedW, l1_lin, h1);
  k_rw<0><<<(N_EDGES+63)/64, 64, 0, stream>>>(ev, l1_rW1, l1_rW2, rw12, rwB, shu);
  k_node1<<<N_NODES/4, 256, 0, stream>>>(send, spec, starts, elist, shu, rw12, h1,
        selT, l1_pw, l1_uw, l1_row, l2_lin, resT, out, outvo4, reso);
  k_rw<1><<<(N_EDGES+63)/64, 64, 0, stream>>>(ev, l2_rW1, l2_rW2, rw12, rwB, shu);
  k_node2<<<N_NODES/4, 256, 0, stream>>>(send, spec, starts, elist, shu, rwB,
        outvo4, reso, l2_pw, l2_roW1, l2_roW2, out);
}

// Round 4
// 176.244 us; speedup vs baseline: 2.7747x; 2.5272x over previous
//
#include <hip/hip_runtime.h>
#include <hip/hip_bf16.h>
#include <math.h>

#define N_NODES 10000
#define N_EDGES 100000
#define NCH 64
#define NSPEC 10

// ---------- CSR build ----------
__global__ void k_count(const int* __restrict__ recv, int* __restrict__ cnt){
  int i = blockIdx.x*blockDim.x + threadIdx.x;
  if (i < N_EDGES) atomicAdd(&cnt[recv[i]], 1);
}

// coarsened scan: 256 threads, 40 nodes each
__global__ void k_scan(int* __restrict__ cnt_cursor, int* __restrict__ starts){
  __shared__ int stot[256];
  int tid = threadIdx.x;
  int base = tid*40;
  int loc[40];
  int sum = 0;
  #pragma unroll
  for (int j = 0; j < 40; j++){
    int i = base + j;
    int v = (i < N_NODES) ? cnt_cursor[i] : 0;
    loc[j] = sum; sum += v;
  }
  stot[tid] = sum;
  __syncthreads();
  for (int off = 1; off < 256; off <<= 1){
    int t = (tid >= off) ? stot[tid-off] : 0;
    __syncthreads();
    stot[tid] += t;
    __syncthreads();
  }
  int excl = stot[tid] - sum;
  #pragma unroll
  for (int j = 0; j < 40; j++){
    int i = base + j;
    if (i < N_NODES){ int st = excl + loc[j]; starts[i] = st; cnt_cursor[i] = st; }
  }
  if (tid == 255) starts[N_NODES] = stot[255];
}

__global__ void k_fill(const int* __restrict__ recv, int* __restrict__ cursor, int* __restrict__ elist){
  int i = blockIdx.x*blockDim.x + threadIdx.x;
  if (i < N_EDGES){ int pos = atomicAdd(&cursor[recv[i]], 1); elist[pos] = i; }
}

// ---------- weight transposes: T[s][d][c] = W[s][c][d] ----------
__global__ void k_trans(const float* __restrict__ sel, const float* __restrict__ resw,
                        float* __restrict__ selT, float* __restrict__ resT){
  int i = blockIdx.x*blockDim.x + threadIdx.x;          // 10*4096
  int s = i >> 12, r = i & 4095, d = r >> 6, c = r & 63;
  int src = s*4096 + c*64 + d;
  selT[i] = sel[src];
  resT[i] = resw[src];
}

// ---------- h1 = embed[species] @ l1_lin_up ----------
__global__ void k_h1(const int* __restrict__ species, const float* __restrict__ embedW,
                     const float* __restrict__ linup, float* __restrict__ h1){
  int w = (blockIdx.x*blockDim.x + threadIdx.x) >> 6;
  int lane = threadIdx.x & 63;
  if (w >= N_NODES) return;
  int sp = __builtin_amdgcn_readfirstlane(species[w]);
  const float* x0 = embedW + sp*NCH;
  float acc = 0.f;
  #pragma unroll
  for (int d = 0; d < NCH; d++) acc += x0[d] * linup[d*NCH + lane];
  h1[w*NCH + lane] = acc;
}

// ---------- tiled radial GEMM: 64-edge tile per 256-thread block ----------
// PHASE 0: rw12[e][c] = (col 4c, col 4c+1) of silu(bessel@rW1)@rW2, + shu[e]
// PHASE 1: rwB[e][c]  =  col 4c
template<int PHASE>
__global__ __launch_bounds__(256) void k_rw(
    const float* __restrict__ ev,
    const float* __restrict__ rW1,
    const float* __restrict__ rW2,
    float2* __restrict__ rw12,
    float*  __restrict__ rwB,
    float4* __restrict__ shu)
{
  __shared__ float s_rad[64*9];        // [e][b], pad 9 (conflict-free lane=e access)
  __shared__ float s_hidT[64*68];      // [h][e], pad 68 (16B-aligned rows)
  __shared__ float s_w2[(PHASE==0)?8192:4096];

  int tid = threadIdx.x;
  int e0 = blockIdx.x*64;

  // stage W2 columns into LDS (one-time, 256 threads x 16)
  if (PHASE == 0){
    float2* w2 = (float2*)s_w2;
    #pragma unroll
    for (int k = 0; k < 16; k++){
      int idx = tid + k*256;           // 4096 = 64h x 64c
      int h = idx >> 6, c = idx & 63;
      w2[idx] = make_float2(rW2[h*256 + 4*c], rW2[h*256 + 4*c + 1]);
    }
  } else {
    #pragma unroll
    for (int k = 0; k < 16; k++){
      int idx = tid + k*256;
      int h = idx >> 6, c = idx & 63;
      s_w2[idx] = rW2[h*256 + 4*c];
    }
  }

  // rad + shu: wave 0, lane = edge
  if (tid < 64){
    int e = e0 + tid;
    bool act = (e < N_EDGES);
    float ex = 0.f, ey = 0.f, ez = 1.f;
    if (act){ ex = ev[e*3+0]; ey = ev[e*3+1]; ez = ev[e*3+2]; }
    float r = sqrtf(ex*ex + ey*ey + ez*ez + 1e-12f);
    float rinv = 1.0f / r;
    float u = r * 0.2f;
    float env = 0.f;
    if (u < 1.f){ float om = 1.f - u; env = om*om*(1.f + 2.f*u); }
    float pref = 0.6324555320336759f * rinv * env;   // sqrt(2/5)
    #pragma unroll
    for (int b = 0; b < 8; b++)
      s_rad[tid*9 + b] = pref * __sinf((float)(b+1) * 3.14159265358979f * u);
    if (PHASE == 0 && act) shu[e] = make_float4(ex*rinv, ey*rinv, ez*rinv, 0.f);
  }
  __syncthreads();

  // hid: thread (e = tid&63, hg = tid>>6), h = hg*16+j ; store transposed
  {
    int e = tid & 63, hg = tid >> 6;
    float rd[8];
    #pragma unroll
    for (int b = 0; b < 8; b++) rd[b] = s_rad[e*9 + b];
    #pragma unroll
    for (int j = 0; j < 16; j++){
      int h = hg*16 + j;
      float ah = 0.f;
      #pragma unroll
      for (int b = 0; b < 8; b++) ah += rd[b] * rW1[b*64 + h];   // wave-uniform -> s_load
      float hid = ah / (1.f + __expf(-ah));
      s_hidT[h*68 + e] = hid;                                    // stride-1 in e: conflict-free
    }
  }
  __syncthreads();

  // GEMM: thread (c = tid&63, eg = tid>>6) accumulates 16 edges x output col(s)
  int c = tid & 63, eg = tid >> 6;
  if (PHASE == 0){
    const float2* w2 = (const float2*)s_w2;
    float2 acc[16];
    #pragma unroll
    for (int j = 0; j < 16; j++) acc[j] = make_float2(0.f, 0.f);
    #pragma unroll 4
    for (int h = 0; h < 64; h++){
      float2 w = w2[h*64 + c];                                   // ds_read_b64
      const float4* hp = (const float4*)(s_hidT + h*68 + eg*16); // uniform broadcasts
      float hv[16];
      *(float4*)&hv[0]  = hp[0];
      *(float4*)&hv[4]  = hp[1];
      *(float4*)&hv[8]  = hp[2];
      *(float4*)&hv[12] = hp[3];
      #pragma unroll
      for (int j = 0; j < 16; j++){
        acc[j].x += hv[j]*w.x;
        acc[j].y += hv[j]*w.y;
      }
    }
    #pragma unroll
    for (int j = 0; j < 16; j++){
      int er = e0 + eg*16 + j;
      if (er < N_EDGES) rw12[(size_t)er*64 + c] = acc[j];
    }
  } else {
    float acc[16];
    #pragma unroll
    for (int j = 0; j < 16; j++) acc[j] = 0.f;
    #pragma unroll 4
    for (int h = 0; h < 64; h++){
      float w = s_w2[h*64 + c];
      const float4* hp = (const float4*)(s_hidT + h*68 + eg*16);
      float hv[16];
      *(float4*)&hv[0]  = hp[0];
      *(float4*)&hv[4]  = hp[1];
      *(float4*)&hv[8]  = hp[2];
      *(float4*)&hv[12] = hp[3];
      #pragma unroll
      for (int j = 0; j < 16; j++) acc[j] += hv[j]*w;
    }
    #pragma unroll
    for (int j = 0; j < 16; j++){
      int er = e0 + eg*16 + j;
      if (er < N_EDGES) rwB[(size_t)er*64 + c] = acc[j];
    }
  }
}

// ---------- pass-1 gather + node transforms (1 wave per node, no weights) ----------
__global__ __launch_bounds__(256) void k_node1(
  const int* __restrict__ senders, const int* __restrict__ species,
  const int* __restrict__ starts, const int* __restrict__ elist,
  const float4* __restrict__ shu,
  const float2* __restrict__ rw12, const float* __restrict__ h1,
  const float* __restrict__ selT,
  const float* __restrict__ pw, const float* __restrict__ uwv,
  const float* __restrict__ row,
  const float* __restrict__ linup2, const float* __restrict__ resT,
  float* __restrict__ out,
  float4* __restrict__ outvo4, float* __restrict__ reso)
{
  int lane  = threadIdx.x & 63;
  int wslot = threadIdx.x >> 6;
  int n = blockIdx.x*4 + wslot;          // grid exact: 2500*4 = 10000
  __shared__ float4 sacc[4][64];

  int s0 = __builtin_amdgcn_readfirstlane(starts[n]);
  int s1 = __builtin_amdgcn_readfirstlane(starts[n+1]);
  int sp = __builtin_amdgcn_readfirstlane(species[n]);

  float acc0 = 0.f, acc1 = 0.f, acc2 = 0.f, acc3 = 0.f;
  for (int base = s0; base < s1; base += 64){
    int m = min(64, s1 - base);
    int e_l = 0, snd_l = 0;
    if (lane < m){
      e_l   = elist[base + lane];
      snd_l = senders[e_l];
    }
    for (int t = 0; t < m; t++){
      int e   = __builtin_amdgcn_readfirstlane(__shfl(e_l, t, 64));
      int snd = __builtin_amdgcn_readfirstlane(__shfl(snd_l, t, 64));
      float2 rv = rw12[(size_t)e*64 + lane];
      float h1s = h1[snd*64 + lane];
      float4 sv = shu[e];                      // uniform addr -> s_load
      acc0 += rv.x * h1s;
      float mm = rv.y * h1s;
      acc1 += mm*sv.x; acc2 += mm*sv.y; acc3 += mm*sv.z;
    }
  }
  const float c10 = 0.1f;                      // 1/AVG_NEIGH
  const float c13 = 0.17320508075688773f;      // sqrt(3)/10
  sacc[wslot][lane] = make_float4(acc0*c10, acc1*c13, acc2*c13, acc3*c13);
  asm volatile("s_waitcnt lgkmcnt(0)" ::: "memory");

  // feats[c,k] = sum_d selW[c,d] * agg[d,k]
  const float* selp = selT + sp*4096;
  float f0 = 0.f, f1 = 0.f, f2 = 0.f, f3 = 0.f;
  #pragma unroll 8
  for (int d = 0; d < 64; d++){
    float wv = selp[d*64 + lane];
    float4 a = sacc[wslot][d];
    f0 += wv*a.x; f1 += wv*a.y; f2 += wv*a.z; f3 += wv*a.w;
  }

  float s = f0;
  const float* pwp = pw  + sp*192;
  const float* uwp = uwv + sp*192;
  float pw0 = pwp[lane], pw1 = pwp[64+lane], pw2 = pwp[128+lane];
  float uw0 = uwp[lane], uw1 = uwp[64+lane], uw2 = uwp[128+lane];
  float ss = s*s;
  float o0  = pw0*s + pw1*ss + pw2*ss*s;
  float uco = uw0 + uw1*s + uw2*ss;

  // ro1 = sum_c o0[c]*row[c]
  float rv = o0 * row[lane];
  #pragma unroll
  for (int off = 32; off >= 1; off >>= 1) rv += __shfl_xor(rv, off, 64);
  if (lane == 0) out[n*2 + 0] = rv;

  // stage o0, compute h2 and res
  float* so = reinterpret_cast<float*>(&sacc[wslot][0]);
  asm volatile("s_waitcnt lgkmcnt(0)" ::: "memory");
  so[lane] = o0;
  asm volatile("s_waitcnt lgkmcnt(0)" ::: "memory");

  float hh = 0.f, rr = 0.f;
  const float* resp = resT + sp*4096;
  #pragma unroll 8
  for (int d = 0; d < 64; d++){
    float od = so[d];
    hh += od * linup2[d*64 + lane];
    rr += od * resp[d*64 + lane];
  }
  outvo4[n*64 + lane] = make_float4(uco*f1, uco*f2, uco*f3, hh);  // .w = h2
  reso[n*64 + lane] = rr;
}

// ---------- pass-2 gather + readout (1 wave per node) ----------
__global__ __launch_bounds__(256) void k_node2(
  const int* __restrict__ senders, const int* __restrict__ species,
  const int* __restrict__ starts, const int* __restrict__ elist,
  const float4* __restrict__ shu,
  const float* __restrict__ rwB,
  const float4* __restrict__ outvo4, const float* __restrict__ reso,
  const float* __restrict__ pw2,
  const float* __restrict__ roW1, const float* __restrict__ roW2,
  float* __restrict__ out)
{
  int lane  = threadIdx.x & 63;
  int wslot = threadIdx.x >> 6;
  int n = blockIdx.x*4 + wslot;
  __shared__ float sout[4][64];

  int s0 = __builtin_amdgcn_readfirstlane(starts[n]);
  int s1 = __builtin_amdgcn_readfirstlane(starts[n+1]);
  int sp = __builtin_amdgcn_readfirstlane(species[n]);

  float acc = 0.f;
  for (int base = s0; base < s1; base += 64){
    int m = min(64, s1 - base);
    int e_l = 0, snd_l = 0;
    if (lane < m){
      e_l   = elist[base + lane];
      snd_l = senders[e_l];
    }
    for (int t = 0; t < m; t++){
      int e   = __builtin_amdgcn_readfirstlane(__shfl(e_l, t, 64));
      int snd = __builtin_amdgcn_readfirstlane(__shfl(snd_l, t, 64));
      float rw = rwB[(size_t)e*64 + lane];
      float4 ov = outvo4[snd*64 + lane];
      float4 sv = shu[e];                      // uniform addr -> s_load
      acc += rw * (ov.w + ov.x*sv.x + ov.y*sv.y + ov.z*sv.z);
    }
  }
  float s2 = acc * 0.1f;
  const float* p2 = pw2 + sp*192;
  float q0 = p2[lane], q1 = p2[64+lane], q2 = p2[128+lane];
  float s2s = s2*s2;
  float o2 = q0*s2 + q1*s2s + q2*s2s*s2 + reso[n*64 + lane];

  sout[wslot][lane] = o2;
  asm volatile("s_waitcnt lgkmcnt(0)" ::: "memory");

  // ro2 = silu(out2 @ roW1) @ roW2
  int j = lane & 15, g = lane >> 4;
  float qp = 0.f;
  #pragma unroll
  for (int t = 0; t < 16; t++){
    int c = g*16 + t;
    qp += sout[wslot][c] * roW1[c*16 + j];
  }
  qp += __shfl_xor(qp, 16, 64);
  qp += __shfl_xor(qp, 32, 64);
  float sil = qp / (1.f + __expf(-qp));
  float contrib = sil * roW2[j];
  contrib += __shfl_xor(contrib, 1, 64);
  contrib += __shfl_xor(contrib, 2, 64);
  contrib += __shfl_xor(contrib, 4, 64);
  contrib += __shfl_xor(contrib, 8, 64);
  if (lane == 0) out[n*2 + 1] = contrib;
}

extern "C" void kernel_launch(void* const* d_in, const int* in_sizes, int n_in,
                              void* d_out, int out_size, void* d_ws, size_t ws_size,
                              hipStream_t stream)
{
  const float* ev     = (const float*)d_in[0];
  const int*   spec   = (const int*)  d_in[1];
  const int*   send   = (const int*)  d_in[2];
  const int*   recv   = (const int*)  d_in[3];
  const float* embedW = (const float*)d_in[4];
  const float* l1_lin = (const float*)d_in[5];
  const float* l1_rW1 = (const float*)d_in[6];
  const float* l1_rW2 = (const float*)d_in[7];
  const float* l1_sel = (const float*)d_in[8];
  const float* l1_pw  = (const float*)d_in[9];
  const float* l1_uw  = (const float*)d_in[10];
  const float* l1_row = (const float*)d_in[11];
  const float* l2_lin = (const float*)d_in[12];
  const float* l2_rW1 = (const float*)d_in[13];
  const float* l2_rW2 = (const float*)d_in[14];
  const float* l2_res = (const float*)d_in[15];
  const float* l2_pw  = (const float*)d_in[16];
  const float* l2_roW1= (const float*)d_in[17];
  const float* l2_roW2= (const float*)d_in[18];
  float* out = (float*)d_out;

  char* w = (char*)d_ws;
  float2* rw12  = (float2*)w; w += (size_t)N_EDGES*64*8;   // 51.2 MB; phase-1 rwB aliases it
  float*  rwB   = (float*)rw12;
  float*  h1    = (float*)w;  w += (size_t)N_NODES*64*4;
  float4* outvo4= (float4*)w; w += (size_t)N_NODES*64*16;
  float*  reso  = (float*)w;  w += (size_t)N_NODES*64*4;
  float*  selT  = (float*)w;  w += (size_t)NSPEC*4096*4;
  float*  resT  = (float*)w;  w += (size_t)NSPEC*4096*4;
  float4* shu   = (float4*)w; w += (size_t)N_EDGES*16;
  int* starts = (int*)w;      w += (size_t)(N_NODES+1)*4;
  int* cursor = (int*)w;      w += (size_t)N_NODES*4;
  int* elist  = (int*)w;      w += (size_t)N_EDGES*4;

  hipMemsetAsync(cursor, 0, N_NODES*sizeof(int), stream);
  k_count<<<(N_EDGES+255)/256, 256, 0, stream>>>(recv, cursor);
  k_scan <<<1, 256, 0, stream>>>(cursor, starts);
  k_fill <<<(N_EDGES+255)/256, 256, 0, stream>>>(recv, cursor, elist);
  k_trans<<<(NSPEC*4096)/256, 256, 0, stream>>>(l1_sel, l2_res, selT, resT);
  k_h1   <<<(N_NODES*64)/256, 256, 0, stream>>>(spec, embedW, l1_lin, h1);
  k_rw<0><<<(N_EDGES+63)/64, 256, 0, stream>>>(ev, l1_rW1, l1_rW2, rw12, rwB, shu);
  k_node1<<<N_NODES/4, 256, 0, stream>>>(send, spec, starts, elist, shu, rw12, h1,
        selT, l1_pw, l1_uw, l1_row, l2_lin, resT, out, outvo4, reso);
  k_rw<1><<<(N_EDGES+63)/64, 256, 0, stream>>>(ev, l2_rW1, l2_rW2, rw12, rwB, shu);
  k_node2<<<N_NODES/4, 256, 0, stream>>>(send, spec, starts, elist, shu, rwB,
        outvo4, reso, l2_pw, l2_roW1, l2_roW2, out);
}

// Round 5
// 172.744 us; speedup vs baseline: 2.8310x; 1.0203x over previous
//
#include <hip/hip_runtime.h>
#include <hip/hip_bf16.h>
#include <math.h>

#define N_NODES 10000
#define N_EDGES 100000
#define NCH 64
#define NSPEC 10

// ---------- CSR build ----------
__global__ void k_count(const int* __restrict__ recv, int* __restrict__ cnt){
  int i = blockIdx.x*blockDim.x + threadIdx.x;
  if (i < N_EDGES) atomicAdd(&cnt[recv[i]], 1);
}

// coarsened scan: 256 threads, 40 nodes each
__global__ void k_scan(int* __restrict__ cnt_cursor, int* __restrict__ starts){
  __shared__ int stot[256];
  int tid = threadIdx.x;
  int base = tid*40;
  int loc[40];
  int sum = 0;
  #pragma unroll
  for (int j = 0; j < 40; j++){
    int i = base + j;
    int v = (i < N_NODES) ? cnt_cursor[i] : 0;
    loc[j] = sum; sum += v;
  }
  stot[tid] = sum;
  __syncthreads();
  for (int off = 1; off < 256; off <<= 1){
    int t = (tid >= off) ? stot[tid-off] : 0;
    __syncthreads();
    stot[tid] += t;
    __syncthreads();
  }
  int excl = stot[tid] - sum;
  #pragma unroll
  for (int j = 0; j < 40; j++){
    int i = base + j;
    if (i < N_NODES){ int st = excl + loc[j]; starts[i] = st; cnt_cursor[i] = st; }
  }
  if (tid == 255) starts[N_NODES] = stot[255];
}

__global__ void k_fill(const int* __restrict__ recv, int* __restrict__ cursor, int* __restrict__ elist){
  int i = blockIdx.x*blockDim.x + threadIdx.x;
  if (i < N_EDGES){ int pos = atomicAdd(&cursor[recv[i]], 1); elist[pos] = i; }
}

// ---------- weight transposes: T[s][d][c] = W[s][c][d] ----------
__global__ void k_trans(const float* __restrict__ sel, const float* __restrict__ resw,
                        float* __restrict__ selT, float* __restrict__ resT){
  int i = blockIdx.x*blockDim.x + threadIdx.x;          // 10*4096
  int s = i >> 12, r = i & 4095, d = r >> 6, c = r & 63;
  int src = s*4096 + c*64 + d;
  selT[i] = sel[src];
  resT[i] = resw[src];
}

// ---------- h1 = embed[species] @ l1_lin_up ----------
__global__ void k_h1(const int* __restrict__ species, const float* __restrict__ embedW,
                     const float* __restrict__ linup, float* __restrict__ h1){
  int w = (blockIdx.x*blockDim.x + threadIdx.x) >> 6;
  int lane = threadIdx.x & 63;
  if (w >= N_NODES) return;
  int sp = __builtin_amdgcn_readfirstlane(species[w]);
  const float* x0 = embedW + sp*NCH;
  float acc = 0.f;
  #pragma unroll
  for (int d = 0; d < NCH; d++) acc += x0[d] * linup[d*NCH + lane];
  h1[w*NCH + lane] = acc;
}

// ---------- tiled radial GEMM: 64-edge tile per 256-thread block ----------
// PHASE 0: rw12[e][c] = (col 4c, col 4c+1) of silu(bessel@rW1)@rW2, + shu[e]
// PHASE 1: rwB[e][c]  =  col 4c
// LDS = s_hidT only (17.4 KB): w2 stays in registers (16-h chunks), rad recomputed per h-group.
template<int PHASE>
__global__ __launch_bounds__(256) void k_rw(
    const float* __restrict__ ev,
    const float* __restrict__ rW1,
    const float* __restrict__ rW2,
    float2* __restrict__ rw12,
    float*  __restrict__ rwB,
    float4* __restrict__ shu)
{
  __shared__ float s_hidT[64*68];      // [h][e], pad 68 (rows stay 16B-aligned)

  int tid = threadIdx.x;
  int e0 = blockIdx.x*64;
  int el = tid & 63;
  int hg = __builtin_amdgcn_readfirstlane(tid >> 6);   // 0..3, wave-uniform

  // geometry (4-way redundant across h-groups; kills s_rad + one sync)
  int e = e0 + el;
  bool act = (e < N_EDGES);
  float ex = 0.f, ey = 0.f, ez = 1.f;
  if (act){ ex = ev[e*3+0]; ey = ev[e*3+1]; ez = ev[e*3+2]; }
  float r = sqrtf(ex*ex + ey*ey + ez*ez + 1e-12f);
  float rinv = 1.0f / r;
  float u = r * 0.2f;
  float env = 0.f;
  if (u < 1.f){ float om = 1.f - u; env = om*om*(1.f + 2.f*u); }
  float pref = 0.6324555320336759f * rinv * env;       // sqrt(2/5)
  float rad[8];
  #pragma unroll
  for (int b = 0; b < 8; b++)
    rad[b] = pref * __sinf((float)(b+1) * 3.14159265358979f * u);
  if (PHASE == 0 && hg == 0 && act) shu[e] = make_float4(ex*rinv, ey*rinv, ez*rinv, 0.f);

  // hid for this group's 16 h, stored transposed
  #pragma unroll
  for (int j = 0; j < 16; j++){
    int h = hg*16 + j;
    float ah = 0.f;
    #pragma unroll
    for (int b = 0; b < 8; b++) ah += rad[b] * rW1[b*64 + h];   // wave-uniform -> s_load
    s_hidT[h*68 + el] = ah / (1.f + __expf(-ah));               // stride-1: conflict-free
  }
  __syncthreads();

  // GEMM: thread (c = tid&63, eg) -> 16 edges x col(s); w2 in regs per 16-h chunk
  int c = el;
  int eg = hg;
  if (PHASE == 0){
    float2 acc[16];
    #pragma unroll
    for (int j = 0; j < 16; j++) acc[j] = make_float2(0.f, 0.f);
    #pragma unroll 1
    for (int hc = 0; hc < 4; hc++){
      float2 wreg[16];
      #pragma unroll
      for (int j = 0; j < 16; j++)
        wreg[j] = *reinterpret_cast<const float2*>(rW2 + (hc*16+j)*256 + 4*c);
      #pragma unroll
      for (int j = 0; j < 16; j++){
        int h = hc*16 + j;
        const float4* hp = (const float4*)(s_hidT + h*68 + eg*16);  // uniform broadcast
        float hv[16];
        *(float4*)&hv[0]  = hp[0];
        *(float4*)&hv[4]  = hp[1];
        *(float4*)&hv[8]  = hp[2];
        *(float4*)&hv[12] = hp[3];
        #pragma unroll
        for (int i = 0; i < 16; i++){
          acc[i].x += hv[i]*wreg[j].x;
          acc[i].y += hv[i]*wreg[j].y;
        }
      }
    }
    #pragma unroll
    for (int j = 0; j < 16; j++){
      int er = e0 + eg*16 + j;
      if (er < N_EDGES) rw12[(size_t)er*64 + c] = acc[j];
    }
  } else {
    float acc[16];
    #pragma unroll
    for (int j = 0; j < 16; j++) acc[j] = 0.f;
    #pragma unroll 1
    for (int hc = 0; hc < 4; hc++){
      float wreg[16];
      #pragma unroll
      for (int j = 0; j < 16; j++)
        wreg[j] = rW2[(hc*16+j)*256 + 4*c];
      #pragma unroll
      for (int j = 0; j < 16; j++){
        int h = hc*16 + j;
        const float4* hp = (const float4*)(s_hidT + h*68 + eg*16);
        float hv[16];
        *(float4*)&hv[0]  = hp[0];
        *(float4*)&hv[4]  = hp[1];
        *(float4*)&hv[8]  = hp[2];
        *(float4*)&hv[12] = hp[3];
        #pragma unroll
        for (int i = 0; i < 16; i++) acc[i] += hv[i]*wreg[j];
      }
    }
    #pragma unroll
    for (int j = 0; j < 16; j++){
      int er = e0 + eg*16 + j;
      if (er < N_EDGES) rwB[(size_t)er*64 + c] = acc[j];
    }
  }
}

// ---------- pass-1 gather + node transforms (1 wave per node, no weights) ----------
__global__ __launch_bounds__(256) void k_node1(
  const int* __restrict__ senders, const int* __restrict__ species,
  const int* __restrict__ starts, const int* __restrict__ elist,
  const float4* __restrict__ shu,
  const float2* __restrict__ rw12, const float* __restrict__ h1,
  const float* __restrict__ selT,
  const float* __restrict__ pw, const float* __restrict__ uwv,
  const float* __restrict__ row,
  const float* __restrict__ linup2, const float* __restrict__ resT,
  float* __restrict__ out,
  float4* __restrict__ outvo4, float* __restrict__ reso)
{
  int lane  = threadIdx.x & 63;
  int wslot = threadIdx.x >> 6;
  int n = blockIdx.x*4 + wslot;          // grid exact: 2500*4 = 10000
  __shared__ float4 sacc[4][64];

  int s0 = __builtin_amdgcn_readfirstlane(starts[n]);
  int s1 = __builtin_amdgcn_readfirstlane(starts[n+1]);
  int sp = __builtin_amdgcn_readfirstlane(species[n]);

  float acc0 = 0.f, acc1 = 0.f, acc2 = 0.f, acc3 = 0.f;
  for (int base = s0; base < s1; base += 64){
    int m = min(64, s1 - base);
    int e_l = 0, snd_l = 0;
    if (lane < m){
      e_l   = elist[base + lane];
      snd_l = senders[e_l];
    }
    int t = 0;
    for (; t+2 <= m; t += 2){
      int ea = __builtin_amdgcn_readfirstlane(__shfl(e_l, t, 64));
      int sa = __builtin_amdgcn_readfirstlane(__shfl(snd_l, t, 64));
      int eb = __builtin_amdgcn_readfirstlane(__shfl(e_l, t+1, 64));
      int sb = __builtin_amdgcn_readfirstlane(__shfl(snd_l, t+1, 64));
      float2 rva = rw12[(size_t)ea*64 + lane];
      float  h1a = h1[sa*64 + lane];
      float4 sva = shu[ea];
      float2 rvb = rw12[(size_t)eb*64 + lane];
      float  h1b = h1[sb*64 + lane];
      float4 svb = shu[eb];
      acc0 += rva.x * h1a;
      float ma = rva.y * h1a;
      acc1 += ma*sva.x; acc2 += ma*sva.y; acc3 += ma*sva.z;
      acc0 += rvb.x * h1b;
      float mb = rvb.y * h1b;
      acc1 += mb*svb.x; acc2 += mb*svb.y; acc3 += mb*svb.z;
    }
    if (t < m){
      int ea = __builtin_amdgcn_readfirstlane(__shfl(e_l, t, 64));
      int sa = __builtin_amdgcn_readfirstlane(__shfl(snd_l, t, 64));
      float2 rva = rw12[(size_t)ea*64 + lane];
      float  h1a = h1[sa*64 + lane];
      float4 sva = shu[ea];
      acc0 += rva.x * h1a;
      float ma = rva.y * h1a;
      acc1 += ma*sva.x; acc2 += ma*sva.y; acc3 += ma*sva.z;
    }
  }
  const float c10 = 0.1f;                      // 1/AVG_NEIGH
  const float c13 = 0.17320508075688773f;      // sqrt(3)/10
  sacc[wslot][lane] = make_float4(acc0*c10, acc1*c13, acc2*c13, acc3*c13);
  asm volatile("s_waitcnt lgkmcnt(0)" ::: "memory");

  // feats[c,k] = sum_d selW[c,d] * agg[d,k]
  const float* selp = selT + sp*4096;
  float f0 = 0.f, f1 = 0.f, f2 = 0.f, f3 = 0.f;
  #pragma unroll 8
  for (int d = 0; d < 64; d++){
    float wv = selp[d*64 + lane];
    float4 a = sacc[wslot][d];
    f0 += wv*a.x; f1 += wv*a.y; f2 += wv*a.z; f3 += wv*a.w;
  }

  float s = f0;
  const float* pwp = pw  + sp*192;
  const float* uwp = uwv + sp*192;
  float pw0 = pwp[lane], pw1 = pwp[64+lane], pw2 = pwp[128+lane];
  float uw0 = uwp[lane], uw1 = uwp[64+lane], uw2 = uwp[128+lane];
  float ss = s*s;
  float o0  = pw0*s + pw1*ss + pw2*ss*s;
  float uco = uw0 + uw1*s + uw2*ss;

  // ro1 = sum_c o0[c]*row[c]
  float rv = o0 * row[lane];
  #pragma unroll
  for (int off = 32; off >= 1; off >>= 1) rv += __shfl_xor(rv, off, 64);
  if (lane == 0) out[n*2 + 0] = rv;

  // stage o0, compute h2 and res
  float* so = reinterpret_cast<float*>(&sacc[wslot][0]);
  asm volatile("s_waitcnt lgkmcnt(0)" ::: "memory");
  so[lane] = o0;
  asm volatile("s_waitcnt lgkmcnt(0)" ::: "memory");

  float hh = 0.f, rr = 0.f;
  const float* resp = resT + sp*4096;
  #pragma unroll 8
  for (int d = 0; d < 64; d++){
    float od = so[d];
    hh += od * linup2[d*64 + lane];
    rr += od * resp[d*64 + lane];
  }
  outvo4[n*64 + lane] = make_float4(uco*f1, uco*f2, uco*f3, hh);  // .w = h2
  reso[n*64 + lane] = rr;
}

// ---------- pass-2 gather + readout (1 wave per node) ----------
__global__ __launch_bounds__(256) void k_node2(
  const int* __restrict__ senders, const int* __restrict__ species,
  const int* __restrict__ starts, const int* __restrict__ elist,
  const float4* __restrict__ shu,
  const float* __restrict__ rwB,
  const float4* __restrict__ outvo4, const float* __restrict__ reso,
  const float* __restrict__ pw2,
  const float* __restrict__ roW1, const float* __restrict__ roW2,
  float* __restrict__ out)
{
  int lane  = threadIdx.x & 63;
  int wslot = threadIdx.x >> 6;
  int n = blockIdx.x*4 + wslot;
  __shared__ float sout[4][64];

  int s0 = __builtin_amdgcn_readfirstlane(starts[n]);
  int s1 = __builtin_amdgcn_readfirstlane(starts[n+1]);
  int sp = __builtin_amdgcn_readfirstlane(species[n]);

  float acc = 0.f;
  for (int base = s0; base < s1; base += 64){
    int m = min(64, s1 - base);
    int e_l = 0, snd_l = 0;
    if (lane < m){
      e_l   = elist[base + lane];
      snd_l = senders[e_l];
    }
    int t = 0;
    for (; t+2 <= m; t += 2){
      int ea = __builtin_amdgcn_readfirstlane(__shfl(e_l, t, 64));
      int sa = __builtin_amdgcn_readfirstlane(__shfl(snd_l, t, 64));
      int eb = __builtin_amdgcn_readfirstlane(__shfl(e_l, t+1, 64));
      int sb = __builtin_amdgcn_readfirstlane(__shfl(snd_l, t+1, 64));
      float rwa = rwB[(size_t)ea*64 + lane];
      float4 ova = outvo4[sa*64 + lane];
      float4 sva = shu[ea];
      float rwb = rwB[(size_t)eb*64 + lane];
      float4 ovb = outvo4[sb*64 + lane];
      float4 svb = shu[eb];
      acc += rwa * (ova.w + ova.x*sva.x + ova.y*sva.y + ova.z*sva.z);
      acc += rwb * (ovb.w + ovb.x*svb.x + ovb.y*svb.y + ovb.z*svb.z);
    }
    if (t < m){
      int ea = __builtin_amdgcn_readfirstlane(__shfl(e_l, t, 64));
      int sa = __builtin_amdgcn_readfirstlane(__shfl(snd_l, t, 64));
      float rwa = rwB[(size_t)ea*64 + lane];
      float4 ova = outvo4[sa*64 + lane];
      float4 sva = shu[ea];
      acc += rwa * (ova.w + ova.x*sva.x + ova.y*sva.y + ova.z*sva.z);
    }
  }
  float s2 = acc * 0.1f;
  const float* p2 = pw2 + sp*192;
  float q0 = p2[lane], q1 = p2[64+lane], q2 = p2[128+lane];
  float s2s = s2*s2;
  float o2 = q0*s2 + q1*s2s + q2*s2s*s2 + reso[n*64 + lane];

  sout[wslot][lane] = o2;
  asm volatile("s_waitcnt lgkmcnt(0)" ::: "memory");

  // ro2 = silu(out2 @ roW1) @ roW2
  int j = lane & 15, g = lane >> 4;
  float qp = 0.f;
  #pragma unroll
  for (int t = 0; t < 16; t++){
    int c = g*16 + t;
    qp += sout[wslot][c] * roW1[c*16 + j];
  }
  qp += __shfl_xor(qp, 16, 64);
  qp += __shfl_xor(qp, 32, 64);
  float sil = qp / (1.f + __expf(-qp));
  float contrib = sil * roW2[j];
  contrib += __shfl_xor(contrib, 1, 64);
  contrib += __shfl_xor(contrib, 2, 64);
  contrib += __shfl_xor(contrib, 4, 64);
  contrib += __shfl_xor(contrib, 8, 64);
  if (lane == 0) out[n*2 + 1] = contrib;
}

extern "C" void kernel_launch(void* const* d_in, const int* in_sizes, int n_in,
                              void* d_out, int out_size, void* d_ws, size_t ws_size,
                              hipStream_t stream)
{
  const float* ev     = (const float*)d_in[0];
  const int*   spec   = (const int*)  d_in[1];
  const int*   send   = (const int*)  d_in[2];
  const int*   recv   = (const int*)  d_in[3];
  const float* embedW = (const float*)d_in[4];
  const float* l1_lin = (const float*)d_in[5];
  const float* l1_rW1 = (const float*)d_in[6];
  const float* l1_rW2 = (const float*)d_in[7];
  const float* l1_sel = (const float*)d_in[8];
  const float* l1_pw  = (const float*)d_in[9];
  const float* l1_uw  = (const float*)d_in[10];
  const float* l1_row = (const float*)d_in[11];
  const float* l2_lin = (const float*)d_in[12];
  const float* l2_rW1 = (const float*)d_in[13];
  const float* l2_rW2 = (const float*)d_in[14];
  const float* l2_res = (const float*)d_in[15];
  const float* l2_pw  = (const float*)d_in[16];
  const float* l2_roW1= (const float*)d_in[17];
  const float* l2_roW2= (const float*)d_in[18];
  float* out = (float*)d_out;

  char* w = (char*)d_ws;
  float2* rw12  = (float2*)w; w += (size_t)N_EDGES*64*8;   // 51.2 MB; phase-1 rwB aliases it
  float*  rwB   = (float*)rw12;
  float*  h1    = (float*)w;  w += (size_t)N_NODES*64*4;
  float4* outvo4= (float4*)w; w += (size_t)N_NODES*64*16;
  float*  reso  = (float*)w;  w += (size_t)N_NODES*64*4;
  float*  selT  = (float*)w;  w += (size_t)NSPEC*4096*4;
  float*  resT  = (float*)w;  w += (size_t)NSPEC*4096*4;
  float4* shu   = (float4*)w; w += (size_t)N_EDGES*16;
  int* starts = (int*)w;      w += (size_t)(N_NODES+1)*4;
  int* cursor = (int*)w;      w += (size_t)N_NODES*4;
  int* elist  = (int*)w;      w += (size_t)N_EDGES*4;

  hipMemsetAsync(cursor, 0, N_NODES*sizeof(int), stream);
  k_count<<<(N_EDGES+255)/256, 256, 0, stream>>>(recv, cursor);
  k_scan <<<1, 256, 0, stream>>>(cursor, starts);
  k_fill <<<(N_EDGES+255)/256, 256, 0, stream>>>(recv, cursor, elist);
  k_trans<<<(NSPEC*4096)/256, 256, 0, stream>>>(l1_sel, l2_res, selT, resT);
  k_h1   <<<(N_NODES*64)/256, 256, 0, stream>>>(spec, embedW, l1_lin, h1);
  k_rw<0><<<(N_EDGES+63)/64, 256, 0, stream>>>(ev, l1_rW1, l1_rW2, rw12, rwB, shu);
  k_node1<<<N_NODES/4, 256, 0, stream>>>(send, spec, starts, elist, shu, rw12, h1,
        selT, l1_pw, l1_uw, l1_row, l2_lin, resT, out, outvo4, reso);
  k_rw<1><<<(N_EDGES+63)/64, 256, 0, stream>>>(ev, l2_rW1, l2_rW2, rw12, rwB, shu);
  k_node2<<<N_NODES/4, 256, 0, stream>>>(send, spec, starts, elist, shu, rwB,
        outvo4, reso, l2_pw, l2_roW1, l2_roW2, out);
}

// Round 6
// 169.288 us; speedup vs baseline: 2.8888x; 1.0204x over previous
//
#include <hip/hip_runtime.h>
#include <hip/hip_bf16.h>
#include <math.h>

#define N_NODES 10000
#define N_EDGES 100000
#define NCH 64
#define NSPEC 10

// ---------- zero cursor (replaces 42us fillBufferAligned) ----------
__global__ void k_zero(int* __restrict__ cursor){
  int i = blockIdx.x*blockDim.x + threadIdx.x;
  if (i < N_NODES) cursor[i] = 0;
}

// ---------- CSR build ----------
__global__ void k_count(const int* __restrict__ recv, int* __restrict__ cnt){
  int i = blockIdx.x*blockDim.x + threadIdx.x;
  if (i < N_EDGES) atomicAdd(&cnt[recv[i]], 1);
}

// coarsened scan: 256 threads, 40 nodes each
__global__ void k_scan(int* __restrict__ cnt_cursor, int* __restrict__ starts){
  __shared__ int stot[256];
  int tid = threadIdx.x;
  int base = tid*40;
  int loc[40];
  int sum = 0;
  #pragma unroll
  for (int j = 0; j < 40; j++){
    int i = base + j;
    int v = (i < N_NODES) ? cnt_cursor[i] : 0;
    loc[j] = sum; sum += v;
  }
  stot[tid] = sum;
  __syncthreads();
  for (int off = 1; off < 256; off <<= 1){
    int t = (tid >= off) ? stot[tid-off] : 0;
    __syncthreads();
    stot[tid] += t;
    __syncthreads();
  }
  int excl = stot[tid] - sum;
  #pragma unroll
  for (int j = 0; j < 40; j++){
    int i = base + j;
    if (i < N_NODES){ int st = excl + loc[j]; starts[i] = st; cnt_cursor[i] = st; }
  }
  if (tid == 255) starts[N_NODES] = stot[255];
}

__global__ void k_fill(const int* __restrict__ recv, int* __restrict__ cursor, int* __restrict__ elist){
  int i = blockIdx.x*blockDim.x + threadIdx.x;
  if (i < N_EDGES){ int pos = atomicAdd(&cursor[recv[i]], 1); elist[pos] = i; }
}

// ---------- weight transposes: T[s][d][c] = W[s][c][d] ----------
__global__ void k_trans(const float* __restrict__ sel, const float* __restrict__ resw,
                        float* __restrict__ selT, float* __restrict__ resT){
  int i = blockIdx.x*blockDim.x + threadIdx.x;          // 10*4096
  int s = i >> 12, r = i & 4095, d = r >> 6, c = r & 63;
  int src = s*4096 + c*64 + d;
  selT[i] = sel[src];
  resT[i] = resw[src];
}

// ---------- h1 = embed[species] @ l1_lin_up ----------
__global__ void k_h1(const int* __restrict__ species, const float* __restrict__ embedW,
                     const float* __restrict__ linup, float* __restrict__ h1){
  int w = (blockIdx.x*blockDim.x + threadIdx.x) >> 6;
  int lane = threadIdx.x & 63;
  if (w >= N_NODES) return;
  int sp = __builtin_amdgcn_readfirstlane(species[w]);
  const float* x0 = embedW + sp*NCH;
  float acc = 0.f;
  #pragma unroll
  for (int d = 0; d < NCH; d++) acc += x0[d] * linup[d*NCH + lane];
  h1[w*NCH + lane] = acc;
}

// ---------- tiled radial GEMM: 64-edge tile per 256-thread block ----------
// PHASE 0: rw12[e][c] = (col 4c, col 4c+1) of silu(bessel@rW1)@rW2, + shu[e]
// PHASE 1: rwB[e][c]  =  col 4c
// LDS = s_hidT only (17.4 KB): w2 stays in registers (16-h chunks), rad recomputed per h-group.
template<int PHASE>
__global__ __launch_bounds__(256) void k_rw(
    const float* __restrict__ ev,
    const float* __restrict__ rW1,
    const float* __restrict__ rW2,
    float2* __restrict__ rw12,
    float*  __restrict__ rwB,
    float4* __restrict__ shu)
{
  __shared__ float s_hidT[64*68];      // [h][e], pad 68 (rows stay 16B-aligned)

  int tid = threadIdx.x;
  int e0 = blockIdx.x*64;
  int el = tid & 63;
  int hg = __builtin_amdgcn_readfirstlane(tid >> 6);   // 0..3, wave-uniform

  // geometry (4-way redundant across h-groups; kills s_rad + one sync)
  int e = e0 + el;
  bool act = (e < N_EDGES);
  float ex = 0.f, ey = 0.f, ez = 1.f;
  if (act){ ex = ev[e*3+0]; ey = ev[e*3+1]; ez = ev[e*3+2]; }
  float r = sqrtf(ex*ex + ey*ey + ez*ez + 1e-12f);
  float rinv = 1.0f / r;
  float u = r * 0.2f;
  float env = 0.f;
  if (u < 1.f){ float om = 1.f - u; env = om*om*(1.f + 2.f*u); }
  float pref = 0.6324555320336759f * rinv * env;       // sqrt(2/5)
  float rad[8];
  #pragma unroll
  for (int b = 0; b < 8; b++)
    rad[b] = pref * __sinf((float)(b+1) * 3.14159265358979f * u);
  if (PHASE == 0 && hg == 0 && act) shu[e] = make_float4(ex*rinv, ey*rinv, ez*rinv, 0.f);

  // hid for this group's 16 h, stored transposed
  #pragma unroll
  for (int j = 0; j < 16; j++){
    int h = hg*16 + j;
    float ah = 0.f;
    #pragma unroll
    for (int b = 0; b < 8; b++) ah += rad[b] * rW1[b*64 + h];   // wave-uniform -> s_load
    s_hidT[h*68 + el] = ah / (1.f + __expf(-ah));               // stride-1: conflict-free
  }
  __syncthreads();

  // GEMM: thread (c = tid&63, eg) -> 16 edges x col(s); w2 in regs per 16-h chunk
  int c = el;
  int eg = hg;
  if (PHASE == 0){
    float2 acc[16];
    #pragma unroll
    for (int j = 0; j < 16; j++) acc[j] = make_float2(0.f, 0.f);
    #pragma unroll 1
    for (int hc = 0; hc < 4; hc++){
      float2 wreg[16];
      #pragma unroll
      for (int j = 0; j < 16; j++)
        wreg[j] = *reinterpret_cast<const float2*>(rW2 + (hc*16+j)*256 + 4*c);
      #pragma unroll
      for (int j = 0; j < 16; j++){
        int h = hc*16 + j;
        const float4* hp = (const float4*)(s_hidT + h*68 + eg*16);  // uniform broadcast
        float hv[16];
        *(float4*)&hv[0]  = hp[0];
        *(float4*)&hv[4]  = hp[1];
        *(float4*)&hv[8]  = hp[2];
        *(float4*)&hv[12] = hp[3];
        #pragma unroll
        for (int i = 0; i < 16; i++){
          acc[i].x += hv[i]*wreg[j].x;
          acc[i].y += hv[i]*wreg[j].y;
        }
      }
    }
    #pragma unroll
    for (int j = 0; j < 16; j++){
      int er = e0 + eg*16 + j;
      if (er < N_EDGES) rw12[(size_t)er*64 + c] = acc[j];
    }
  } else {
    float acc[16];
    #pragma unroll
    for (int j = 0; j < 16; j++) acc[j] = 0.f;
    #pragma unroll 1
    for (int hc = 0; hc < 4; hc++){
      float wreg[16];
      #pragma unroll
      for (int j = 0; j < 16; j++)
        wreg[j] = rW2[(hc*16+j)*256 + 4*c];
      #pragma unroll
      for (int j = 0; j < 16; j++){
        int h = hc*16 + j;
        const float4* hp = (const float4*)(s_hidT + h*68 + eg*16);
        float hv[16];
        *(float4*)&hv[0]  = hp[0];
        *(float4*)&hv[4]  = hp[1];
        *(float4*)&hv[8]  = hp[2];
        *(float4*)&hv[12] = hp[3];
        #pragma unroll
        for (int i = 0; i < 16; i++) acc[i] += hv[i]*wreg[j];
      }
    }
    #pragma unroll
    for (int j = 0; j < 16; j++){
      int er = e0 + eg*16 + j;
      if (er < N_EDGES) rwB[(size_t)er*64 + c] = acc[j];
    }
  }
}

// ---------- pass-1 gather + node transforms (1 wave per node, no weights) ----------
__global__ __launch_bounds__(256) void k_node1(
  const int* __restrict__ senders, const int* __restrict__ species,
  const int* __restrict__ starts, const int* __restrict__ elist,
  const float4* __restrict__ shu,
  const float2* __restrict__ rw12, const float* __restrict__ h1,
  const float* __restrict__ selT,
  const float* __restrict__ pw, const float* __restrict__ uwv,
  const float* __restrict__ row,
  const float* __restrict__ linup2, const float* __restrict__ resT,
  float* __restrict__ out,
  float4* __restrict__ outvo4, float* __restrict__ reso)
{
  int lane  = threadIdx.x & 63;
  int wslot = threadIdx.x >> 6;
  int n = blockIdx.x*4 + wslot;          // grid exact: 2500*4 = 10000
  __shared__ float4 sacc[4][64];

  int s0 = __builtin_amdgcn_readfirstlane(starts[n]);
  int s1 = __builtin_amdgcn_readfirstlane(starts[n+1]);
  int sp = __builtin_amdgcn_readfirstlane(species[n]);

  float acc0 = 0.f, acc1 = 0.f, acc2 = 0.f, acc3 = 0.f;
  for (int base = s0; base < s1; base += 64){
    int m = min(64, s1 - base);
    int e_l = 0, snd_l = 0;
    if (lane < m){
      e_l   = elist[base + lane];
      snd_l = senders[e_l];
    }
    int t = 0;
    for (; t+2 <= m; t += 2){
      int ea = __builtin_amdgcn_readfirstlane(__shfl(e_l, t, 64));
      int sa = __builtin_amdgcn_readfirstlane(__shfl(snd_l, t, 64));
      int eb = __builtin_amdgcn_readfirstlane(__shfl(e_l, t+1, 64));
      int sb = __builtin_amdgcn_readfirstlane(__shfl(snd_l, t+1, 64));
      float2 rva = rw12[(size_t)ea*64 + lane];
      float  h1a = h1[sa*64 + lane];
      float4 sva = shu[ea];
      float2 rvb = rw12[(size_t)eb*64 + lane];
      float  h1b = h1[sb*64 + lane];
      float4 svb = shu[eb];
      acc0 += rva.x * h1a;
      float ma = rva.y * h1a;
      acc1 += ma*sva.x; acc2 += ma*sva.y; acc3 += ma*sva.z;
      acc0 += rvb.x * h1b;
      float mb = rvb.y * h1b;
      acc1 += mb*svb.x; acc2 += mb*svb.y; acc3 += mb*svb.z;
    }
    if (t < m){
      int ea = __builtin_amdgcn_readfirstlane(__shfl(e_l, t, 64));
      int sa = __builtin_amdgcn_readfirstlane(__shfl(snd_l, t, 64));
      float2 rva = rw12[(size_t)ea*64 + lane];
      float  h1a = h1[sa*64 + lane];
      float4 sva = shu[ea];
      acc0 += rva.x * h1a;
      float ma = rva.y * h1a;
      acc1 += ma*sva.x; acc2 += ma*sva.y; acc3 += ma*sva.z;
    }
  }
  const float c10 = 0.1f;                      // 1/AVG_NEIGH
  const float c13 = 0.17320508075688773f;      // sqrt(3)/10
  sacc[wslot][lane] = make_float4(acc0*c10, acc1*c13, acc2*c13, acc3*c13);
  asm volatile("s_waitcnt lgkmcnt(0)" ::: "memory");

  // feats[c,k] = sum_d selW[c,d] * agg[d,k]
  const float* selp = selT + sp*4096;
  float f0 = 0.f, f1 = 0.f, f2 = 0.f, f3 = 0.f;
  #pragma unroll 8
  for (int d = 0; d < 64; d++){
    float wv = selp[d*64 + lane];
    float4 a = sacc[wslot][d];
    f0 += wv*a.x; f1 += wv*a.y; f2 += wv*a.z; f3 += wv*a.w;
  }

  float s = f0;
  const float* pwp = pw  + sp*192;
  const float* uwp = uwv + sp*192;
  float pw0 = pwp[lane], pw1 = pwp[64+lane], pw2 = pwp[128+lane];
  float uw0 = uwp[lane], uw1 = uwp[64+lane], uw2 = uwp[128+lane];
  float ss = s*s;
  float o0  = pw0*s + pw1*ss + pw2*ss*s;
  float uco = uw0 + uw1*s + uw2*ss;

  // ro1 = sum_c o0[c]*row[c]
  float rv = o0 * row[lane];
  #pragma unroll
  for (int off = 32; off >= 1; off >>= 1) rv += __shfl_xor(rv, off, 64);
  if (lane == 0) out[n*2 + 0] = rv;

  // stage o0, compute h2 and res
  float* so = reinterpret_cast<float*>(&sacc[wslot][0]);
  asm volatile("s_waitcnt lgkmcnt(0)" ::: "memory");
  so[lane] = o0;
  asm volatile("s_waitcnt lgkmcnt(0)" ::: "memory");

  float hh = 0.f, rr = 0.f;
  const float* resp = resT + sp*4096;
  #pragma unroll 8
  for (int d = 0; d < 64; d++){
    float od = so[d];
    hh += od * linup2[d*64 + lane];
    rr += od * resp[d*64 + lane];
  }
  outvo4[n*64 + lane] = make_float4(uco*f1, uco*f2, uco*f3, hh);  // .w = h2
  reso[n*64 + lane] = rr;
}

// ---------- pass-2 gather + readout (1 wave per node) ----------
__global__ __launch_bounds__(256) void k_node2(
  const int* __restrict__ senders, const int* __restrict__ species,
  const int* __restrict__ starts, const int* __restrict__ elist,
  const float4* __restrict__ shu,
  const float* __restrict__ rwB,
  const float4* __restrict__ outvo4, const float* __restrict__ reso,
  const float* __restrict__ pw2,
  const float* __restrict__ roW1, const float* __restrict__ roW2,
  float* __restrict__ out)
{
  int lane  = threadIdx.x & 63;
  int wslot = threadIdx.x >> 6;
  int n = blockIdx.x*4 + wslot;
  __shared__ float sout[4][64];

  int s0 = __builtin_amdgcn_readfirstlane(starts[n]);
  int s1 = __builtin_amdgcn_readfirstlane(starts[n+1]);
  int sp = __builtin_amdgcn_readfirstlane(species[n]);

  float acc = 0.f;
  for (int base = s0; base < s1; base += 64){
    int m = min(64, s1 - base);
    int e_l = 0, snd_l = 0;
    if (lane < m){
      e_l   = elist[base + lane];
      snd_l = senders[e_l];
    }
    int t = 0;
    for (; t+2 <= m; t += 2){
      int ea = __builtin_amdgcn_readfirstlane(__shfl(e_l, t, 64));
      int sa = __builtin_amdgcn_readfirstlane(__shfl(snd_l, t, 64));
      int eb = __builtin_amdgcn_readfirstlane(__shfl(e_l, t+1, 64));
      int sb = __builtin_amdgcn_readfirstlane(__shfl(snd_l, t+1, 64));
      float rwa = rwB[(size_t)ea*64 + lane];
      float4 ova = outvo4[sa*64 + lane];
      float4 sva = shu[ea];
      float rwb = rwB[(size_t)eb*64 + lane];
      float4 ovb = outvo4[sb*64 + lane];
      float4 svb = shu[eb];
      acc += rwa * (ova.w + ova.x*sva.x + ova.y*sva.y + ova.z*sva.z);
      acc += rwb * (ovb.w + ovb.x*svb.x + ovb.y*svb.y + ovb.z*svb.z);
    }
    if (t < m){
      int ea = __builtin_amdgcn_readfirstlane(__shfl(e_l, t, 64));
      int sa = __builtin_amdgcn_readfirstlane(__shfl(snd_l, t, 64));
      float rwa = rwB[(size_t)ea*64 + lane];
      float4 ova = outvo4[sa*64 + lane];
      float4 sva = shu[ea];
      acc += rwa * (ova.w + ova.x*sva.x + ova.y*sva.y + ova.z*sva.z);
    }
  }
  float s2 = acc * 0.1f;
  const float* p2 = pw2 + sp*192;
  float q0 = p2[lane], q1 = p2[64+lane], q2 = p2[128+lane];
  float s2s = s2*s2;
  float o2 = q0*s2 + q1*s2s + q2*s2s*s2 + reso[n*64 + lane];

  sout[wslot][lane] = o2;
  asm volatile("s_waitcnt lgkmcnt(0)" ::: "memory");

  // ro2 = silu(out2 @ roW1) @ roW2
  int j = lane & 15, g = lane >> 4;
  float qp = 0.f;
  #pragma unroll
  for (int t = 0; t < 16; t++){
    int c = g*16 + t;
    qp += sout[wslot][c] * roW1[c*16 + j];
  }
  qp += __shfl_xor(qp, 16, 64);
  qp += __shfl_xor(qp, 32, 64);
  float sil = qp / (1.f + __expf(-qp));
  float contrib = sil * roW2[j];
  contrib += __shfl_xor(contrib, 1, 64);
  contrib += __shfl_xor(contrib, 2, 64);
  contrib += __shfl_xor(contrib, 4, 64);
  contrib += __shfl_xor(contrib, 8, 64);
  if (lane == 0) out[n*2 + 1] = contrib;
}

extern "C" void kernel_launch(void* const* d_in, const int* in_sizes, int n_in,
                              void* d_out, int out_size, void* d_ws, size_t ws_size,
                              hipStream_t stream)
{
  const float* ev     = (const float*)d_in[0];
  const int*   spec   = (const int*)  d_in[1];
  const int*   send   = (const int*)  d_in[2];
  const int*   recv   = (const int*)  d_in[3];
  const float* embedW = (const float*)d_in[4];
  const float* l1_lin = (const float*)d_in[5];
  const float* l1_rW1 = (const float*)d_in[6];
  const float* l1_rW2 = (const float*)d_in[7];
  const float* l1_sel = (const float*)d_in[8];
  const float* l1_pw  = (const float*)d_in[9];
  const float* l1_uw  = (const float*)d_in[10];
  const float* l1_row = (const float*)d_in[11];
  const float* l2_lin = (const float*)d_in[12];
  const float* l2_rW1 = (const float*)d_in[13];
  const float* l2_rW2 = (const float*)d_in[14];
  const float* l2_res = (const float*)d_in[15];
  const float* l2_pw  = (const float*)d_in[16];
  const float* l2_roW1= (const float*)d_in[17];
  const float* l2_roW2= (const float*)d_in[18];
  float* out = (float*)d_out;

  char* w = (char*)d_ws;
  float2* rw12  = (float2*)w; w += (size_t)N_EDGES*64*8;   // 51.2 MB; phase-1 rwB aliases it
  float*  rwB   = (float*)rw12;
  float*  h1    = (float*)w;  w += (size_t)N_NODES*64*4;
  float4* outvo4= (float4*)w; w += (size_t)N_NODES*64*16;
  float*  reso  = (float*)w;  w += (size_t)N_NODES*64*4;
  float*  selT  = (float*)w;  w += (size_t)NSPEC*4096*4;
  float*  resT  = (float*)w;  w += (size_t)NSPEC*4096*4;
  float4* shu   = (float4*)w; w += (size_t)N_EDGES*16;
  int* starts = (int*)w;      w += (size_t)(N_NODES+1)*4;
  int* cursor = (int*)w;      w += (size_t)N_NODES*4;
  int* elist  = (int*)w;      w += (size_t)N_EDGES*4;

  k_zero <<<(N_NODES+255)/256, 256, 0, stream>>>(cursor);
  k_count<<<(N_EDGES+255)/256, 256, 0, stream>>>(recv, cursor);
  k_scan <<<1, 256, 0, stream>>>(cursor, starts);
  k_fill <<<(N_EDGES+255)/256, 256, 0, stream>>>(recv, cursor, elist);
  k_trans<<<(NSPEC*4096)/256, 256, 0, stream>>>(l1_sel, l2_res, selT, resT);
  k_h1   <<<(N_NODES*64)/256, 256, 0, stream>>>(spec, embedW, l1_lin, h1);
  k_rw<0><<<(N_EDGES+63)/64, 256, 0, stream>>>(ev, l1_rW1, l1_rW2, rw12, rwB, shu);
  k_node1<<<N_NODES/4, 256, 0, stream>>>(send, spec, starts, elist, shu, rw12, h1,
        selT, l1_pw, l1_uw, l1_row, l2_lin, resT, out, outvo4, reso);
  k_rw<1><<<(N_EDGES+63)/64, 256, 0, stream>>>(ev, l2_rW1, l2_rW2, rw12, rwB, shu);
  k_node2<<<N_NODES/4, 256, 0, stream>>>(send, spec, starts, elist, shu, rwB,
        outvo4, reso, l2_pw, l2_roW1, l2_roW2, out);
}

// Round 7
// 138.038 us; speedup vs baseline: 3.5427x; 1.2264x over previous
//
#include <hip/hip_runtime.h>
#include <hip/hip_bf16.h>
#include <math.h>

#define N_NODES 10000
#define N_EDGES 100000
#define NCH 64
#define NSPEC 10

// ---------- CSR count ----------
__global__ void k_count(const int* __restrict__ recv, int* __restrict__ cnt){
  int i = blockIdx.x*blockDim.x + threadIdx.x;
  if (i < N_EDGES) atomicAdd(&cnt[recv[i]], 1);
}

// ---------- fused prologue: zero cursor | weight transposes | h1 ----------
__global__ __launch_bounds__(256) void k_pre(
  int* __restrict__ cursor,
  const float* __restrict__ sel, const float* __restrict__ resw,
  float* __restrict__ selT, float* __restrict__ resT,
  const int* __restrict__ species, const float* __restrict__ embedW,
  const float* __restrict__ linup, float* __restrict__ h1)
{
  int b = blockIdx.x;
  int tid = threadIdx.x;
  if (b < 40){                                  // zero cursor (10000 ints)
    int i = b*256 + tid;
    if (i < N_NODES) cursor[i] = 0;
  } else if (b < 200){                          // selT/resT transpose (40960 elems)
    int i = (b-40)*256 + tid;
    int s = i >> 12, r = i & 4095, d = r >> 6, c = r & 63;
    int src = s*4096 + c*64 + d;
    selT[i] = sel[src];
    resT[i] = resw[src];
  } else {                                      // h1 = embed[species] @ l1_lin_up
    int w = ((b-200)*256 + tid) >> 6;           // 2500 blocks * 4 = 10000
    int lane = tid & 63;
    int sp = __builtin_amdgcn_readfirstlane(species[w]);
    const float* x0 = embedW + sp*NCH;
    float acc = 0.f;
    #pragma unroll
    for (int d = 0; d < NCH; d++) acc += x0[d] * linup[d*NCH + lane];
    h1[w*NCH + lane] = acc;
  }
}

// ---------- block 0: CSR scan | blocks 1..: merged radial GEMM (both layers) ----------
// rw12[e][c] = (col 4c, col 4c+1) of silu(bessel@l1_rW1)@l1_rW2 ; shu[e]
// rwB[e][c]  =  col 4c          of silu(bessel@l2_rW1)@l2_rW2
__global__ __launch_bounds__(256) void k_scanrw(
    int* __restrict__ cnt_cursor, int* __restrict__ starts,
    const float* __restrict__ ev,
    const float* __restrict__ rW1a, const float* __restrict__ rW2a,
    const float* __restrict__ rW1b, const float* __restrict__ rW2b,
    float2* __restrict__ rw12, float* __restrict__ rwB,
    float4* __restrict__ shu)
{
  __shared__ float s_hidT[64*68];      // [h][e], pad 68; reused by both layers

  int tid = threadIdx.x;

  if (blockIdx.x == 0){
    // coarsened scan: 256 threads, 40 nodes each (reuses s_hidT as int buffer)
    int* stot = (int*)s_hidT;
    int base = tid*40;
    int loc[40];
    int sum = 0;
    #pragma unroll
    for (int j = 0; j < 40; j++){
      int i = base + j;
      int v = (i < N_NODES) ? cnt_cursor[i] : 0;
      loc[j] = sum; sum += v;
    }
    stot[tid] = sum;
    __syncthreads();
    for (int off = 1; off < 256; off <<= 1){
      int t = (tid >= off) ? stot[tid-off] : 0;
      __syncthreads();
      stot[tid] += t;
      __syncthreads();
    }
    int excl = stot[tid] - sum;
    #pragma unroll
    for (int j = 0; j < 40; j++){
      int i = base + j;
      if (i < N_NODES){ int st = excl + loc[j]; starts[i] = st; cnt_cursor[i] = st; }
    }
    if (tid == 255) starts[N_NODES] = stot[255];
    return;
  }

  int e0 = (blockIdx.x-1)*64;
  int el = tid & 63;
  int hg = __builtin_amdgcn_readfirstlane(tid >> 6);   // 0..3, wave-uniform

  // geometry + bessel: once for both layers (4-way redundant across h-groups)
  int e = e0 + el;
  bool act = (e < N_EDGES);
  float ex = 0.f, ey = 0.f, ez = 1.f;
  if (act){ ex = ev[e*3+0]; ey = ev[e*3+1]; ez = ev[e*3+2]; }
  float r = sqrtf(ex*ex + ey*ey + ez*ez + 1e-12f);
  float rinv = 1.0f / r;
  float u = r * 0.2f;
  float env = 0.f;
  if (u < 1.f){ float om = 1.f - u; env = om*om*(1.f + 2.f*u); }
  float pref = 0.6324555320336759f * rinv * env;       // sqrt(2/5)
  float rad[8];
  #pragma unroll
  for (int b = 0; b < 8; b++)
    rad[b] = pref * __sinf((float)(b+1) * 3.14159265358979f * u);
  if (hg == 0 && act) shu[e] = make_float4(ex*rinv, ey*rinv, ez*rinv, 0.f);

  int c = el, eg = hg;

  // ---- layer 1: hid1 -> rw12 (2 cols) ----
  #pragma unroll
  for (int j = 0; j < 16; j++){
    int h = hg*16 + j;
    float ah = 0.f;
    #pragma unroll
    for (int b = 0; b < 8; b++) ah += rad[b] * rW1a[b*64 + h];   // uniform -> s_load
    s_hidT[h*68 + el] = ah / (1.f + __expf(-ah));
  }
  __syncthreads();
  {
    float2 acc[16];
    #pragma unroll
    for (int j = 0; j < 16; j++) acc[j] = make_float2(0.f, 0.f);
    #pragma unroll 1
    for (int hc = 0; hc < 4; hc++){
      float2 wreg[16];
      #pragma unroll
      for (int j = 0; j < 16; j++)
        wreg[j] = *reinterpret_cast<const float2*>(rW2a + (hc*16+j)*256 + 4*c);
      #pragma unroll
      for (int j = 0; j < 16; j++){
        int h = hc*16 + j;
        const float4* hp = (const float4*)(s_hidT + h*68 + eg*16);  // uniform broadcast
        float hv[16];
        *(float4*)&hv[0]  = hp[0];
        *(float4*)&hv[4]  = hp[1];
        *(float4*)&hv[8]  = hp[2];
        *(float4*)&hv[12] = hp[3];
        #pragma unroll
        for (int i = 0; i < 16; i++){
          acc[i].x += hv[i]*wreg[j].x;
          acc[i].y += hv[i]*wreg[j].y;
        }
      }
    }
    #pragma unroll
    for (int j = 0; j < 16; j++){
      int er = e0 + eg*16 + j;
      if (er < N_EDGES) rw12[(size_t)er*64 + c] = acc[j];
    }
  }
  __syncthreads();

  // ---- layer 2: hid2 -> rwB (1 col) ----
  #pragma unroll
  for (int j = 0; j < 16; j++){
    int h = hg*16 + j;
    float ah = 0.f;
    #pragma unroll
    for (int b = 0; b < 8; b++) ah += rad[b] * rW1b[b*64 + h];
    s_hidT[h*68 + el] = ah / (1.f + __expf(-ah));
  }
  __syncthreads();
  {
    float acc[16];
    #pragma unroll
    for (int j = 0; j < 16; j++) acc[j] = 0.f;
    #pragma unroll 1
    for (int hc = 0; hc < 4; hc++){
      float wreg[16];
      #pragma unroll
      for (int j = 0; j < 16; j++)
        wreg[j] = rW2b[(hc*16+j)*256 + 4*c];
      #pragma unroll
      for (int j = 0; j < 16; j++){
        int h = hc*16 + j;
        const float4* hp = (const float4*)(s_hidT + h*68 + eg*16);
        float hv[16];
        *(float4*)&hv[0]  = hp[0];
        *(float4*)&hv[4]  = hp[1];
        *(float4*)&hv[8]  = hp[2];
        *(float4*)&hv[12] = hp[3];
        #pragma unroll
        for (int i = 0; i < 16; i++) acc[i] += hv[i]*wreg[j];
      }
    }
    #pragma unroll
    for (int j = 0; j < 16; j++){
      int er = e0 + eg*16 + j;
      if (er < N_EDGES) rwB[(size_t)er*64 + c] = acc[j];
    }
  }
}

__global__ void k_fill(const int* __restrict__ recv, int* __restrict__ cursor, int* __restrict__ elist){
  int i = blockIdx.x*blockDim.x + threadIdx.x;
  if (i < N_EDGES){ int pos = atomicAdd(&cursor[recv[i]], 1); elist[pos] = i; }
}

// ---------- pass-1 gather + node transforms (1 wave per node, no weights) ----------
__global__ __launch_bounds__(256) void k_node1(
  const int* __restrict__ senders, const int* __restrict__ species,
  const int* __restrict__ starts, const int* __restrict__ elist,
  const float4* __restrict__ shu,
  const float2* __restrict__ rw12, const float* __restrict__ h1,
  const float* __restrict__ selT,
  const float* __restrict__ pw, const float* __restrict__ uwv,
  const float* __restrict__ row,
  const float* __restrict__ linup2, const float* __restrict__ resT,
  float* __restrict__ out,
  float4* __restrict__ outvo4, float* __restrict__ reso)
{
  int lane  = threadIdx.x & 63;
  int wslot = threadIdx.x >> 6;
  int n = blockIdx.x*4 + wslot;          // grid exact: 2500*4 = 10000
  __shared__ float4 sacc[4][64];

  int s0 = __builtin_amdgcn_readfirstlane(starts[n]);
  int s1 = __builtin_amdgcn_readfirstlane(starts[n+1]);
  int sp = __builtin_amdgcn_readfirstlane(species[n]);

  float acc0 = 0.f, acc1 = 0.f, acc2 = 0.f, acc3 = 0.f;
  for (int base = s0; base < s1; base += 64){
    int m = min(64, s1 - base);
    int e_l = 0, snd_l = 0;
    if (lane < m){
      e_l   = elist[base + lane];
      snd_l = senders[e_l];
    }
    int t = 0;
    for (; t+2 <= m; t += 2){
      int ea = __builtin_amdgcn_readfirstlane(__shfl(e_l, t, 64));
      int sa = __builtin_amdgcn_readfirstlane(__shfl(snd_l, t, 64));
      int eb = __builtin_amdgcn_readfirstlane(__shfl(e_l, t+1, 64));
      int sb = __builtin_amdgcn_readfirstlane(__shfl(snd_l, t+1, 64));
      float2 rva = rw12[(size_t)ea*64 + lane];
      float  h1a = h1[sa*64 + lane];
      float4 sva = shu[ea];
      float2 rvb = rw12[(size_t)eb*64 + lane];
      float  h1b = h1[sb*64 + lane];
      float4 svb = shu[eb];
      acc0 += rva.x * h1a;
      float ma = rva.y * h1a;
      acc1 += ma*sva.x; acc2 += ma*sva.y; acc3 += ma*sva.z;
      acc0 += rvb.x * h1b;
      float mb = rvb.y * h1b;
      acc1 += mb*svb.x; acc2 += mb*svb.y; acc3 += mb*svb.z;
    }
    if (t < m){
      int ea = __builtin_amdgcn_readfirstlane(__shfl(e_l, t, 64));
      int sa = __builtin_amdgcn_readfirstlane(__shfl(snd_l, t, 64));
      float2 rva = rw12[(size_t)ea*64 + lane];
      float  h1a = h1[sa*64 + lane];
      float4 sva = shu[ea];
      acc0 += rva.x * h1a;
      float ma = rva.y * h1a;
      acc1 += ma*sva.x; acc2 += ma*sva.y; acc3 += ma*sva.z;
    }
  }
  const float c10 = 0.1f;                      // 1/AVG_NEIGH
  const float c13 = 0.17320508075688773f;      // sqrt(3)/10
  sacc[wslot][lane] = make_float4(acc0*c10, acc1*c13, acc2*c13, acc3*c13);
  asm volatile("s_waitcnt lgkmcnt(0)" ::: "memory");

  // feats[c,k] = sum_d selW[c,d] * agg[d,k]
  const float* selp = selT + sp*4096;
  float f0 = 0.f, f1 = 0.f, f2 = 0.f, f3 = 0.f;
  #pragma unroll 8
  for (int d = 0; d < 64; d++){
    float wv = selp[d*64 + lane];
    float4 a = sacc[wslot][d];
    f0 += wv*a.x; f1 += wv*a.y; f2 += wv*a.z; f3 += wv*a.w;
  }

  float s = f0;
  const float* pwp = pw  + sp*192;
  const float* uwp = uwv + sp*192;
  float pw0 = pwp[lane], pw1 = pwp[64+lane], pw2 = pwp[128+lane];
  float uw0 = uwp[lane], uw1 = uwp[64+lane], uw2 = uwp[128+lane];
  float ss = s*s;
  float o0  = pw0*s + pw1*ss + pw2*ss*s;
  float uco = uw0 + uw1*s + uw2*ss;

  // ro1 = sum_c o0[c]*row[c]
  float rv = o0 * row[lane];
  #pragma unroll
  for (int off = 32; off >= 1; off >>= 1) rv += __shfl_xor(rv, off, 64);
  if (lane == 0) out[n*2 + 0] = rv;

  // stage o0, compute h2 and res
  float* so = reinterpret_cast<float*>(&sacc[wslot][0]);
  asm volatile("s_waitcnt lgkmcnt(0)" ::: "memory");
  so[lane] = o0;
  asm volatile("s_waitcnt lgkmcnt(0)" ::: "memory");

  float hh = 0.f, rr = 0.f;
  const float* resp = resT + sp*4096;
  #pragma unroll 8
  for (int d = 0; d < 64; d++){
    float od = so[d];
    hh += od * linup2[d*64 + lane];
    rr += od * resp[d*64 + lane];
  }
  outvo4[n*64 + lane] = make_float4(uco*f1, uco*f2, uco*f3, hh);  // .w = h2
  reso[n*64 + lane] = rr;
}

// ---------- pass-2 gather + readout (1 wave per node) ----------
__global__ __launch_bounds__(256) void k_node2(
  const int* __restrict__ senders, const int* __restrict__ species,
  const int* __restrict__ starts, const int* __restrict__ elist,
  const float4* __restrict__ shu,
  const float* __restrict__ rwB,
  const float4* __restrict__ outvo4, const float* __restrict__ reso,
  const float* __restrict__ pw2,
  const float* __restrict__ roW1, const float* __restrict__ roW2,
  float* __restrict__ out)
{
  int lane  = threadIdx.x & 63;
  int wslot = threadIdx.x >> 6;
  int n = blockIdx.x*4 + wslot;
  __shared__ float sout[4][64];

  int s0 = __builtin_amdgcn_readfirstlane(starts[n]);
  int s1 = __builtin_amdgcn_readfirstlane(starts[n+1]);
  int sp = __builtin_amdgcn_readfirstlane(species[n]);

  float acc = 0.f;
  for (int base = s0; base < s1; base += 64){
    int m = min(64, s1 - base);
    int e_l = 0, snd_l = 0;
    if (lane < m){
      e_l   = elist[base + lane];
      snd_l = senders[e_l];
    }
    int t = 0;
    for (; t+2 <= m; t += 2){
      int ea = __builtin_amdgcn_readfirstlane(__shfl(e_l, t, 64));
      int sa = __builtin_amdgcn_readfirstlane(__shfl(snd_l, t, 64));
      int eb = __builtin_amdgcn_readfirstlane(__shfl(e_l, t+1, 64));
      int sb = __builtin_amdgcn_readfirstlane(__shfl(snd_l, t+1, 64));
      float rwa = rwB[(size_t)ea*64 + lane];
      float4 ova = outvo4[sa*64 + lane];
      float4 sva = shu[ea];
      float rwb = rwB[(size_t)eb*64 + lane];
      float4 ovb = outvo4[sb*64 + lane];
      float4 svb = shu[eb];
      acc += rwa * (ova.w + ova.x*sva.x + ova.y*sva.y + ova.z*sva.z);
      acc += rwb * (ovb.w + ovb.x*svb.x + ovb.y*svb.y + ovb.z*svb.z);
    }
    if (t < m){
      int ea = __builtin_amdgcn_readfirstlane(__shfl(e_l, t, 64));
      int sa = __builtin_amdgcn_readfirstlane(__shfl(snd_l, t, 64));
      float rwa = rwB[(size_t)ea*64 + lane];
      float4 ova = outvo4[sa*64 + lane];
      float4 sva = shu[ea];
      acc += rwa * (ova.w + ova.x*sva.x + ova.y*sva.y + ova.z*sva.z);
    }
  }
  float s2 = acc * 0.1f;
  const float* p2 = pw2 + sp*192;
  float q0 = p2[lane], q1 = p2[64+lane], q2 = p2[128+lane];
  float s2s = s2*s2;
  float o2 = q0*s2 + q1*s2s + q2*s2s*s2 + reso[n*64 + lane];

  sout[wslot][lane] = o2;
  asm volatile("s_waitcnt lgkmcnt(0)" ::: "memory");

  // ro2 = silu(out2 @ roW1) @ roW2
  int j = lane & 15, g = lane >> 4;
  float qp = 0.f;
  #pragma unroll
  for (int t = 0; t < 16; t++){
    int c = g*16 + t;
    qp += sout[wslot][c] * roW1[c*16 + j];
  }
  qp += __shfl_xor(qp, 16, 64);
  qp += __shfl_xor(qp, 32, 64);
  float sil = qp / (1.f + __expf(-qp));
  float contrib = sil * roW2[j];
  contrib += __shfl_xor(contrib, 1, 64);
  contrib += __shfl_xor(contrib, 2, 64);
  contrib += __shfl_xor(contrib, 4, 64);
  contrib += __shfl_xor(contrib, 8, 64);
  if (lane == 0) out[n*2 + 1] = contrib;
}

extern "C" void kernel_launch(void* const* d_in, const int* in_sizes, int n_in,
                              void* d_out, int out_size, void* d_ws, size_t ws_size,
                              hipStream_t stream)
{
  const float* ev     = (const float*)d_in[0];
  const int*   spec   = (const int*)  d_in[1];
  const int*   send   = (const int*)  d_in[2];
  const int*   recv   = (const int*)  d_in[3];
  const float* embedW = (const float*)d_in[4];
  const float* l1_lin = (const float*)d_in[5];
  const float* l1_rW1 = (const float*)d_in[6];
  const float* l1_rW2 = (const float*)d_in[7];
  const float* l1_sel = (const float*)d_in[8];
  const float* l1_pw  = (const float*)d_in[9];
  const float* l1_uw  = (const float*)d_in[10];
  const float* l1_row = (const float*)d_in[11];
  const float* l2_lin = (const float*)d_in[12];
  const float* l2_rW1 = (const float*)d_in[13];
  const float* l2_rW2 = (const float*)d_in[14];
  const float* l2_res = (const float*)d_in[15];
  const float* l2_pw  = (const float*)d_in[16];
  const float* l2_roW1= (const float*)d_in[17];
  const float* l2_roW2= (const float*)d_in[18];
  float* out = (float*)d_out;

  char* w = (char*)d_ws;
  float2* rw12  = (float2*)w; w += (size_t)N_EDGES*64*8;   // 51.2 MB
  float*  rwB   = (float*)w;  w += (size_t)N_EDGES*64*4;   // 25.6 MB (de-aliased)
  float*  h1    = (float*)w;  w += (size_t)N_NODES*64*4;
  float4* outvo4= (float4*)w; w += (size_t)N_NODES*64*16;
  float*  reso  = (float*)w;  w += (size_t)N_NODES*64*4;
  float*  selT  = (float*)w;  w += (size_t)NSPEC*4096*4;
  float*  resT  = (float*)w;  w += (size_t)NSPEC*4096*4;
  float4* shu   = (float4*)w; w += (size_t)N_EDGES*16;
  int* starts = (int*)w;      w += (size_t)(N_NODES+1)*4;
  int* cursor = (int*)w;      w += (size_t)N_NODES*4;
  int* elist  = (int*)w;      w += (size_t)N_EDGES*4;

  k_pre  <<<2700, 256, 0, stream>>>(cursor, l1_sel, l2_res, selT, resT,
                                    spec, embedW, l1_lin, h1);
  k_count<<<(N_EDGES+255)/256, 256, 0, stream>>>(recv, cursor);
  k_scanrw<<<1 + (N_EDGES+63)/64, 256, 0, stream>>>(cursor, starts,
        ev, l1_rW1, l1_rW2, l2_rW1, l2_rW2, rw12, rwB, shu);
  k_fill <<<(N_EDGES+255)/256, 256, 0, stream>>>(recv, cursor, elist);
  k_node1<<<N_NODES/4, 256, 0, stream>>>(send, spec, starts, elist, shu, rw12, h1,
        selT, l1_pw, l1_uw, l1_row, l2_lin, resT, out, outvo4, reso);
  k_node2<<<N_NODES/4, 256, 0, stream>>>(send, spec, starts, elist, shu, rwB,
        outvo4, reso, l2_pw, l2_roW1, l2_roW2, out);
}

// Round 8
// 129.292 us; speedup vs baseline: 3.7824x; 1.0677x over previous
//
#include <hip/hip_runtime.h>
#include <hip/hip_bf16.h>
#include <math.h>

#define N_NODES 10000
#define N_EDGES 100000
#define NCH 64
#define NSPEC 10

typedef __attribute__((ext_vector_type(8))) short short8v;
typedef __attribute__((ext_vector_type(4))) float f32x4;

static __device__ __forceinline__ unsigned short f2bf(float f){
  unsigned u = __float_as_uint(f);
  u += 0x7fff + ((u >> 16) & 1);          // round-to-nearest-even
  return (unsigned short)(u >> 16);
}

// ---------- CSR count ----------
__global__ void k_count(const int* __restrict__ recv, int* __restrict__ cnt){
  int i = blockIdx.x*blockDim.x + threadIdx.x;
  if (i < N_EDGES) atomicAdd(&cnt[recv[i]], 1);
}

// ---------- fused prologue: zero cursor | weight transposes | h1 ----------
__global__ __launch_bounds__(256) void k_pre(
  int* __restrict__ cursor,
  const float* __restrict__ sel, const float* __restrict__ resw,
  float* __restrict__ selT, float* __restrict__ resT,
  const int* __restrict__ species, const float* __restrict__ embedW,
  const float* __restrict__ linup, float* __restrict__ h1)
{
  int b = blockIdx.x;
  int tid = threadIdx.x;
  if (b < 40){                                  // zero cursor (10000 ints)
    int i = b*256 + tid;
    if (i < N_NODES) cursor[i] = 0;
  } else if (b < 200){                          // selT/resT transpose (40960 elems)
    int i = (b-40)*256 + tid;
    int s = i >> 12, r = i & 4095, d = r >> 6, c = r & 63;
    int src = s*4096 + c*64 + d;
    selT[i] = sel[src];
    resT[i] = resw[src];
  } else {                                      // h1 = embed[species] @ l1_lin_up
    int w = ((b-200)*256 + tid) >> 6;           // 2500 blocks * 4 = 10000
    int lane = tid & 63;
    int sp = __builtin_amdgcn_readfirstlane(species[w]);
    const float* x0 = embedW + sp*NCH;
    float acc = 0.f;
    #pragma unroll
    for (int d = 0; d < NCH; d++) acc += x0[d] * linup[d*NCH + lane];
    h1[w*NCH + lane] = acc;
  }
}

// ---------- block 0: CSR scan | blocks 1..: MFMA radial GEMM (both layers) ----------
// rw12[e][c] = (col 4c, col 4c+1) of silu(bessel@l1_rW1)@l1_rW2 ; shu[e]
// rwB[e][c]  =  col 4c          of silu(bessel@l2_rW1)@l2_rW2
// 64-edge tile; hid staged bf16 in LDS; GEMM on mfma_f32_16x16x32_bf16.
__global__ __launch_bounds__(256) void k_scanrw(
    int* __restrict__ cnt_cursor, int* __restrict__ starts,
    const float* __restrict__ ev,
    const float* __restrict__ rW1a, const float* __restrict__ rW2a,
    const float* __restrict__ rW1b, const float* __restrict__ rW2b,
    float2* __restrict__ rw12, float* __restrict__ rwB,
    float4* __restrict__ shu)
{
  __shared__ short s_hid[64*72];       // [e][h] bf16, row stride 72 shorts (144B, 16B-aligned)

  int tid = threadIdx.x;

  if (blockIdx.x == 0){
    // coarsened scan: 256 threads, 40 nodes each (reuses s_hid as int buffer)
    int* stot = (int*)s_hid;
    int base = tid*40;
    int loc[40];
    int sum = 0;
    #pragma unroll
    for (int j = 0; j < 40; j++){
      int i = base + j;
      int v = (i < N_NODES) ? cnt_cursor[i] : 0;
      loc[j] = sum; sum += v;
    }
    stot[tid] = sum;
    __syncthreads();
    for (int off = 1; off < 256; off <<= 1){
      int t = (tid >= off) ? stot[tid-off] : 0;
      __syncthreads();
      stot[tid] += t;
      __syncthreads();
    }
    int excl = stot[tid] - sum;
    #pragma unroll
    for (int j = 0; j < 40; j++){
      int i = base + j;
      if (i < N_NODES){ int st = excl + loc[j]; starts[i] = st; cnt_cursor[i] = st; }
    }
    if (tid == 255) starts[N_NODES] = stot[255];
    return;
  }

  int e0 = (blockIdx.x-1)*64;
  int lane = tid & 63;
  int w = __builtin_amdgcn_readfirstlane(tid >> 6);    // wave id 0..3

  // geometry + bessel for edge e0+lane (each wave redundantly for its lane's edge)
  int e = e0 + lane;
  bool act = (e < N_EDGES);
  float ex = 0.f, ey = 0.f, ez = 1.f;
  if (act){ ex = ev[e*3+0]; ey = ev[e*3+1]; ez = ev[e*3+2]; }
  float r = sqrtf(ex*ex + ey*ey + ez*ez + 1e-12f);
  float rinv = 1.0f / r;
  float u = r * 0.2f;
  float env = 0.f;
  if (u < 1.f){ float om = 1.f - u; env = om*om*(1.f + 2.f*u); }
  float pref = 0.6324555320336759f * rinv * env;       // sqrt(2/5)
  float rad[8];
  #pragma unroll
  for (int b = 0; b < 8; b++)
    rad[b] = pref * __sinf((float)(b+1) * 3.14159265358979f * u);
  if (w == 0 && act) shu[e] = make_float4(ex*rinv, ey*rinv, ez*rinv, 0.f);

  int cl = lane & 15;                 // col within 16-tile
  int hb = (lane >> 4) * 8;           // k base within 32-step
  int rowq = (lane >> 4) * 4;         // D row base

  // ======================= layer 1 =======================
  // hid1: wave w produces h in [16w,16w+16) for its lane's edge; bf16 into LDS
  {
    short8v hv0, hv1;
    #pragma unroll
    for (int j = 0; j < 16; j++){
      int h = w*16 + j;
      float ah = 0.f;
      #pragma unroll
      for (int b = 0; b < 8; b++) ah += rad[b] * rW1a[b*64 + h];   // uniform -> s_load
      float hid = ah / (1.f + __expf(-ah));
      unsigned short hb16 = f2bf(hid);
      if (j < 8) hv0[j] = (short)hb16; else hv1[j-8] = (short)hb16;
    }
    *(short8v*)&s_hid[lane*72 + w*16]     = hv0;
    *(short8v*)&s_hid[lane*72 + w*16 + 8] = hv1;
  }
  __syncthreads();

  // A frags: e = e0 + 16w + (lane&15), k = hb + j (+32 for step 1)
  short8v a0 = *(short8v*)&s_hid[(w*16 + cl)*72 + hb];
  short8v a1 = *(short8v*)&s_hid[(w*16 + cl)*72 + hb + 32];
  __syncthreads();                    // LDS free for layer 2

  {
    f32x4 ax[4], ay[4];
    #pragma unroll
    for (int t = 0; t < 4; t++){
      ax[t] = (f32x4)(0.f); ay[t] = (f32x4)(0.f);
    }
    #pragma unroll
    for (int t = 0; t < 4; t++){
      int c4 = 4*(t*16 + cl);
      short8v bx0, bx1, by0, by1;
      #pragma unroll
      for (int j = 0; j < 8; j++){
        bx0[j] = (short)f2bf(rW2a[(hb      + j)*256 + c4    ]);
        bx1[j] = (short)f2bf(rW2a[(hb + 32 + j)*256 + c4    ]);
        by0[j] = (short)f2bf(rW2a[(hb      + j)*256 + c4 + 1]);
        by1[j] = (short)f2bf(rW2a[(hb + 32 + j)*256 + c4 + 1]);
      }
      ax[t] = __builtin_amdgcn_mfma_f32_16x16x32_bf16(a0, bx0, ax[t], 0, 0, 0);
      ax[t] = __builtin_amdgcn_mfma_f32_16x16x32_bf16(a1, bx1, ax[t], 0, 0, 0);
      ay[t] = __builtin_amdgcn_mfma_f32_16x16x32_bf16(a0, by0, ay[t], 0, 0, 0);
      ay[t] = __builtin_amdgcn_mfma_f32_16x16x32_bf16(a1, by1, ay[t], 0, 0, 0);
    }
    #pragma unroll
    for (int t = 0; t < 4; t++){
      #pragma unroll
      for (int i = 0; i < 4; i++){
        int er = e0 + w*16 + rowq + i;
        if (er < N_EDGES)
          rw12[(size_t)er*64 + t*16 + cl] = make_float2(ax[t][i], ay[t][i]);
      }
    }
  }

  // ======================= layer 2 =======================
  {
    short8v hv0, hv1;
    #pragma unroll
    for (int j = 0; j < 16; j++){
      int h = w*16 + j;
      float ah = 0.f;
      #pragma unroll
      for (int b = 0; b < 8; b++) ah += rad[b] * rW1b[b*64 + h];
      float hid = ah / (1.f + __expf(-ah));
      unsigned short hb16 = f2bf(hid);
      if (j < 8) hv0[j] = (short)hb16; else hv1[j-8] = (short)hb16;
    }
    __syncthreads();                  // all layer-1 A reads done (already synced) — safe ordering
    *(short8v*)&s_hid[lane*72 + w*16]     = hv0;
    *(short8v*)&s_hid[lane*72 + w*16 + 8] = hv1;
  }
  __syncthreads();

  short8v c0f = *(short8v*)&s_hid[(w*16 + cl)*72 + hb];
  short8v c1f = *(short8v*)&s_hid[(w*16 + cl)*72 + hb + 32];

  {
    f32x4 acc[4];
    #pragma unroll
    for (int t = 0; t < 4; t++) acc[t] = (f32x4)(0.f);
    #pragma unroll
    for (int t = 0; t < 4; t++){
      int c4 = 4*(t*16 + cl);
      short8v b0, b1;
      #pragma unroll
      for (int j = 0; j < 8; j++){
        b0[j] = (short)f2bf(rW2b[(hb      + j)*256 + c4]);
        b1[j] = (short)f2bf(rW2b[(hb + 32 + j)*256 + c4]);
      }
      acc[t] = __builtin_amdgcn_mfma_f32_16x16x32_bf16(c0f, b0, acc[t], 0, 0, 0);
      acc[t] = __builtin_amdgcn_mfma_f32_16x16x32_bf16(c1f, b1, acc[t], 0, 0, 0);
    }
    #pragma unroll
    for (int t = 0; t < 4; t++){
      #pragma unroll
      for (int i = 0; i < 4; i++){
        int er = e0 + w*16 + rowq + i;
        if (er < N_EDGES)
          rwB[(size_t)er*64 + t*16 + cl] = acc[t][i];
      }
    }
  }
}

__global__ void k_fill(const int* __restrict__ recv, int* __restrict__ cursor, int* __restrict__ elist){
  int i = blockIdx.x*blockDim.x + threadIdx.x;
  if (i < N_EDGES){ int pos = atomicAdd(&cursor[recv[i]], 1); elist[pos] = i; }
}

// ---------- pass-1 gather + node transforms (1 wave per node, no weights) ----------
__global__ __launch_bounds__(256) void k_node1(
  const int* __restrict__ senders, const int* __restrict__ species,
  const int* __restrict__ starts, const int* __restrict__ elist,
  const float4* __restrict__ shu,
  const float2* __restrict__ rw12, const float* __restrict__ h1,
  const float* __restrict__ selT,
  const float* __restrict__ pw, const float* __restrict__ uwv,
  const float* __restrict__ row,
  const float* __restrict__ linup2, const float* __restrict__ resT,
  float* __restrict__ out,
  float4* __restrict__ outvo4, float* __restrict__ reso)
{
  int lane  = threadIdx.x & 63;
  int wslot = threadIdx.x >> 6;
  int n = blockIdx.x*4 + wslot;          // grid exact: 2500*4 = 10000
  __shared__ float4 sacc[4][64];

  int s0 = __builtin_amdgcn_readfirstlane(starts[n]);
  int s1 = __builtin_amdgcn_readfirstlane(starts[n+1]);
  int sp = __builtin_amdgcn_readfirstlane(species[n]);

  float acc0 = 0.f, acc1 = 0.f, acc2 = 0.f, acc3 = 0.f;
  for (int base = s0; base < s1; base += 64){
    int m = min(64, s1 - base);
    int e_l = 0, snd_l = 0;
    if (lane < m){
      e_l   = elist[base + lane];
      snd_l = senders[e_l];
    }
    int t = 0;
    for (; t+2 <= m; t += 2){
      int ea = __builtin_amdgcn_readfirstlane(__shfl(e_l, t, 64));
      int sa = __builtin_amdgcn_readfirstlane(__shfl(snd_l, t, 64));
      int eb = __builtin_amdgcn_readfirstlane(__shfl(e_l, t+1, 64));
      int sb = __builtin_amdgcn_readfirstlane(__shfl(snd_l, t+1, 64));
      float2 rva = rw12[(size_t)ea*64 + lane];
      float  h1a = h1[sa*64 + lane];
      float4 sva = shu[ea];
      float2 rvb = rw12[(size_t)eb*64 + lane];
      float  h1b = h1[sb*64 + lane];
      float4 svb = shu[eb];
      acc0 += rva.x * h1a;
      float ma = rva.y * h1a;
      acc1 += ma*sva.x; acc2 += ma*sva.y; acc3 += ma*sva.z;
      acc0 += rvb.x * h1b;
      float mb = rvb.y * h1b;
      acc1 += mb*svb.x; acc2 += mb*svb.y; acc3 += mb*svb.z;
    }
    if (t < m){
      int ea = __builtin_amdgcn_readfirstlane(__shfl(e_l, t, 64));
      int sa = __builtin_amdgcn_readfirstlane(__shfl(snd_l, t, 64));
      float2 rva = rw12[(size_t)ea*64 + lane];
      float  h1a = h1[sa*64 + lane];
      float4 sva = shu[ea];
      acc0 += rva.x * h1a;
      float ma = rva.y * h1a;
      acc1 += ma*sva.x; acc2 += ma*sva.y; acc3 += ma*sva.z;
    }
  }
  const float c10 = 0.1f;                      // 1/AVG_NEIGH
  const float c13 = 0.17320508075688773f;      // sqrt(3)/10
  sacc[wslot][lane] = make_float4(acc0*c10, acc1*c13, acc2*c13, acc3*c13);
  asm volatile("s_waitcnt lgkmcnt(0)" ::: "memory");

  // feats[c,k] = sum_d selW[c,d] * agg[d,k]
  const float* selp = selT + sp*4096;
  float f0 = 0.f, f1 = 0.f, f2 = 0.f, f3 = 0.f;
  #pragma unroll 8
  for (int d = 0; d < 64; d++){
    float wv = selp[d*64 + lane];
    float4 a = sacc[wslot][d];
    f0 += wv*a.x; f1 += wv*a.y; f2 += wv*a.z; f3 += wv*a.w;
  }

  float s = f0;
  const float* pwp = pw  + sp*192;
  const float* uwp = uwv + sp*192;
  float pw0 = pwp[lane], pw1 = pwp[64+lane], pw2 = pwp[128+lane];
  float uw0 = uwp[lane], uw1 = uwp[64+lane], uw2 = uwp[128+lane];
  float ss = s*s;
  float o0  = pw0*s + pw1*ss + pw2*ss*s;
  float uco = uw0 + uw1*s + uw2*ss;

  // ro1 = sum_c o0[c]*row[c]
  float rv = o0 * row[lane];
  #pragma unroll
  for (int off = 32; off >= 1; off >>= 1) rv += __shfl_xor(rv, off, 64);
  if (lane == 0) out[n*2 + 0] = rv;

  // stage o0, compute h2 and res
  float* so = reinterpret_cast<float*>(&sacc[wslot][0]);
  asm volatile("s_waitcnt lgkmcnt(0)" ::: "memory");
  so[lane] = o0;
  asm volatile("s_waitcnt lgkmcnt(0)" ::: "memory");

  float hh = 0.f, rr = 0.f;
  const float* resp = resT + sp*4096;
  #pragma unroll 8
  for (int d = 0; d < 64; d++){
    float od = so[d];
    hh += od * linup2[d*64 + lane];
    rr += od * resp[d*64 + lane];
  }
  outvo4[n*64 + lane] = make_float4(uco*f1, uco*f2, uco*f3, hh);  // .w = h2
  reso[n*64 + lane] = rr;
}

// ---------- pass-2 gather + readout (1 wave per node) ----------
__global__ __launch_bounds__(256) void k_node2(
  const int* __restrict__ senders, const int* __restrict__ species,
  const int* __restrict__ starts, const int* __restrict__ elist,
  const float4* __restrict__ shu,
  const float* __restrict__ rwB,
  const float4* __restrict__ outvo4, const float* __restrict__ reso,
  const float* __restrict__ pw2,
  const float* __restrict__ roW1, const float* __restrict__ roW2,
  float* __restrict__ out)
{
  int lane  = threadIdx.x & 63;
  int wslot = threadIdx.x >> 6;
  int n = blockIdx.x*4 + wslot;
  __shared__ float sout[4][64];

  int s0 = __builtin_amdgcn_readfirstlane(starts[n]);
  int s1 = __builtin_amdgcn_readfirstlane(starts[n+1]);
  int sp = __builtin_amdgcn_readfirstlane(species[n]);

  float acc = 0.f;
  for (int base = s0; base < s1; base += 64){
    int m = min(64, s1 - base);
    int e_l = 0, snd_l = 0;
    if (lane < m){
      e_l   = elist[base + lane];
      snd_l = senders[e_l];
    }
    int t = 0;
    for (; t+2 <= m; t += 2){
      int ea = __builtin_amdgcn_readfirstlane(__shfl(e_l, t, 64));
      int sa = __builtin_amdgcn_readfirstlane(__shfl(snd_l, t, 64));
      int eb = __builtin_amdgcn_readfirstlane(__shfl(e_l, t+1, 64));
      int sb = __builtin_amdgcn_readfirstlane(__shfl(snd_l, t+1, 64));
      float rwa = rwB[(size_t)ea*64 + lane];
      float4 ova = outvo4[sa*64 + lane];
      float4 sva = shu[ea];
      float rwb = rwB[(size_t)eb*64 + lane];
      float4 ovb = outvo4[sb*64 + lane];
      float4 svb = shu[eb];
      acc += rwa * (ova.w + ova.x*sva.x + ova.y*sva.y + ova.z*sva.z);
      acc += rwb * (ovb.w + ovb.x*svb.x + ovb.y*svb.y + ovb.z*svb.z);
    }
    if (t < m){
      int ea = __builtin_amdgcn_readfirstlane(__shfl(e_l, t, 64));
      int sa = __builtin_amdgcn_readfirstlane(__shfl(snd_l, t, 64));
      float rwa = rwB[(size_t)ea*64 + lane];
      float4 ova = outvo4[sa*64 + lane];
      float4 sva = shu[ea];
      acc += rwa * (ova.w + ova.x*sva.x + ova.y*sva.y + ova.z*sva.z);
    }
  }
  float s2 = acc * 0.1f;
  const float* p2 = pw2 + sp*192;
  float q0 = p2[lane], q1 = p2[64+lane], q2 = p2[128+lane];
  float s2s = s2*s2;
  float o2 = q0*s2 + q1*s2s + q2*s2s*s2 + reso[n*64 + lane];

  sout[wslot][lane] = o2;
  asm volatile("s_waitcnt lgkmcnt(0)" ::: "memory");

  // ro2 = silu(out2 @ roW1) @ roW2
  int j = lane & 15, g = lane >> 4;
  float qp = 0.f;
  #pragma unroll
  for (int t = 0; t < 16; t++){
    int c = g*16 + t;
    qp += sout[wslot][c] * roW1[c*16 + j];
  }
  qp += __shfl_xor(qp, 16, 64);
  qp += __shfl_xor(qp, 32, 64);
  float sil = qp / (1.f + __expf(-qp));
  float contrib = sil * roW2[j];
  contrib += __shfl_xor(contrib, 1, 64);
  contrib += __shfl_xor(contrib, 2, 64);
  contrib += __shfl_xor(contrib, 4, 64);
  contrib += __shfl_xor(contrib, 8, 64);
  if (lane == 0) out[n*2 + 1] = contrib;
}

extern "C" void kernel_launch(void* const* d_in, const int* in_sizes, int n_in,
                              void* d_out, int out_size, void* d_ws, size_t ws_size,
                              hipStream_t stream)
{
  const float* ev     = (const float*)d_in[0];
  const int*   spec   = (const int*)  d_in[1];
  const int*   send   = (const int*)  d_in[2];
  const int*   recv   = (const int*)  d_in[3];
  const float* embedW = (const float*)d_in[4];
  const float* l1_lin = (const float*)d_in[5];
  const float* l1_rW1 = (const float*)d_in[6];
  const float* l1_rW2 = (const float*)d_in[7];
  const float* l1_sel = (const float*)d_in[8];
  const float* l1_pw  = (const float*)d_in[9];
  const float* l1_uw  = (const float*)d_in[10];
  const float* l1_row = (const float*)d_in[11];
  const float* l2_lin = (const float*)d_in[12];
  const float* l2_rW1 = (const float*)d_in[13];
  const float* l2_rW2 = (const float*)d_in[14];
  const float* l2_res = (const float*)d_in[15];
  const float* l2_pw  = (const float*)d_in[16];
  const float* l2_roW1= (const float*)d_in[17];
  const float* l2_roW2= (const float*)d_in[18];
  float* out = (float*)d_out;

  char* w = (char*)d_ws;
  float2* rw12  = (float2*)w; w += (size_t)N_EDGES*64*8;   // 51.2 MB
  float*  rwB   = (float*)w;  w += (size_t)N_EDGES*64*4;   // 25.6 MB
  float*  h1    = (float*)w;  w += (size_t)N_NODES*64*4;
  float4* outvo4= (float4*)w; w += (size_t)N_NODES*64*16;
  float*  reso  = (float*)w;  w += (size_t)N_NODES*64*4;
  float*  selT  = (float*)w;  w += (size_t)NSPEC*4096*4;
  float*  resT  = (float*)w;  w += (size_t)NSPEC*4096*4;
  float4* shu   = (float4*)w; w += (size_t)N_EDGES*16;
  int* starts = (int*)w;      w += (size_t)(N_NODES+1)*4;
  int* cursor = (int*)w;      w += (size_t)N_NODES*4;
  int* elist  = (int*)w;      w += (size_t)N_EDGES*4;

  k_pre  <<<2700, 256, 0, stream>>>(cursor, l1_sel, l2_res, selT, resT,
                                    spec, embedW, l1_lin, h1);
  k_count<<<(N_EDGES+255)/256, 256, 0, stream>>>(recv, cursor);
  k_scanrw<<<1 + (N_EDGES+63)/64, 256, 0, stream>>>(cursor, starts,
        ev, l1_rW1, l1_rW2, l2_rW1, l2_rW2, rw12, rwB, shu);
  k_fill <<<(N_EDGES+255)/256, 256, 0, stream>>>(recv, cursor, elist);
  k_node1<<<N_NODES/4, 256, 0, stream>>>(send, spec, starts, elist, shu, rw12, h1,
        selT, l1_pw, l1_uw, l1_row, l2_lin, resT, out, outvo4, reso);
  k_node2<<<N_NODES/4, 256, 0, stream>>>(send, spec, starts, elist, shu, rwB,
        outvo4, reso, l2_pw, l2_roW1, l2_roW2, out);
}

// Round 9
// 107.808 us; speedup vs baseline: 4.5362x; 1.1993x over previous
//
#include <hip/hip_runtime.h>
#include <hip/hip_bf16.h>
#include <math.h>

#define N_NODES 10000
#define N_EDGES 100000
#define NCH 64
#define NSPEC 10

typedef __attribute__((ext_vector_type(8))) short short8v;
typedef __attribute__((ext_vector_type(4))) float f32x4;

static __device__ __forceinline__ unsigned short f2bf(float f){
  unsigned u = __float_as_uint(f);
  u += 0x7fff + ((u >> 16) & 1);          // round-to-nearest-even
  return (unsigned short)(u >> 16);
}

// ---------- CSR count ----------
__global__ void k_count(const int* __restrict__ recv, int* __restrict__ cnt){
  int i = blockIdx.x*blockDim.x + threadIdx.x;
  if (i < N_EDGES) atomicAdd(&cnt[recv[i]], 1);
}

// ---------- fused prologue: zero cursor | transposes | h1 | bf16 B-fragments ----------
// wfrag layout (short8v entries, MFMA B-fragment order; lane: cl=lane&15, hb=(lane>>4)*8):
//   layer1 slot s=t*4+f (f: 0=x/k0,1=x/k32,2=y/k0,3=y/k32):  wf[s*64+lane][j] = bf16(rW2a[(hb+off+j)*256 + 4*(t*16+cl) + colofs])
//   layer2 slot s=t*2+f (f: 0=k0,1=k32) at offset 1024:       ... rW2b ... col 4c
__global__ __launch_bounds__(256) void k_pre(
  int* __restrict__ cursor,
  const float* __restrict__ sel, const float* __restrict__ resw,
  float* __restrict__ selT, float* __restrict__ resT,
  const int* __restrict__ species, const float* __restrict__ embedW,
  const float* __restrict__ linup, float* __restrict__ h1,
  const float* __restrict__ rW2a, const float* __restrict__ rW2b,
  unsigned short* __restrict__ wfrag)
{
  int b = blockIdx.x;
  int tid = threadIdx.x;
  if (b < 40){                                  // zero cursor (10000 ints)
    int i = b*256 + tid;
    if (i < N_NODES) cursor[i] = 0;
  } else if (b < 200){                          // selT/resT transpose (40960 elems)
    int i = (b-40)*256 + tid;
    int s = i >> 12, r = i & 4095, d = r >> 6, c = r & 63;
    int src = s*4096 + c*64 + d;
    selT[i] = sel[src];
    resT[i] = resw[src];
  } else if (b < 2700){                         // h1 = embed[species] @ l1_lin_up
    int w = ((b-200)*256 + tid) >> 6;           // 2500 blocks * 4 = 10000
    int lane = tid & 63;
    int sp = __builtin_amdgcn_readfirstlane(species[w]);
    const float* x0 = embedW + sp*NCH;
    float acc = 0.f;
    #pragma unroll
    for (int d = 0; d < NCH; d++) acc += x0[d] * linup[d*NCH + lane];
    h1[w*NCH + lane] = acc;
  } else {                                      // bf16 B-fragments (12288 shorts)
    int i = (b-2700)*256 + tid;
    int slot = i >> 9;                          // 0..23
    int rem  = i & 511;
    int lane = rem >> 3, j = rem & 7;
    int cl = lane & 15, hb = (lane >> 4)*8;
    float v;
    if (slot < 16){
      int t = slot >> 2, f = slot & 3;
      int colofs = f >> 1, off = (f & 1)*32;
      v = rW2a[(hb + off + j)*256 + 4*(t*16 + cl) + colofs];
    } else {
      int s2 = slot - 16;
      int t = s2 >> 1, f = s2 & 1;
      int off = f*32;
      v = rW2b[(hb + off + j)*256 + 4*(t*16 + cl)];
    }
    wfrag[i] = f2bf(v);
  }
}

// ---------- block 0: CSR scan | blocks 1..: MFMA radial GEMM (both layers) ----------
__global__ __launch_bounds__(256) void k_scanrw(
    int* __restrict__ cnt_cursor, int* __restrict__ starts,
    const float* __restrict__ ev,
    const float* __restrict__ rW1a, const float* __restrict__ rW1b,
    const unsigned short* __restrict__ wfrag,
    float2* __restrict__ rw12, float* __restrict__ rwB,
    float4* __restrict__ shu)
{
  __shared__ short s_hid[64*72];       // [e][h] bf16, row stride 72 shorts (144B, 16B-aligned)

  int tid = threadIdx.x;

  if (blockIdx.x == 0){
    // coarsened scan: 256 threads, 40 nodes each (reuses s_hid as int buffer)
    int* stot = (int*)s_hid;
    int base = tid*40;
    int loc[40];
    int sum = 0;
    #pragma unroll
    for (int j = 0; j < 40; j++){
      int i = base + j;
      int v = (i < N_NODES) ? cnt_cursor[i] : 0;
      loc[j] = sum; sum += v;
    }
    stot[tid] = sum;
    __syncthreads();
    for (int off = 1; off < 256; off <<= 1){
      int t = (tid >= off) ? stot[tid-off] : 0;
      __syncthreads();
      stot[tid] += t;
      __syncthreads();
    }
    int excl = stot[tid] - sum;
    #pragma unroll
    for (int j = 0; j < 40; j++){
      int i = base + j;
      if (i < N_NODES){ int st = excl + loc[j]; starts[i] = st; cnt_cursor[i] = st; }
    }
    if (tid == 255) starts[N_NODES] = stot[255];
    return;
  }

  int e0 = (blockIdx.x-1)*64;
  int lane = tid & 63;
  int w = __builtin_amdgcn_readfirstlane(tid >> 6);    // wave id 0..3

  // geometry + bessel for edge e0+lane (4-way redundant across waves)
  int e = e0 + lane;
  bool act = (e < N_EDGES);
  float ex = 0.f, ey = 0.f, ez = 1.f;
  if (act){ ex = ev[e*3+0]; ey = ev[e*3+1]; ez = ev[e*3+2]; }
  float r = sqrtf(ex*ex + ey*ey + ez*ez + 1e-12f);
  float rinv = 1.0f / r;
  float u = r * 0.2f;
  float env = 0.f;
  if (u < 1.f){ float om = 1.f - u; env = om*om*(1.f + 2.f*u); }
  float pref = 0.6324555320336759f * rinv * env;       // sqrt(2/5)
  float rad[8];
  #pragma unroll
  for (int b = 0; b < 8; b++)
    rad[b] = pref * __sinf((float)(b+1) * 3.14159265358979f * u);
  if (w == 0 && act) shu[e] = make_float4(ex*rinv, ey*rinv, ez*rinv, 0.f);

  int cl = lane & 15;                 // col within 16-tile
  int hb = (lane >> 4) * 8;           // k base within 32-step
  int rowq = (lane >> 4) * 4;         // D row base

  const short8v* wf1 = (const short8v*)wfrag;           // 16*64 frags
  const short8v* wf2 = ((const short8v*)wfrag) + 1024;  // 8*64 frags

  // ======================= layer 1 =======================
  {
    short8v hv0, hv1;
    #pragma unroll
    for (int j = 0; j < 16; j++){
      int h = w*16 + j;
      float ah = 0.f;
      #pragma unroll
      for (int b = 0; b < 8; b++) ah += rad[b] * rW1a[b*64 + h];   // uniform -> s_load
      float hid = ah / (1.f + __expf(-ah));
      unsigned short hb16 = f2bf(hid);
      if (j < 8) hv0[j] = (short)hb16; else hv1[j-8] = (short)hb16;
    }
    *(short8v*)&s_hid[lane*72 + w*16]     = hv0;
    *(short8v*)&s_hid[lane*72 + w*16 + 8] = hv1;
  }
  __syncthreads();

  // A frags: e = e0 + 16w + (lane&15), k = hb + j (+32 for step 1)
  short8v a0 = *(short8v*)&s_hid[(w*16 + cl)*72 + hb];
  short8v a1 = *(short8v*)&s_hid[(w*16 + cl)*72 + hb + 32];
  __syncthreads();                    // all reads done -> LDS free for layer 2

  {
    f32x4 ax[4], ay[4];
    #pragma unroll
    for (int t = 0; t < 4; t++){
      ax[t] = (f32x4)(0.f); ay[t] = (f32x4)(0.f);
    }
    #pragma unroll
    for (int t = 0; t < 4; t++){
      short8v bx0 = wf1[(t*4+0)*64 + lane];   // coalesced 16B/lane
      short8v bx1 = wf1[(t*4+1)*64 + lane];
      short8v by0 = wf1[(t*4+2)*64 + lane];
      short8v by1 = wf1[(t*4+3)*64 + lane];
      ax[t] = __builtin_amdgcn_mfma_f32_16x16x32_bf16(a0, bx0, ax[t], 0, 0, 0);
      ax[t] = __builtin_amdgcn_mfma_f32_16x16x32_bf16(a1, bx1, ax[t], 0, 0, 0);
      ay[t] = __builtin_amdgcn_mfma_f32_16x16x32_bf16(a0, by0, ay[t], 0, 0, 0);
      ay[t] = __builtin_amdgcn_mfma_f32_16x16x32_bf16(a1, by1, ay[t], 0, 0, 0);
    }
    #pragma unroll
    for (int t = 0; t < 4; t++){
      #pragma unroll
      for (int i = 0; i < 4; i++){
        int er = e0 + w*16 + rowq + i;
        if (er < N_EDGES)
          rw12[(size_t)er*64 + t*16 + cl] = make_float2(ax[t][i], ay[t][i]);
      }
    }
  }

  // ======================= layer 2 =======================
  {
    short8v hv0, hv1;
    #pragma unroll
    for (int j = 0; j < 16; j++){
      int h = w*16 + j;
      float ah = 0.f;
      #pragma unroll
      for (int b = 0; b < 8; b++) ah += rad[b] * rW1b[b*64 + h];
      float hid = ah / (1.f + __expf(-ah));
      unsigned short hb16 = f2bf(hid);
      if (j < 8) hv0[j] = (short)hb16; else hv1[j-8] = (short)hb16;
    }
    *(short8v*)&s_hid[lane*72 + w*16]     = hv0;
    *(short8v*)&s_hid[lane*72 + w*16 + 8] = hv1;
  }
  __syncthreads();

  short8v c0f = *(short8v*)&s_hid[(w*16 + cl)*72 + hb];
  short8v c1f = *(short8v*)&s_hid[(w*16 + cl)*72 + hb + 32];

  {
    f32x4 acc[4];
    #pragma unroll
    for (int t = 0; t < 4; t++) acc[t] = (f32x4)(0.f);
    #pragma unroll
    for (int t = 0; t < 4; t++){
      short8v b0 = wf2[(t*2+0)*64 + lane];
      short8v b1 = wf2[(t*2+1)*64 + lane];
      acc[t] = __builtin_amdgcn_mfma_f32_16x16x32_bf16(c0f, b0, acc[t], 0, 0, 0);
      acc[t] = __builtin_amdgcn_mfma_f32_16x16x32_bf16(c1f, b1, acc[t], 0, 0, 0);
    }
    #pragma unroll
    for (int t = 0; t < 4; t++){
      #pragma unroll
      for (int i = 0; i < 4; i++){
        int er = e0 + w*16 + rowq + i;
        if (er < N_EDGES)
          rwB[(size_t)er*64 + t*16 + cl] = acc[t][i];
      }
    }
  }
}

__global__ void k_fill(const int* __restrict__ recv, int* __restrict__ cursor, int* __restrict__ elist){
  int i = blockIdx.x*blockDim.x + threadIdx.x;
  if (i < N_EDGES){ int pos = atomicAdd(&cursor[recv[i]], 1); elist[pos] = i; }
}

// ---------- pass-1 gather + node transforms (1 wave per node, no weights) ----------
__global__ __launch_bounds__(256) void k_node1(
  const int* __restrict__ senders, const int* __restrict__ species,
  const int* __restrict__ starts, const int* __restrict__ elist,
  const float4* __restrict__ shu,
  const float2* __restrict__ rw12, const float* __restrict__ h1,
  const float* __restrict__ selT,
  const float* __restrict__ pw, const float* __restrict__ uwv,
  const float* __restrict__ row,
  const float* __restrict__ linup2, const float* __restrict__ resT,
  float* __restrict__ out,
  float4* __restrict__ outvo4, float* __restrict__ reso)
{
  int lane  = threadIdx.x & 63;
  int wslot = threadIdx.x >> 6;
  int n = blockIdx.x*4 + wslot;          // grid exact: 2500*4 = 10000
  __shared__ float4 sacc[4][64];

  int s0 = __builtin_amdgcn_readfirstlane(starts[n]);
  int s1 = __builtin_amdgcn_readfirstlane(starts[n+1]);
  int sp = __builtin_amdgcn_readfirstlane(species[n]);

  float acc0 = 0.f, acc1 = 0.f, acc2 = 0.f, acc3 = 0.f;
  for (int base = s0; base < s1; base += 64){
    int m = min(64, s1 - base);
    int e_l = 0, snd_l = 0;
    if (lane < m){
      e_l   = elist[base + lane];
      snd_l = senders[e_l];
    }
    int t = 0;
    for (; t+2 <= m; t += 2){
      int ea = __builtin_amdgcn_readfirstlane(__shfl(e_l, t, 64));
      int sa = __builtin_amdgcn_readfirstlane(__shfl(snd_l, t, 64));
      int eb = __builtin_amdgcn_readfirstlane(__shfl(e_l, t+1, 64));
      int sb = __builtin_amdgcn_readfirstlane(__shfl(snd_l, t+1, 64));
      float2 rva = rw12[(size_t)ea*64 + lane];
      float  h1a = h1[sa*64 + lane];
      float4 sva = shu[ea];
      float2 rvb = rw12[(size_t)eb*64 + lane];
      float  h1b = h1[sb*64 + lane];
      float4 svb = shu[eb];
      acc0 += rva.x * h1a;
      float ma = rva.y * h1a;
      acc1 += ma*sva.x; acc2 += ma*sva.y; acc3 += ma*sva.z;
      acc0 += rvb.x * h1b;
      float mb = rvb.y * h1b;
      acc1 += mb*svb.x; acc2 += mb*svb.y; acc3 += mb*svb.z;
    }
    if (t < m){
      int ea = __builtin_amdgcn_readfirstlane(__shfl(e_l, t, 64));
      int sa = __builtin_amdgcn_readfirstlane(__shfl(snd_l, t, 64));
      float2 rva = rw12[(size_t)ea*64 + lane];
      float  h1a = h1[sa*64 + lane];
      float4 sva = shu[ea];
      acc0 += rva.x * h1a;
      float ma = rva.y * h1a;
      acc1 += ma*sva.x; acc2 += ma*sva.y; acc3 += ma*sva.z;
    }
  }
  const float c10 = 0.1f;                      // 1/AVG_NEIGH
  const float c13 = 0.17320508075688773f;      // sqrt(3)/10
  sacc[wslot][lane] = make_float4(acc0*c10, acc1*c13, acc2*c13, acc3*c13);
  asm volatile("s_waitcnt lgkmcnt(0)" ::: "memory");

  // feats[c,k] = sum_d selW[c,d] * agg[d,k]
  const float* selp = selT + sp*4096;
  float f0 = 0.f, f1 = 0.f, f2 = 0.f, f3 = 0.f;
  #pragma unroll 8
  for (int d = 0; d < 64; d++){
    float wv = selp[d*64 + lane];
    float4 a = sacc[wslot][d];
    f0 += wv*a.x; f1 += wv*a.y; f2 += wv*a.z; f3 += wv*a.w;
  }

  float s = f0;
  const float* pwp = pw  + sp*192;
  const float* uwp = uwv + sp*192;
  float pw0 = pwp[lane], pw1 = pwp[64+lane], pw2 = pwp[128+lane];
  float uw0 = uwp[lane], uw1 = uwp[64+lane], uw2 = uwp[128+lane];
  float ss = s*s;
  float o0  = pw0*s + pw1*ss + pw2*ss*s;
  float uco = uw0 + uw1*s + uw2*ss;

  // ro1 = sum_c o0[c]*row[c]
  float rv = o0 * row[lane];
  #pragma unroll
  for (int off = 32; off >= 1; off >>= 1) rv += __shfl_xor(rv, off, 64);
  if (lane == 0) out[n*2 + 0] = rv;

  // stage o0, compute h2 and res
  float* so = reinterpret_cast<float*>(&sacc[wslot][0]);
  asm volatile("s_waitcnt lgkmcnt(0)" ::: "memory");
  so[lane] = o0;
  asm volatile("s_waitcnt lgkmcnt(0)" ::: "memory");

  float hh = 0.f, rr = 0.f;
  const float* resp = resT + sp*4096;
  #pragma unroll 8
  for (int d = 0; d < 64; d++){
    float od = so[d];
    hh += od * linup2[d*64 + lane];
    rr += od * resp[d*64 + lane];
  }
  outvo4[n*64 + lane] = make_float4(uco*f1, uco*f2, uco*f3, hh);  // .w = h2
  reso[n*64 + lane] = rr;
}

// ---------- pass-2 gather + readout (1 wave per node) ----------
__global__ __launch_bounds__(256) void k_node2(
  const int* __restrict__ senders, const int* __restrict__ species,
  const int* __restrict__ starts, const int* __restrict__ elist,
  const float4* __restrict__ shu,
  const float* __restrict__ rwB,
  const float4* __restrict__ outvo4, const float* __restrict__ reso,
  const float* __restrict__ pw2,
  const float* __restrict__ roW1, const float* __restrict__ roW2,
  float* __restrict__ out)
{
  int lane  = threadIdx.x & 63;
  int wslot = threadIdx.x >> 6;
  int n = blockIdx.x*4 + wslot;
  __shared__ float sout[4][64];

  int s0 = __builtin_amdgcn_readfirstlane(starts[n]);
  int s1 = __builtin_amdgcn_readfirstlane(starts[n+1]);
  int sp = __builtin_amdgcn_readfirstlane(species[n]);

  float acc = 0.f;
  for (int base = s0; base < s1; base += 64){
    int m = min(64, s1 - base);
    int e_l = 0, snd_l = 0;
    if (lane < m){
      e_l   = elist[base + lane];
      snd_l = senders[e_l];
    }
    int t = 0;
    for (; t+2 <= m; t += 2){
      int ea = __builtin_amdgcn_readfirstlane(__shfl(e_l, t, 64));
      int sa = __builtin_amdgcn_readfirstlane(__shfl(snd_l, t, 64));
      int eb = __builtin_amdgcn_readfirstlane(__shfl(e_l, t+1, 64));
      int sb = __builtin_amdgcn_readfirstlane(__shfl(snd_l, t+1, 64));
      float rwa = rwB[(size_t)ea*64 + lane];
      float4 ova = outvo4[sa*64 + lane];
      float4 sva = shu[ea];
      float rwb = rwB[(size_t)eb*64 + lane];
      float4 ovb = outvo4[sb*64 + lane];
      float4 svb = shu[eb];
      acc += rwa * (ova.w + ova.x*sva.x + ova.y*sva.y + ova.z*sva.z);
      acc += rwb * (ovb.w + ovb.x*svb.x + ovb.y*svb.y + ovb.z*svb.z);
    }
    if (t < m){
      int ea = __builtin_amdgcn_readfirstlane(__shfl(e_l, t, 64));
      int sa = __builtin_amdgcn_readfirstlane(__shfl(snd_l, t, 64));
      float rwa = rwB[(size_t)ea*64 + lane];
      float4 ova = outvo4[sa*64 + lane];
      float4 sva = shu[ea];
      acc += rwa * (ova.w + ova.x*sva.x + ova.y*sva.y + ova.z*sva.z);
    }
  }
  float s2 = acc * 0.1f;
  const float* p2 = pw2 + sp*192;
  float q0 = p2[lane], q1 = p2[64+lane], q2 = p2[128+lane];
  float s2s = s2*s2;
  float o2 = q0*s2 + q1*s2s + q2*s2s*s2 + reso[n*64 + lane];

  sout[wslot][lane] = o2;
  asm volatile("s_waitcnt lgkmcnt(0)" ::: "memory");

  // ro2 = silu(out2 @ roW1) @ roW2
  int j = lane & 15, g = lane >> 4;
  float qp = 0.f;
  #pragma unroll
  for (int t = 0; t < 16; t++){
    int c = g*16 + t;
    qp += sout[wslot][c] * roW1[c*16 + j];
  }
  qp += __shfl_xor(qp, 16, 64);
  qp += __shfl_xor(qp, 32, 64);
  float sil = qp / (1.f + __expf(-qp));
  float contrib = sil * roW2[j];
  contrib += __shfl_xor(contrib, 1, 64);
  contrib += __shfl_xor(contrib, 2, 64);
  contrib += __shfl_xor(contrib, 4, 64);
  contrib += __shfl_xor(contrib, 8, 64);
  if (lane == 0) out[n*2 + 1] = contrib;
}

extern "C" void kernel_launch(void* const* d_in, const int* in_sizes, int n_in,
                              void* d_out, int out_size, void* d_ws, size_t ws_size,
                              hipStream_t stream)
{
  const float* ev     = (const float*)d_in[0];
  const int*   spec   = (const int*)  d_in[1];
  const int*   send   = (const int*)  d_in[2];
  const int*   recv   = (const int*)  d_in[3];
  const float* embedW = (const float*)d_in[4];
  const float* l1_lin = (const float*)d_in[5];
  const float* l1_rW1 = (const float*)d_in[6];
  const float* l1_rW2 = (const float*)d_in[7];
  const float* l1_sel = (const float*)d_in[8];
  const float* l1_pw  = (const float*)d_in[9];
  const float* l1_uw  = (const float*)d_in[10];
  const float* l1_row = (const float*)d_in[11];
  const float* l2_lin = (const float*)d_in[12];
  const float* l2_rW1 = (const float*)d_in[13];
  const float* l2_rW2 = (const float*)d_in[14];
  const float* l2_res = (const float*)d_in[15];
  const float* l2_pw  = (const float*)d_in[16];
  const float* l2_roW1= (const float*)d_in[17];
  const float* l2_roW2= (const float*)d_in[18];
  float* out = (float*)d_out;

  char* w = (char*)d_ws;
  float2* rw12  = (float2*)w; w += (size_t)N_EDGES*64*8;   // 51.2 MB
  float*  rwB   = (float*)w;  w += (size_t)N_EDGES*64*4;   // 25.6 MB
  float*  h1    = (float*)w;  w += (size_t)N_NODES*64*4;
  float4* outvo4= (float4*)w; w += (size_t)N_NODES*64*16;
  float*  reso  = (float*)w;  w += (size_t)N_NODES*64*4;
  float*  selT  = (float*)w;  w += (size_t)NSPEC*4096*4;
  float*  resT  = (float*)w;  w += (size_t)NSPEC*4096*4;
  float4* shu   = (float4*)w; w += (size_t)N_EDGES*16;
  unsigned short* wfrag = (unsigned short*)w; w += 12288*2;
  int* starts = (int*)w;      w += (size_t)(N_NODES+1)*4;
  int* cursor = (int*)w;      w += (size_t)N_NODES*4;
  int* elist  = (int*)w;      w += (size_t)N_EDGES*4;

  k_pre  <<<2748, 256, 0, stream>>>(cursor, l1_sel, l2_res, selT, resT,
                                    spec, embedW, l1_lin, h1,
                                    l1_rW2, l2_rW2, wfrag);
  k_count<<<(N_EDGES+255)/256, 256, 0, stream>>>(recv, cursor);
  k_scanrw<<<1 + (N_EDGES+63)/64, 256, 0, stream>>>(cursor, starts,
        ev, l1_rW1, l2_rW1, wfrag, rw12, rwB, shu);
  k_fill <<<(N_EDGES+255)/256, 256, 0, stream>>>(recv, cursor, elist);
  k_node1<<<N_NODES/4, 256, 0, stream>>>(send, spec, starts, elist, shu, rw12, h1,
        selT, l1_pw, l1_uw, l1_row, l2_lin, resT, out, outvo4, reso);
  k_node2<<<N_NODES/4, 256, 0, stream>>>(send, spec, starts, elist, shu, rwB,
        outvo4, reso, l2_pw, l2_roW1, l2_roW2, out);
}

// Round 10
// 98.471 us; speedup vs baseline: 4.9663x; 1.0948x over previous
//
#include <hip/hip_runtime.h>
#include <hip/hip_bf16.h>
#include <math.h>

#define N_NODES 10000
#define N_EDGES 100000
#define NCH 64
#define NSPEC 10

typedef __attribute__((ext_vector_type(8))) short short8v;
typedef __attribute__((ext_vector_type(4))) float f32x4;

static __device__ __forceinline__ unsigned short f2bf(float f){
  unsigned u = __float_as_uint(f);
  u += 0x7fff + ((u >> 16) & 1);          // round-to-nearest-even
  return (unsigned short)(u >> 16);
}
static __device__ __forceinline__ float bf2f(unsigned u){
  return __uint_as_float(u << 16);
}
static __device__ __forceinline__ unsigned packbf(float a, float b){
  return (unsigned)f2bf(a) | ((unsigned)f2bf(b) << 16);
}

// ---------- CSR count ----------
__global__ void k_count(const int* __restrict__ recv, int* __restrict__ cnt){
  int i = blockIdx.x*blockDim.x + threadIdx.x;
  if (i < N_EDGES) atomicAdd(&cnt[recv[i]], 1);
}

// ---------- fused prologue: zero cursor | transposes | h1 | bf16 B-fragments ----------
__global__ __launch_bounds__(256) void k_pre(
  int* __restrict__ cursor,
  const float* __restrict__ sel, const float* __restrict__ resw,
  float* __restrict__ selT, float* __restrict__ resT,
  const int* __restrict__ species, const float* __restrict__ embedW,
  const float* __restrict__ linup, float* __restrict__ h1,
  const float* __restrict__ rW2a, const float* __restrict__ rW2b,
  unsigned short* __restrict__ wfrag)
{
  int b = blockIdx.x;
  int tid = threadIdx.x;
  if (b < 40){                                  // zero cursor (10000 ints)
    int i = b*256 + tid;
    if (i < N_NODES) cursor[i] = 0;
  } else if (b < 200){                          // selT/resT transpose (40960 elems)
    int i = (b-40)*256 + tid;
    int s = i >> 12, r = i & 4095, d = r >> 6, c = r & 63;
    int src = s*4096 + c*64 + d;
    selT[i] = sel[src];
    resT[i] = resw[src];
  } else if (b < 2700){                         // h1 = embed[species] @ l1_lin_up
    int w = ((b-200)*256 + tid) >> 6;           // 2500 blocks * 4 = 10000
    int lane = tid & 63;
    int sp = __builtin_amdgcn_readfirstlane(species[w]);
    const float* x0 = embedW + sp*NCH;
    float acc = 0.f;
    #pragma unroll
    for (int d = 0; d < NCH; d++) acc += x0[d] * linup[d*NCH + lane];
    h1[w*NCH + lane] = acc;
  } else {                                      // bf16 B-fragments (12288 shorts)
    int i = (b-2700)*256 + tid;
    int slot = i >> 9;                          // 0..23
    int rem  = i & 511;
    int lane = rem >> 3, j = rem & 7;
    int cl = lane & 15, hb = (lane >> 4)*8;
    float v;
    if (slot < 16){
      int t = slot >> 2, f = slot & 3;
      int colofs = f >> 1, off = (f & 1)*32;
      v = rW2a[(hb + off + j)*256 + 4*(t*16 + cl) + colofs];
    } else {
      int s2 = slot - 16;
      int t = s2 >> 1, f = s2 & 1;
      int off = f*32;
      v = rW2b[(hb + off + j)*256 + 4*(t*16 + cl)];
    }
    wfrag[i] = f2bf(v);
  }
}

// ---------- block 0: CSR scan | blocks 1..: MFMA radial GEMM (both layers) ----------
// rw12p[e][c] = packed bf16 (col 4c, col 4c+1) of layer-1 radial MLP; shu[e]
// rwBp[e][c]  = bf16 col 4c of layer-2 radial MLP
__global__ __launch_bounds__(256) void k_scanrw(
    int* __restrict__ cnt_cursor, int* __restrict__ starts,
    const float* __restrict__ ev,
    const float* __restrict__ rW1a, const float* __restrict__ rW1b,
    const unsigned short* __restrict__ wfrag,
    unsigned* __restrict__ rw12p, unsigned short* __restrict__ rwBp,
    float4* __restrict__ shu)
{
  __shared__ short s_hid[64*72];       // [e][h] bf16, row stride 72 shorts (144B, 16B-aligned)

  int tid = threadIdx.x;

  if (blockIdx.x == 0){
    // coarsened scan: 256 threads, 40 nodes each (reuses s_hid as int buffer)
    int* stot = (int*)s_hid;
    int base = tid*40;
    int loc[40];
    int sum = 0;
    #pragma unroll
    for (int j = 0; j < 40; j++){
      int i = base + j;
      int v = (i < N_NODES) ? cnt_cursor[i] : 0;
      loc[j] = sum; sum += v;
    }
    stot[tid] = sum;
    __syncthreads();
    for (int off = 1; off < 256; off <<= 1){
      int t = (tid >= off) ? stot[tid-off] : 0;
      __syncthreads();
      stot[tid] += t;
      __syncthreads();
    }
    int excl = stot[tid] - sum;
    #pragma unroll
    for (int j = 0; j < 40; j++){
      int i = base + j;
      if (i < N_NODES){ int st = excl + loc[j]; starts[i] = st; cnt_cursor[i] = st; }
    }
    if (tid == 255) starts[N_NODES] = stot[255];
    return;
  }

  int e0 = (blockIdx.x-1)*64;
  int lane = tid & 63;
  int w = __builtin_amdgcn_readfirstlane(tid >> 6);    // wave id 0..3

  // geometry + bessel for edge e0+lane (4-way redundant across waves)
  int e = e0 + lane;
  bool act = (e < N_EDGES);
  float ex = 0.f, ey = 0.f, ez = 1.f;
  if (act){ ex = ev[e*3+0]; ey = ev[e*3+1]; ez = ev[e*3+2]; }
  float r = sqrtf(ex*ex + ey*ey + ez*ez + 1e-12f);
  float rinv = 1.0f / r;
  float u = r * 0.2f;
  float env = 0.f;
  if (u < 1.f){ float om = 1.f - u; env = om*om*(1.f + 2.f*u); }
  float pref = 0.6324555320336759f * rinv * env;       // sqrt(2/5)
  float rad[8];
  #pragma unroll
  for (int b = 0; b < 8; b++)
    rad[b] = pref * __sinf((float)(b+1) * 3.14159265358979f * u);
  if (w == 0 && act) shu[e] = make_float4(ex*rinv, ey*rinv, ez*rinv, 0.f);

  int cl = lane & 15;                 // col within 16-tile
  int hb = (lane >> 4) * 8;           // k base within 32-step
  int rowq = (lane >> 4) * 4;         // D row base

  const short8v* wf1 = (const short8v*)wfrag;           // 16*64 frags
  const short8v* wf2 = ((const short8v*)wfrag) + 1024;  // 8*64 frags

  // ======================= layer 1 =======================
  {
    short8v hv0, hv1;
    #pragma unroll
    for (int j = 0; j < 16; j++){
      int h = w*16 + j;
      float ah = 0.f;
      #pragma unroll
      for (int b = 0; b < 8; b++) ah += rad[b] * rW1a[b*64 + h];   // uniform -> s_load
      float hid = ah / (1.f + __expf(-ah));
      unsigned short hb16 = f2bf(hid);
      if (j < 8) hv0[j] = (short)hb16; else hv1[j-8] = (short)hb16;
    }
    *(short8v*)&s_hid[lane*72 + w*16]     = hv0;
    *(short8v*)&s_hid[lane*72 + w*16 + 8] = hv1;
  }
  __syncthreads();

  short8v a0 = *(short8v*)&s_hid[(w*16 + cl)*72 + hb];
  short8v a1 = *(short8v*)&s_hid[(w*16 + cl)*72 + hb + 32];
  __syncthreads();                    // LDS free for layer 2

  {
    f32x4 ax[4], ay[4];
    #pragma unroll
    for (int t = 0; t < 4; t++){
      ax[t] = (f32x4)(0.f); ay[t] = (f32x4)(0.f);
    }
    #pragma unroll
    for (int t = 0; t < 4; t++){
      short8v bx0 = wf1[(t*4+0)*64 + lane];   // coalesced 16B/lane
      short8v bx1 = wf1[(t*4+1)*64 + lane];
      short8v by0 = wf1[(t*4+2)*64 + lane];
      short8v by1 = wf1[(t*4+3)*64 + lane];
      ax[t] = __builtin_amdgcn_mfma_f32_16x16x32_bf16(a0, bx0, ax[t], 0, 0, 0);
      ax[t] = __builtin_amdgcn_mfma_f32_16x16x32_bf16(a1, bx1, ax[t], 0, 0, 0);
      ay[t] = __builtin_amdgcn_mfma_f32_16x16x32_bf16(a0, by0, ay[t], 0, 0, 0);
      ay[t] = __builtin_amdgcn_mfma_f32_16x16x32_bf16(a1, by1, ay[t], 0, 0, 0);
    }
    #pragma unroll
    for (int t = 0; t < 4; t++){
      #pragma unroll
      for (int i = 0; i < 4; i++){
        int er = e0 + w*16 + rowq + i;
        if (er < N_EDGES)
          rw12p[(size_t)er*64 + t*16 + cl] = packbf(ax[t][i], ay[t][i]);
      }
    }
  }

  // ======================= layer 2 =======================
  {
    short8v hv0, hv1;
    #pragma unroll
    for (int j = 0; j < 16; j++){
      int h = w*16 + j;
      float ah = 0.f;
      #pragma unroll
      for (int b = 0; b < 8; b++) ah += rad[b] * rW1b[b*64 + h];
      float hid = ah / (1.f + __expf(-ah));
      unsigned short hb16 = f2bf(hid);
      if (j < 8) hv0[j] = (short)hb16; else hv1[j-8] = (short)hb16;
    }
    *(short8v*)&s_hid[lane*72 + w*16]     = hv0;
    *(short8v*)&s_hid[lane*72 + w*16 + 8] = hv1;
  }
  __syncthreads();

  short8v c0f = *(short8v*)&s_hid[(w*16 + cl)*72 + hb];
  short8v c1f = *(short8v*)&s_hid[(w*16 + cl)*72 + hb + 32];

  {
    f32x4 acc[4];
    #pragma unroll
    for (int t = 0; t < 4; t++) acc[t] = (f32x4)(0.f);
    #pragma unroll
    for (int t = 0; t < 4; t++){
      short8v b0 = wf2[(t*2+0)*64 + lane];
      short8v b1 = wf2[(t*2+1)*64 + lane];
      acc[t] = __builtin_amdgcn_mfma_f32_16x16x32_bf16(c0f, b0, acc[t], 0, 0, 0);
      acc[t] = __builtin_amdgcn_mfma_f32_16x16x32_bf16(c1f, b1, acc[t], 0, 0, 0);
    }
    #pragma unroll
    for (int t = 0; t < 4; t++){
      #pragma unroll
      for (int i = 0; i < 4; i++){
        int er = e0 + w*16 + rowq + i;
        if (er < N_EDGES)
          rwBp[(size_t)er*64 + t*16 + cl] = f2bf(acc[t][i]);
      }
    }
  }
}

__global__ void k_fill(const int* __restrict__ recv, int* __restrict__ cursor, int* __restrict__ elist){
  int i = blockIdx.x*blockDim.x + threadIdx.x;
  if (i < N_EDGES){ int pos = atomicAdd(&cursor[recv[i]], 1); elist[pos] = i; }
}

// ---------- pass-1 gather + node transforms (1 wave per node) ----------
__global__ __launch_bounds__(256) void k_node1(
  const int* __restrict__ senders, const int* __restrict__ species,
  const int* __restrict__ starts, const int* __restrict__ elist,
  const float4* __restrict__ shu,
  const unsigned* __restrict__ rw12p, const float* __restrict__ h1,
  const float* __restrict__ selT,
  const float* __restrict__ pw, const float* __restrict__ uwv,
  const float* __restrict__ row,
  const float* __restrict__ linup2, const float* __restrict__ resT,
  float* __restrict__ out,
  uint2* __restrict__ outvp, float* __restrict__ reso)
{
  int lane  = threadIdx.x & 63;
  int wslot = threadIdx.x >> 6;
  int n = blockIdx.x*4 + wslot;          // grid exact: 2500*4 = 10000
  __shared__ float4 sacc[4][64];

  int s0 = __builtin_amdgcn_readfirstlane(starts[n]);
  int s1 = __builtin_amdgcn_readfirstlane(starts[n+1]);
  int sp = __builtin_amdgcn_readfirstlane(species[n]);

  float acc0 = 0.f, acc1 = 0.f, acc2 = 0.f, acc3 = 0.f;
  for (int base = s0; base < s1; base += 64){
    int m = min(64, s1 - base);
    int e_l = 0, snd_l = 0;
    if (lane < m){
      e_l   = elist[base + lane];
      snd_l = senders[e_l];
    }
    int t = 0;
    for (; t+2 <= m; t += 2){
      int ea = __builtin_amdgcn_readfirstlane(__shfl(e_l, t, 64));
      int sa = __builtin_amdgcn_readfirstlane(__shfl(snd_l, t, 64));
      int eb = __builtin_amdgcn_readfirstlane(__shfl(e_l, t+1, 64));
      int sb = __builtin_amdgcn_readfirstlane(__shfl(snd_l, t+1, 64));
      unsigned pa = rw12p[(size_t)ea*64 + lane];
      float  h1a = h1[sa*64 + lane];
      float4 sva = shu[ea];
      unsigned pb = rw12p[(size_t)eb*64 + lane];
      float  h1b = h1[sb*64 + lane];
      float4 svb = shu[eb];
      acc0 += bf2f(pa & 0xffffu) * h1a;
      float ma = bf2f(pa >> 16) * h1a;
      acc1 += ma*sva.x; acc2 += ma*sva.y; acc3 += ma*sva.z;
      acc0 += bf2f(pb & 0xffffu) * h1b;
      float mb = bf2f(pb >> 16) * h1b;
      acc1 += mb*svb.x; acc2 += mb*svb.y; acc3 += mb*svb.z;
    }
    if (t < m){
      int ea = __builtin_amdgcn_readfirstlane(__shfl(e_l, t, 64));
      int sa = __builtin_amdgcn_readfirstlane(__shfl(snd_l, t, 64));
      unsigned pa = rw12p[(size_t)ea*64 + lane];
      float  h1a = h1[sa*64 + lane];
      float4 sva = shu[ea];
      acc0 += bf2f(pa & 0xffffu) * h1a;
      float ma = bf2f(pa >> 16) * h1a;
      acc1 += ma*sva.x; acc2 += ma*sva.y; acc3 += ma*sva.z;
    }
  }
  const float c10 = 0.1f;                      // 1/AVG_NEIGH
  const float c13 = 0.17320508075688773f;      // sqrt(3)/10
  sacc[wslot][lane] = make_float4(acc0*c10, acc1*c13, acc2*c13, acc3*c13);
  asm volatile("s_waitcnt lgkmcnt(0)" ::: "memory");

  // feats[c,k] = sum_d selW[c,d] * agg[d,k]
  const float* selp = selT + sp*4096;
  float f0 = 0.f, f1 = 0.f, f2 = 0.f, f3 = 0.f;
  #pragma unroll 8
  for (int d = 0; d < 64; d++){
    float wv = selp[d*64 + lane];
    float4 a = sacc[wslot][d];
    f0 += wv*a.x; f1 += wv*a.y; f2 += wv*a.z; f3 += wv*a.w;
  }

  float s = f0;
  const float* pwp = pw  + sp*192;
  const float* uwp = uwv + sp*192;
  float pw0 = pwp[lane], pw1 = pwp[64+lane], pw2 = pwp[128+lane];
  float uw0 = uwp[lane], uw1 = uwp[64+lane], uw2 = uwp[128+lane];
  float ss = s*s;
  float o0  = pw0*s + pw1*ss + pw2*ss*s;
  float uco = uw0 + uw1*s + uw2*ss;

  // ro1 = sum_c o0[c]*row[c]
  float rv = o0 * row[lane];
  #pragma unroll
  for (int off = 32; off >= 1; off >>= 1) rv += __shfl_xor(rv, off, 64);
  if (lane == 0) out[n*2 + 0] = rv;

  // stage o0, compute h2 and res
  float* so = reinterpret_cast<float*>(&sacc[wslot][0]);
  asm volatile("s_waitcnt lgkmcnt(0)" ::: "memory");
  so[lane] = o0;
  asm volatile("s_waitcnt lgkmcnt(0)" ::: "memory");

  float hh = 0.f, rr = 0.f;
  const float* resp = resT + sp*4096;
  #pragma unroll 8
  for (int d = 0; d < 64; d++){
    float od = so[d];
    hh += od * linup2[d*64 + lane];
    rr += od * resp[d*64 + lane];
  }
  uint2 op;
  op.x = packbf(uco*f1, uco*f2);
  op.y = packbf(uco*f3, hh);
  outvp[n*64 + lane] = op;
  reso[n*64 + lane] = rr;
}

// ---------- pass-2 gather + readout (1 wave per node) ----------
__global__ __launch_bounds__(256) void k_node2(
  const int* __restrict__ senders, const int* __restrict__ species,
  const int* __restrict__ starts, const int* __restrict__ elist,
  const float4* __restrict__ shu,
  const unsigned short* __restrict__ rwBp,
  const uint2* __restrict__ outvp, const float* __restrict__ reso,
  const float* __restrict__ pw2,
  const float* __restrict__ roW1, const float* __restrict__ roW2,
  float* __restrict__ out)
{
  int lane  = threadIdx.x & 63;
  int wslot = threadIdx.x >> 6;
  int n = blockIdx.x*4 + wslot;
  __shared__ float sout[4][64];

  int s0 = __builtin_amdgcn_readfirstlane(starts[n]);
  int s1 = __builtin_amdgcn_readfirstlane(starts[n+1]);
  int sp = __builtin_amdgcn_readfirstlane(species[n]);

  float acc = 0.f;
  for (int base = s0; base < s1; base += 64){
    int m = min(64, s1 - base);
    int e_l = 0, snd_l = 0;
    if (lane < m){
      e_l   = elist[base + lane];
      snd_l = senders[e_l];
    }
    int t = 0;
    for (; t+2 <= m; t += 2){
      int ea = __builtin_amdgcn_readfirstlane(__shfl(e_l, t, 64));
      int sa = __builtin_amdgcn_readfirstlane(__shfl(snd_l, t, 64));
      int eb = __builtin_amdgcn_readfirstlane(__shfl(e_l, t+1, 64));
      int sb = __builtin_amdgcn_readfirstlane(__shfl(snd_l, t+1, 64));
      float rwa = bf2f(rwBp[(size_t)ea*64 + lane]);
      uint2 ova = outvp[sa*64 + lane];
      float4 sva = shu[ea];
      float rwb = bf2f(rwBp[(size_t)eb*64 + lane]);
      uint2 ovb = outvp[sb*64 + lane];
      float4 svb = shu[eb];
      acc += rwa * (bf2f(ova.y >> 16) + bf2f(ova.x & 0xffffu)*sva.x
                    + bf2f(ova.x >> 16)*sva.y + bf2f(ova.y & 0xffffu)*sva.z);
      acc += rwb * (bf2f(ovb.y >> 16) + bf2f(ovb.x & 0xffffu)*svb.x
                    + bf2f(ovb.x >> 16)*svb.y + bf2f(ovb.y & 0xffffu)*svb.z);
    }
    if (t < m){
      int ea = __builtin_amdgcn_readfirstlane(__shfl(e_l, t, 64));
      int sa = __builtin_amdgcn_readfirstlane(__shfl(snd_l, t, 64));
      float rwa = bf2f(rwBp[(size_t)ea*64 + lane]);
      uint2 ova = outvp[sa*64 + lane];
      float4 sva = shu[ea];
      acc += rwa * (bf2f(ova.y >> 16) + bf2f(ova.x & 0xffffu)*sva.x
                    + bf2f(ova.x >> 16)*sva.y + bf2f(ova.y & 0xffffu)*sva.z);
    }
  }
  float s2 = acc * 0.1f;
  const float* p2 = pw2 + sp*192;
  float q0 = p2[lane], q1 = p2[64+lane], q2 = p2[128+lane];
  float s2s = s2*s2;
  float o2 = q0*s2 + q1*s2s + q2*s2s*s2 + reso[n*64 + lane];

  sout[wslot][lane] = o2;
  asm volatile("s_waitcnt lgkmcnt(0)" ::: "memory");

  // ro2 = silu(out2 @ roW1) @ roW2
  int j = lane & 15, g = lane >> 4;
  float qp = 0.f;
  #pragma unroll
  for (int t = 0; t < 16; t++){
    int c = g*16 + t;
    qp += sout[wslot][c] * roW1[c*16 + j];
  }
  qp += __shfl_xor(qp, 16, 64);
  qp += __shfl_xor(qp, 32, 64);
  float sil = qp / (1.f + __expf(-qp));
  float contrib = sil * roW2[j];
  contrib += __shfl_xor(contrib, 1, 64);
  contrib += __shfl_xor(contrib, 2, 64);
  contrib += __shfl_xor(contrib, 4, 64);
  contrib += __shfl_xor(contrib, 8, 64);
  if (lane == 0) out[n*2 + 1] = contrib;
}

extern "C" void kernel_launch(void* const* d_in, const int* in_sizes, int n_in,
                              void* d_out, int out_size, void* d_ws, size_t ws_size,
                              hipStream_t stream)
{
  const float* ev     = (const float*)d_in[0];
  const int*   spec   = (const int*)  d_in[1];
  const int*   send   = (const int*)  d_in[2];
  const int*   recv   = (const int*)  d_in[3];
  const float* embedW = (const float*)d_in[4];
  const float* l1_lin = (const float*)d_in[5];
  const float* l1_rW1 = (const float*)d_in[6];
  const float* l1_rW2 = (const float*)d_in[7];
  const float* l1_sel = (const float*)d_in[8];
  const float* l1_pw  = (const float*)d_in[9];
  const float* l1_uw  = (const float*)d_in[10];
  const float* l1_row = (const float*)d_in[11];
  const float* l2_lin = (const float*)d_in[12];
  const float* l2_rW1 = (const float*)d_in[13];
  const float* l2_rW2 = (const float*)d_in[14];
  const float* l2_res = (const float*)d_in[15];
  const float* l2_pw  = (const float*)d_in[16];
  const float* l2_roW1= (const float*)d_in[17];
  const float* l2_roW2= (const float*)d_in[18];
  float* out = (float*)d_out;

  char* w = (char*)d_ws;
  unsigned*       rw12p = (unsigned*)w;       w += (size_t)N_EDGES*64*4;  // 25.6 MB
  unsigned short* rwBp  = (unsigned short*)w; w += (size_t)N_EDGES*64*2;  // 12.8 MB
  float*  h1    = (float*)w;  w += (size_t)N_NODES*64*4;
  uint2*  outvp = (uint2*)w;  w += (size_t)N_NODES*64*8;                  // 5.12 MB
  float*  reso  = (float*)w;  w += (size_t)N_NODES*64*4;
  float*  selT  = (float*)w;  w += (size_t)NSPEC*4096*4;
  float*  resT  = (float*)w;  w += (size_t)NSPEC*4096*4;
  float4* shu   = (float4*)w; w += (size_t)N_EDGES*16;
  unsigned short* wfrag = (unsigned short*)w; w += 12288*2;
  int* starts = (int*)w;      w += (size_t)(N_NODES+1)*4;
  int* cursor = (int*)w;      w += (size_t)N_NODES*4;
  int* elist  = (int*)w;      w += (size_t)N_EDGES*4;

  k_pre  <<<2748, 256, 0, stream>>>(cursor, l1_sel, l2_res, selT, resT,
                                    spec, embedW, l1_lin, h1,
                                    l1_rW2, l2_rW2, wfrag);
  k_count<<<(N_EDGES+255)/256, 256, 0, stream>>>(recv, cursor);
  k_scanrw<<<1 + (N_EDGES+63)/64, 256, 0, stream>>>(cursor, starts,
        ev, l1_rW1, l2_rW1, wfrag, rw12p, rwBp, shu);
  k_fill <<<(N_EDGES+255)/256, 256, 0, stream>>>(recv, cursor, elist);
  k_node1<<<N_NODES/4, 256, 0, stream>>>(send, spec, starts, elist, shu, rw12p, h1,
        selT, l1_pw, l1_uw, l1_row, l2_lin, resT, out, outvp, reso);
  k_node2<<<N_NODES/4, 256, 0, stream>>>(send, spec, starts, elist, shu, rwBp,
        outvp, reso, l2_pw, l2_roW1, l2_roW2, out);
}

// Round 11
// 92.661 us; speedup vs baseline: 5.2777x; 1.0627x over previous
//
#include <hip/hip_runtime.h>
#include <hip/hip_bf16.h>
#include <math.h>

#define N_NODES 10000
#define N_EDGES 100000
#define NCH 64
#define NSPEC 10

typedef __attribute__((ext_vector_type(8))) short short8v;
typedef __attribute__((ext_vector_type(4))) float f32x4;

static __device__ __forceinline__ unsigned short f2bf(float f){
  unsigned u = __float_as_uint(f);
  u += 0x7fff + ((u >> 16) & 1);          // round-to-nearest-even
  return (unsigned short)(u >> 16);
}
static __device__ __forceinline__ float bf2f(unsigned u){
  return __uint_as_float(u << 16);
}
static __device__ __forceinline__ unsigned packbf(float a, float b){
  return (unsigned)f2bf(a) | ((unsigned)f2bf(b) << 16);
}

// ---------- CSR count ----------
__global__ void k_count(const int* __restrict__ recv, int* __restrict__ cnt){
  int i = blockIdx.x*blockDim.x + threadIdx.x;
  if (i < N_EDGES) atomicAdd(&cnt[recv[i]], 1);
}

// ---------- fused prologue: zero cursor | transposes | h1(bf16) | bf16 B-fragments ----------
__global__ __launch_bounds__(256) void k_pre(
  int* __restrict__ cursor,
  const float* __restrict__ sel, const float* __restrict__ resw,
  float* __restrict__ selT, float* __restrict__ resT,
  const int* __restrict__ species, const float* __restrict__ embedW,
  const float* __restrict__ linup, unsigned short* __restrict__ h1p,
  const float* __restrict__ rW2a, const float* __restrict__ rW2b,
  unsigned short* __restrict__ wfrag)
{
  int b = blockIdx.x;
  int tid = threadIdx.x;
  if (b < 40){                                  // zero cursor (10000 ints)
    int i = b*256 + tid;
    if (i < N_NODES) cursor[i] = 0;
  } else if (b < 200){                          // selT/resT transpose (40960 elems)
    int i = (b-40)*256 + tid;
    int s = i >> 12, r = i & 4095, d = r >> 6, c = r & 63;
    int src = s*4096 + c*64 + d;
    selT[i] = sel[src];
    resT[i] = resw[src];
  } else if (b < 2700){                         // h1 = embed[species] @ l1_lin_up (bf16)
    int w = ((b-200)*256 + tid) >> 6;           // 2500 blocks * 4 = 10000
    int lane = tid & 63;
    int sp = __builtin_amdgcn_readfirstlane(species[w]);
    const float* x0 = embedW + sp*NCH;
    float acc = 0.f;
    #pragma unroll
    for (int d = 0; d < NCH; d++) acc += x0[d] * linup[d*NCH + lane];
    h1p[w*NCH + lane] = f2bf(acc);
  } else {                                      // bf16 B-fragments (12288 shorts)
    int i = (b-2700)*256 + tid;
    int slot = i >> 9;                          // 0..23
    int rem  = i & 511;
    int lane = rem >> 3, j = rem & 7;
    int cl = lane & 15, hb = (lane >> 4)*8;
    float v;
    if (slot < 16){
      int t = slot >> 2, f = slot & 3;
      int colofs = f >> 1, off = (f & 1)*32;
      v = rW2a[(hb + off + j)*256 + 4*(t*16 + cl) + colofs];
    } else {
      int s2 = slot - 16;
      int t = s2 >> 1, f = s2 & 1;
      int off = f*32;
      v = rW2b[(hb + off + j)*256 + 4*(t*16 + cl)];
    }
    wfrag[i] = f2bf(v);
  }
}

// ---------- block 0: CSR scan | blocks 1..: MFMA radial GEMM (both layers, 1 barrier) ----------
__global__ __launch_bounds__(256) void k_scanrw(
    int* __restrict__ cnt_cursor, int* __restrict__ starts,
    const float* __restrict__ ev,
    const float* __restrict__ rW1a, const float* __restrict__ rW1b,
    const unsigned short* __restrict__ wfrag,
    unsigned* __restrict__ rw12p, unsigned short* __restrict__ rwBp,
    float4* __restrict__ shu)
{
  __shared__ short s_hid1[64*72];      // [e][h] bf16, row stride 72 (144B)
  __shared__ short s_hid2[64*72];

  int tid = threadIdx.x;

  if (blockIdx.x == 0){
    // coarsened scan: 256 threads, 40 nodes each
    int* stot = (int*)s_hid1;
    int base = tid*40;
    int loc[40];
    int sum = 0;
    #pragma unroll
    for (int j = 0; j < 40; j++){
      int i = base + j;
      int v = (i < N_NODES) ? cnt_cursor[i] : 0;
      loc[j] = sum; sum += v;
    }
    stot[tid] = sum;
    __syncthreads();
    for (int off = 1; off < 256; off <<= 1){
      int t = (tid >= off) ? stot[tid-off] : 0;
      __syncthreads();
      stot[tid] += t;
      __syncthreads();
    }
    int excl = stot[tid] - sum;
    #pragma unroll
    for (int j = 0; j < 40; j++){
      int i = base + j;
      if (i < N_NODES){ int st = excl + loc[j]; starts[i] = st; cnt_cursor[i] = st; }
    }
    if (tid == 255) starts[N_NODES] = stot[255];
    return;
  }

  int e0 = (blockIdx.x-1)*64;
  int lane = tid & 63;
  int w = __builtin_amdgcn_readfirstlane(tid >> 6);    // wave id 0..3

  // geometry + bessel for edge e0+lane (4-way redundant across waves)
  int e = e0 + lane;
  bool act = (e < N_EDGES);
  float ex = 0.f, ey = 0.f, ez = 1.f;
  if (act){ ex = ev[e*3+0]; ey = ev[e*3+1]; ez = ev[e*3+2]; }
  float r = sqrtf(ex*ex + ey*ey + ez*ez + 1e-12f);
  float rinv = 1.0f / r;
  float u = r * 0.2f;
  float env = 0.f;
  if (u < 1.f){ float om = 1.f - u; env = om*om*(1.f + 2.f*u); }
  float pref = 0.6324555320336759f * rinv * env;       // sqrt(2/5)
  float rad[8];
  #pragma unroll
  for (int b = 0; b < 8; b++)
    rad[b] = pref * __sinf((float)(b+1) * 3.14159265358979f * u);
  if (w == 0 && act) shu[e] = make_float4(ex*rinv, ey*rinv, ez*rinv, 0.f);

  // hid for both layers (16 h per wave each), one barrier total
  {
    short8v hv0, hv1, gv0, gv1;
    #pragma unroll
    for (int j = 0; j < 16; j++){
      int h = w*16 + j;
      float a1 = 0.f, a2 = 0.f;
      #pragma unroll
      for (int b = 0; b < 8; b++){
        a1 += rad[b] * rW1a[b*64 + h];               // uniform -> s_load
        a2 += rad[b] * rW1b[b*64 + h];
      }
      float hd1 = a1 / (1.f + __expf(-a1));
      float hd2 = a2 / (1.f + __expf(-a2));
      unsigned short q1 = f2bf(hd1), q2 = f2bf(hd2);
      if (j < 8){ hv0[j] = (short)q1; gv0[j] = (short)q2; }
      else      { hv1[j-8] = (short)q1; gv1[j-8] = (short)q2; }
    }
    *(short8v*)&s_hid1[lane*72 + w*16]     = hv0;
    *(short8v*)&s_hid1[lane*72 + w*16 + 8] = hv1;
    *(short8v*)&s_hid2[lane*72 + w*16]     = gv0;
    *(short8v*)&s_hid2[lane*72 + w*16 + 8] = gv1;
  }
  __syncthreads();

  int cl = lane & 15;                 // col within 16-tile
  int hb = (lane >> 4) * 8;           // k base within 32-step
  int rowq = (lane >> 4) * 4;         // D row base

  short8v a0  = *(short8v*)&s_hid1[(w*16 + cl)*72 + hb];
  short8v a1  = *(short8v*)&s_hid1[(w*16 + cl)*72 + hb + 32];
  short8v c0f = *(short8v*)&s_hid2[(w*16 + cl)*72 + hb];
  short8v c1f = *(short8v*)&s_hid2[(w*16 + cl)*72 + hb + 32];

  const short8v* wf1 = (const short8v*)wfrag;           // 16*64 frags
  const short8v* wf2 = ((const short8v*)wfrag) + 1024;  // 8*64 frags

  f32x4 ax[4], ay[4], bc[4];
  #pragma unroll
  for (int t = 0; t < 4; t++){
    ax[t] = (f32x4)(0.f); ay[t] = (f32x4)(0.f); bc[t] = (f32x4)(0.f);
  }
  #pragma unroll
  for (int t = 0; t < 4; t++){
    short8v bx0 = wf1[(t*4+0)*64 + lane];   // coalesced 16B/lane
    short8v bx1 = wf1[(t*4+1)*64 + lane];
    short8v by0 = wf1[(t*4+2)*64 + lane];
    short8v by1 = wf1[(t*4+3)*64 + lane];
    short8v b20 = wf2[(t*2+0)*64 + lane];
    short8v b21 = wf2[(t*2+1)*64 + lane];
    ax[t] = __builtin_amdgcn_mfma_f32_16x16x32_bf16(a0, bx0, ax[t], 0, 0, 0);
    ax[t] = __builtin_amdgcn_mfma_f32_16x16x32_bf16(a1, bx1, ax[t], 0, 0, 0);
    ay[t] = __builtin_amdgcn_mfma_f32_16x16x32_bf16(a0, by0, ay[t], 0, 0, 0);
    ay[t] = __builtin_amdgcn_mfma_f32_16x16x32_bf16(a1, by1, ay[t], 0, 0, 0);
    bc[t] = __builtin_amdgcn_mfma_f32_16x16x32_bf16(c0f, b20, bc[t], 0, 0, 0);
    bc[t] = __builtin_amdgcn_mfma_f32_16x16x32_bf16(c1f, b21, bc[t], 0, 0, 0);
  }
  #pragma unroll
  for (int t = 0; t < 4; t++){
    #pragma unroll
    for (int i = 0; i < 4; i++){
      int er = e0 + w*16 + rowq + i;
      if (er < N_EDGES){
        rw12p[(size_t)er*64 + t*16 + cl] = packbf(ax[t][i], ay[t][i]);
        rwBp [(size_t)er*64 + t*16 + cl] = f2bf(bc[t][i]);
      }
    }
  }
}

__global__ void k_fill(const int* __restrict__ recv, int* __restrict__ cursor, int* __restrict__ elist){
  int i = blockIdx.x*blockDim.x + threadIdx.x;
  if (i < N_EDGES){ int pos = atomicAdd(&cursor[recv[i]], 1); elist[pos] = i; }
}

// ---------- pass-1 gather + node transforms (1 wave per node, 4-deep prefetch) ----------
__global__ __launch_bounds__(256) void k_node1(
  const int* __restrict__ senders, const int* __restrict__ species,
  const int* __restrict__ starts, const int* __restrict__ elist,
  const float4* __restrict__ shu,
  const unsigned* __restrict__ rw12p, const unsigned short* __restrict__ h1p,
  const float* __restrict__ selT,
  const float* __restrict__ pw, const float* __restrict__ uwv,
  const float* __restrict__ row,
  const float* __restrict__ linup2, const float* __restrict__ resT,
  float* __restrict__ out,
  uint2* __restrict__ outvp, float* __restrict__ reso)
{
  int lane  = threadIdx.x & 63;
  int wslot = threadIdx.x >> 6;
  int n = blockIdx.x*4 + wslot;          // grid exact: 2500*4 = 10000
  __shared__ float4 sacc[4][64];

  int s0 = __builtin_amdgcn_readfirstlane(starts[n]);
  int s1 = __builtin_amdgcn_readfirstlane(starts[n+1]);
  int sp = __builtin_amdgcn_readfirstlane(species[n]);

  float acc0 = 0.f, acc1 = 0.f, acc2 = 0.f, acc3 = 0.f;
  for (int base = s0; base < s1; base += 64){
    int m = min(64, s1 - base);
    int e_l = 0, snd_l = 0;
    if (lane < m){
      e_l   = elist[base + lane];
      snd_l = senders[e_l];
    }
    for (int t = 0; t < m; t += 4){
      int i0 = t;
      int i1 = min(t+1, m-1), i2 = min(t+2, m-1), i3 = min(t+3, m-1);
      float w1 = (t+1 < m) ? 1.f : 0.f;
      float w2 = (t+2 < m) ? 1.f : 0.f;
      float w3 = (t+3 < m) ? 1.f : 0.f;
      int e0i = __builtin_amdgcn_readfirstlane(__shfl(e_l, i0, 64));
      int s0i = __builtin_amdgcn_readfirstlane(__shfl(snd_l, i0, 64));
      int e1i = __builtin_amdgcn_readfirstlane(__shfl(e_l, i1, 64));
      int s1i = __builtin_amdgcn_readfirstlane(__shfl(snd_l, i1, 64));
      int e2i = __builtin_amdgcn_readfirstlane(__shfl(e_l, i2, 64));
      int s2i = __builtin_amdgcn_readfirstlane(__shfl(snd_l, i2, 64));
      int e3i = __builtin_amdgcn_readfirstlane(__shfl(e_l, i3, 64));
      int s3i = __builtin_amdgcn_readfirstlane(__shfl(snd_l, i3, 64));
      unsigned p0 = rw12p[(size_t)e0i*64 + lane];
      unsigned p1 = rw12p[(size_t)e1i*64 + lane];
      unsigned p2 = rw12p[(size_t)e2i*64 + lane];
      unsigned p3 = rw12p[(size_t)e3i*64 + lane];
      float h0 = bf2f(h1p[s0i*64 + lane]);
      float h1v = bf2f(h1p[s1i*64 + lane]) * w1;
      float h2v = bf2f(h1p[s2i*64 + lane]) * w2;
      float h3v = bf2f(h1p[s3i*64 + lane]) * w3;
      float4 v0 = shu[e0i];
      float4 v1 = shu[e1i];
      float4 v2 = shu[e2i];
      float4 v3 = shu[e3i];
      acc0 += bf2f(p0 & 0xffffu)*h0;  float m0 = bf2f(p0 >> 16)*h0;
      acc1 += m0*v0.x; acc2 += m0*v0.y; acc3 += m0*v0.z;
      acc0 += bf2f(p1 & 0xffffu)*h1v; float m1 = bf2f(p1 >> 16)*h1v;
      acc1 += m1*v1.x; acc2 += m1*v1.y; acc3 += m1*v1.z;
      acc0 += bf2f(p2 & 0xffffu)*h2v; float m2 = bf2f(p2 >> 16)*h2v;
      acc1 += m2*v2.x; acc2 += m2*v2.y; acc3 += m2*v2.z;
      acc0 += bf2f(p3 & 0xffffu)*h3v; float m3 = bf2f(p3 >> 16)*h3v;
      acc1 += m3*v3.x; acc2 += m3*v3.y; acc3 += m3*v3.z;
    }
  }
  const float c10 = 0.1f;                      // 1/AVG_NEIGH
  const float c13 = 0.17320508075688773f;      // sqrt(3)/10
  sacc[wslot][lane] = make_float4(acc0*c10, acc1*c13, acc2*c13, acc3*c13);
  asm volatile("s_waitcnt lgkmcnt(0)" ::: "memory");

  // feats[c,k] = sum_d selW[c,d] * agg[d,k]
  const float* selp = selT + sp*4096;
  float f0 = 0.f, f1 = 0.f, f2 = 0.f, f3 = 0.f;
  #pragma unroll 8
  for (int d = 0; d < 64; d++){
    float wv = selp[d*64 + lane];
    float4 a = sacc[wslot][d];
    f0 += wv*a.x; f1 += wv*a.y; f2 += wv*a.z; f3 += wv*a.w;
  }

  float s = f0;
  const float* pwp = pw  + sp*192;
  const float* uwp = uwv + sp*192;
  float pw0 = pwp[lane], pw1 = pwp[64+lane], pw2 = pwp[128+lane];
  float uw0 = uwp[lane], uw1 = uwp[64+lane], uw2 = uwp[128+lane];
  float ss = s*s;
  float o0  = pw0*s + pw1*ss + pw2*ss*s;
  float uco = uw0 + uw1*s + uw2*ss;

  // ro1 = sum_c o0[c]*row[c]
  float rv = o0 * row[lane];
  #pragma unroll
  for (int off = 32; off >= 1; off >>= 1) rv += __shfl_xor(rv, off, 64);
  if (lane == 0) out[n*2 + 0] = rv;

  // stage o0, compute h2 and res
  float* so = reinterpret_cast<float*>(&sacc[wslot][0]);
  asm volatile("s_waitcnt lgkmcnt(0)" ::: "memory");
  so[lane] = o0;
  asm volatile("s_waitcnt lgkmcnt(0)" ::: "memory");

  float hh = 0.f, rr = 0.f;
  const float* resp = resT + sp*4096;
  #pragma unroll 8
  for (int d = 0; d < 64; d++){
    float od = so[d];
    hh += od * linup2[d*64 + lane];
    rr += od * resp[d*64 + lane];
  }
  uint2 op;
  op.x = packbf(uco*f1, uco*f2);
  op.y = packbf(uco*f3, hh);
  outvp[n*64 + lane] = op;
  reso[n*64 + lane] = rr;
}

// ---------- pass-2 gather + readout (1 wave per node, 4-deep prefetch) ----------
__global__ __launch_bounds__(256) void k_node2(
  const int* __restrict__ senders, const int* __restrict__ species,
  const int* __restrict__ starts, const int* __restrict__ elist,
  const float4* __restrict__ shu,
  const unsigned short* __restrict__ rwBp,
  const uint2* __restrict__ outvp, const float* __restrict__ reso,
  const float* __restrict__ pw2,
  const float* __restrict__ roW1, const float* __restrict__ roW2,
  float* __restrict__ out)
{
  int lane  = threadIdx.x & 63;
  int wslot = threadIdx.x >> 6;
  int n = blockIdx.x*4 + wslot;
  __shared__ float sout[4][64];

  int s0 = __builtin_amdgcn_readfirstlane(starts[n]);
  int s1 = __builtin_amdgcn_readfirstlane(starts[n+1]);
  int sp = __builtin_amdgcn_readfirstlane(species[n]);

  float acc = 0.f;
  for (int base = s0; base < s1; base += 64){
    int m = min(64, s1 - base);
    int e_l = 0, snd_l = 0;
    if (lane < m){
      e_l   = elist[base + lane];
      snd_l = senders[e_l];
    }
    for (int t = 0; t < m; t += 4){
      int i0 = t;
      int i1 = min(t+1, m-1), i2 = min(t+2, m-1), i3 = min(t+3, m-1);
      float w1 = (t+1 < m) ? 1.f : 0.f;
      float w2 = (t+2 < m) ? 1.f : 0.f;
      float w3 = (t+3 < m) ? 1.f : 0.f;
      int e0i = __builtin_amdgcn_readfirstlane(__shfl(e_l, i0, 64));
      int s0i = __builtin_amdgcn_readfirstlane(__shfl(snd_l, i0, 64));
      int e1i = __builtin_amdgcn_readfirstlane(__shfl(e_l, i1, 64));
      int s1i = __builtin_amdgcn_readfirstlane(__shfl(snd_l, i1, 64));
      int e2i = __builtin_amdgcn_readfirstlane(__shfl(e_l, i2, 64));
      int s2i = __builtin_amdgcn_readfirstlane(__shfl(snd_l, i2, 64));
      int e3i = __builtin_amdgcn_readfirstlane(__shfl(e_l, i3, 64));
      int s3i = __builtin_amdgcn_readfirstlane(__shfl(snd_l, i3, 64));
      float r0 = bf2f(rwBp[(size_t)e0i*64 + lane]);
      float r1 = bf2f(rwBp[(size_t)e1i*64 + lane]) * w1;
      float r2 = bf2f(rwBp[(size_t)e2i*64 + lane]) * w2;
      float r3 = bf2f(rwBp[(size_t)e3i*64 + lane]) * w3;
      uint2 o0v = outvp[s0i*64 + lane];
      uint2 o1v = outvp[s1i*64 + lane];
      uint2 o2v = outvp[s2i*64 + lane];
      uint2 o3v = outvp[s3i*64 + lane];
      float4 v0 = shu[e0i];
      float4 v1 = shu[e1i];
      float4 v2 = shu[e2i];
      float4 v3 = shu[e3i];
      acc += r0 * (bf2f(o0v.y >> 16) + bf2f(o0v.x & 0xffffu)*v0.x
                   + bf2f(o0v.x >> 16)*v0.y + bf2f(o0v.y & 0xffffu)*v0.z);
      acc += r1 * (bf2f(o1v.y >> 16) + bf2f(o1v.x & 0xffffu)*v1.x
                   + bf2f(o1v.x >> 16)*v1.y + bf2f(o1v.y & 0xffffu)*v1.z);
      acc += r2 * (bf2f(o2v.y >> 16) + bf2f(o2v.x & 0xffffu)*v2.x
                   + bf2f(o2v.x >> 16)*v2.y + bf2f(o2v.y & 0xffffu)*v2.z);
      acc += r3 * (bf2f(o3v.y >> 16) + bf2f(o3v.x & 0xffffu)*v3.x
                   + bf2f(o3v.x >> 16)*v3.y + bf2f(o3v.y & 0xffffu)*v3.z);
    }
  }
  float s2 = acc * 0.1f;
  const float* p2 = pw2 + sp*192;
  float q0 = p2[lane], q1 = p2[64+lane], q2 = p2[128+lane];
  float s2s = s2*s2;
  float o2 = q0*s2 + q1*s2s + q2*s2s*s2 + reso[n*64 + lane];

  sout[wslot][lane] = o2;
  asm volatile("s_waitcnt lgkmcnt(0)" ::: "memory");

  // ro2 = silu(out2 @ roW1) @ roW2
  int j = lane & 15, g = lane >> 4;
  float qp = 0.f;
  #pragma unroll
  for (int t = 0; t < 16; t++){
    int c = g*16 + t;
    qp += sout[wslot][c] * roW1[c*16 + j];
  }
  qp += __shfl_xor(qp, 16, 64);
  qp += __shfl_xor(qp, 32, 64);
  float sil = qp / (1.f + __expf(-qp));
  float contrib = sil * roW2[j];
  contrib += __shfl_xor(contrib, 1, 64);
  contrib += __shfl_xor(contrib, 2, 64);
  contrib += __shfl_xor(contrib, 4, 64);
  contrib += __shfl_xor(contrib, 8, 64);
  if (lane == 0) out[n*2 + 1] = contrib;
}

extern "C" void kernel_launch(void* const* d_in, const int* in_sizes, int n_in,
                              void* d_out, int out_size, void* d_ws, size_t ws_size,
                              hipStream_t stream)
{
  const float* ev     = (const float*)d_in[0];
  const int*   spec   = (const int*)  d_in[1];
  const int*   send   = (const int*)  d_in[2];
  const int*   recv   = (const int*)  d_in[3];
  const float* embedW = (const float*)d_in[4];
  const float* l1_lin = (const float*)d_in[5];
  const float* l1_rW1 = (const float*)d_in[6];
  const float* l1_rW2 = (const float*)d_in[7];
  const float* l1_sel = (const float*)d_in[8];
  const float* l1_pw  = (const float*)d_in[9];
  const float* l1_uw  = (const float*)d_in[10];
  const float* l1_row = (const float*)d_in[11];
  const float* l2_lin = (const float*)d_in[12];
  const float* l2_rW1 = (const float*)d_in[13];
  const float* l2_rW2 = (const float*)d_in[14];
  const float* l2_res = (const float*)d_in[15];
  const float* l2_pw  = (const float*)d_in[16];
  const float* l2_roW1= (const float*)d_in[17];
  const float* l2_roW2= (const float*)d_in[18];
  float* out = (float*)d_out;

  char* w = (char*)d_ws;
  unsigned*       rw12p = (unsigned*)w;       w += (size_t)N_EDGES*64*4;  // 25.6 MB
  unsigned short* rwBp  = (unsigned short*)w; w += (size_t)N_EDGES*64*2;  // 12.8 MB
  unsigned short* h1p   = (unsigned short*)w; w += (size_t)N_NODES*64*2;  // 1.28 MB
  uint2*  outvp = (uint2*)w;  w += (size_t)N_NODES*64*8;                  // 5.12 MB
  float*  reso  = (float*)w;  w += (size_t)N_NODES*64*4;
  float*  selT  = (float*)w;  w += (size_t)NSPEC*4096*4;
  float*  resT  = (float*)w;  w += (size_t)NSPEC*4096*4;
  float4* shu   = (float4*)w; w += (size_t)N_EDGES*16;
  unsigned short* wfrag = (unsigned short*)w; w += 12288*2;
  int* starts = (int*)w;      w += (size_t)(N_NODES+1)*4;
  int* cursor = (int*)w;      w += (size_t)N_NODES*4;
  int* elist  = (int*)w;      w += (size_t)N_EDGES*4;

  k_pre  <<<2748, 256, 0, stream>>>(cursor, l1_sel, l2_res, selT, resT,
                                    spec, embedW, l1_lin, h1p,
                                    l1_rW2, l2_rW2, wfrag);
  k_count<<<(N_EDGES+255)/256, 256, 0, stream>>>(recv, cursor);
  k_scanrw<<<1 + (N_EDGES+63)/64, 256, 0, stream>>>(cursor, starts,
        ev, l1_rW1, l2_rW1, wfrag, rw12p, rwBp, shu);
  k_fill <<<(N_EDGES+255)/256, 256, 0, stream>>>(recv, cursor, elist);
  k_node1<<<N_NODES/4, 256, 0, stream>>>(send, spec, starts, elist, shu, rw12p, h1p,
        selT, l1_pw, l1_uw, l1_row, l2_lin, resT, out, outvp, reso);
  k_node2<<<N_NODES/4, 256, 0, stream>>>(send, spec, starts, elist, shu, rwBp,
        outvp, reso, l2_pw, l2_roW1, l2_roW2, out);
}